// Round 1
// baseline (131.430 us; speedup 1.0000x reference)
//
#include <hip/hip_runtime.h>
#include <hip/hip_cooperative_groups.h>
#include <math.h>

namespace cg = cooperative_groups;

// Problem dims (fixed by setup_inputs)
#define NR   1500     // rows of X_m  (Nt - Lt)
#define NTT  1508     // Nt
#define QD   12       // D
#define LT   8
#define DIN  192      // 2*Lt*Q
#define MM   192      // M
#define JITTER 1e-6f
// Exact per-row suprema: psi1 expo <= logdet1[n], psi2 expo <= logdet2[n].
// Rows below this cut contribute < e^-30 ~ 1e-13 each -> provably < 1e-6 relative.
#define PRUNE_CUT -30.0f

// ---- workspace layout (float offsets) ----
#define OFF_W2    0
#define OFF_WU2   288000
#define OFF_P1    576000
#define OFF_R1    864000
#define OFF_S1    1152000
#define OFF_S2    1153500
#define OFF_V     1155000
#define OFF_D2ZZ  1191864
#define OFF_KUU   1228728
#define OFF_PSI1  1265592
#define OFF_PSI2  1553592
#define OFF_LC    1590456
#define OFF_LC2   1627320
#define OFF_G     1664184
#define OFF_SCAL  1666488
#define OFF_NLIST 1666504     // 1500 ints: surviving-n list for psi2
#define OFF_BSUM  1668016     // 256 blocks x 4 per-block input-sum partials
#define OFF_F     1670016     // de-aliased from P1 (was a latent same-dispatch race)
// scal slots: 0 trace_raw, 2 ||Y||^2, 3 sum(X_vo), 4 sum(X_mo^2),
//             5 sum(log X_vo), 6 sum(X_mb^2+X_vb), 7 0.5*logdetKuu, 8 0.5*logdetC2,
//             12 cnt2 (psi2 survivors), 13 cnt1 (psi1 survivors), 14 gflag (G != 0),
//             15 ticket (fallback sumsfinal last-block)

#define LDWSF(p)   __hip_atomic_load((p), __ATOMIC_RELAXED, __HIP_MEMORY_SCOPE_AGENT)
#define LDWSI(p)   __hip_atomic_load((p), __ATOMIC_RELAXED, __HIP_MEMORY_SCOPE_AGENT)
#define STWSF(p,v) __hip_atomic_store((p), (v), __ATOMIC_RELAXED, __HIP_MEMORY_SCOPE_AGENT)

__device__ __forceinline__ float wave_reduce(float s) {
    s += __shfl_down(s, 32); s += __shfl_down(s, 16); s += __shfl_down(s, 8);
    s += __shfl_down(s, 4);  s += __shfl_down(s, 2);  s += __shfl_down(s, 1);
    return s;
}
__device__ __forceinline__ float bfly_sum(float s) {
    s += __shfl_xor(s, 32); s += __shfl_xor(s, 16); s += __shfl_xor(s, 8);
    s += __shfl_xor(s, 4);  s += __shfl_xor(s, 2);  s += __shfl_xor(s, 1);
    return s;
}
__device__ __forceinline__ int rd_cnt(const float* ws, int slot) {
    return ((const int*)(ws + OFF_SCAL))[slot];
}

#define ALD 196
#define NB  32
#define ZR  196
#define FGRID 256

// ============================================================================
// Fused cooperative kernel: the whole dependency chain in ONE dispatch.
// Fast path (cnt1==cnt2==0, true for the bench data): prep+sums -> 1 grid
// sync -> final assembly. Slow path keeps all original phases, separated by
// grid syncs (coop launch guarantees co-residency + memory visibility).
// 147 KB static LDS pins occupancy to 1 block/CU -> grid of 256 is legal.
// ============================================================================
__global__ __launch_bounds__(256, 1) void k_fused(
    const float* __restrict__ Xm_m, const float* __restrict__ Xm_v,
    const float* __restrict__ Z, const float* __restrict__ X_mean,
    const float* __restrict__ X_var, const float* __restrict__ kern_var,
    const float* __restrict__ kern_ls, const float* __restrict__ lik,
    float* __restrict__ ws, float* __restrict__ out)
{
    cg::grid_group grid = cg::this_grid();
    __shared__ __align__(16) float smem[MM * ALD];   // 150528 B, union for all phases
    const int tid  = threadIdx.x;
    const int lane = tid & 63;
    const int wav  = tid >> 6;
    const int nblk = gridDim.x;
    const int ty4  = tid >> 4, tx4 = tid & 15;

    // ---------------- Phase A: per-n prep + input sums ----------------
    for (int n = blockIdx.x * 4 + wav; n < NR; n += nblk * 4) {
        float v0 = 0, v1 = 0, v2 = 0, v3 = 0;
        #pragma unroll
        for (int s = 0; s < 3; s++) {
            int q = lane + 64 * s;
            float u, v;
            if (q < 96) { u = X_mean[n * QD + q]; v = X_var[n * QD + q]; }
            else        { int j = q - 96; u = Xm_m[(1 + n) * QD + j]; v = Xm_v[(1 + n) * QD + j]; }
            float ls = kern_ls[q]; float l2 = ls * ls;
            float d1 = l2 + v, d2 = l2 + 2.0f * v;
            float i1 = 1.0f / d1, i2 = 1.0f / d2;
            ws[OFF_P1  + n * DIN + q] = u * i1;
            ws[OFF_R1  + n * DIN + q] = i1;
            ws[OFF_W2  + n * DIN + q] = i2;
            ws[OFF_WU2 + n * DIN + q] = u * i2;
            v0 += log1pf(v / l2);
            v1 += log1pf(2.0f * v / l2);
            v2 += u * u * i1;
            v3 += u * u * i2;
        }
        v0 = bfly_sum(v0); v1 = bfly_sum(v1); v2 = bfly_sum(v2); v3 = bfly_sum(v3);
        if (lane == 0) {
            ws[OFF_S1 + n] = -0.5f * (v0 + v2);
            ws[OFF_S2 + n] = -0.5f * v1 - v3;
            float ld1 = -0.5f * v0;                // exact sup of psi1 exponent
            float ld2 = -0.5f * v1;                // exact sup of psi2 exponent
            int* cnts = (int*)(ws + OFF_SCAL);
            if (ld1 > PRUNE_CUT) atomicAdd(&cnts[13], 1);
            if (ld2 > PRUNE_CUT) {
                int idx = atomicAdd(&cnts[12], 1);
                ((int*)(ws + OFF_NLIST))[idx] = n;
            }
        }
    }
    {   // input sums (Svo, Smo2, Slog, Smb) -> per-block partials, no atomics
        float pVo = 0, pMo = 0, pLg = 0, pMb = 0;
        for (int idx = blockIdx.x * 256 + tid; idx < NTT * QD; idx += nblk * 256) {
            float xm = X_mean[idx], xv = X_var[idx];
            if (idx >= LT * QD) { pVo += xv; pMo += xm * xm; pLg += logf(xv); }
            else                { pMb += xm * xm + xv; }
        }
        pVo = bfly_sum(pVo); pMo = bfly_sum(pMo); pLg = bfly_sum(pLg); pMb = bfly_sum(pMb);
        float* part = smem;   // 16 floats
        if (lane == 0) { part[wav*4+0] = pVo; part[wav*4+1] = pMo; part[wav*4+2] = pLg; part[wav*4+3] = pMb; }
        __syncthreads();
        if (tid < 4) {
            float s = part[tid] + part[4 + tid] + part[8 + tid] + part[12 + tid];
            STWSF(&ws[OFF_BSUM + blockIdx.x * 4 + tid], s);
        }
        __syncthreads();
    }
    grid.sync();

    const int* scal_i = (const int*)(ws + OFF_SCAL);
    const int cnt1 = LDWSI(scal_i + 13);
    const int cnt2 = LDWSI(scal_i + 12);

    if ((cnt1 | cnt2) != 0) {
        // =================== SLOW PATH (not exercised by bench data) =========
        float kv = *kern_var;
        // -------- Phase B: Kuu/d2zz tiles + psi1 tiles + F tiles --------
        for (int vb = blockIdx.x; vb < 144 + 2 * 1128; vb += nblk) {
            if (vb < 144) {
                int bx = vb / 12, by = vb - bx * 12;
                float (*Zm)[17] = (float(*)[17])smem;
                float (*Zp)[17] = (float(*)[17])(smem + 272);
                int m = bx * 16 + ty4, p = by * 16 + tx4;
                float d = 0.0f;
                for (int qc = 0; qc < 12; qc++) {
                    int q0 = qc * 16;
                    float inv_ls = 1.0f / kern_ls[q0 + tx4];
                    Zm[ty4][tx4] = Z[(bx * 16 + ty4) * DIN + q0 + tx4] * inv_ls;
                    Zp[ty4][tx4] = Z[(by * 16 + ty4) * DIN + q0 + tx4] * inv_ls;
                    __syncthreads();
                    #pragma unroll
                    for (int k = 0; k < 16; k++) { float t = Zm[ty4][k] - Zp[tx4][k]; d = fmaf(t, t, d); }
                    __syncthreads();
                }
                ws[OFF_D2ZZ + m * MM + p] = d;
                ws[OFF_KUU  + m * MM + p] = kv * __expf(-0.5f * d) + ((m == p) ? JITTER : 0.0f);
            } else if (vb < 144 + 1128) {
                if (cnt1 != 0) {
                    int t = vb - 144, bx = t % 94, by = t / 94;
                    int n = bx * 16 + ty4, m = by * 16 + tx4;
                    float (*Ps)[17]  = (float(*)[17])smem;
                    float (*Rs)[17]  = (float(*)[17])(smem + 272);
                    float (*Zs)[17]  = (float(*)[17])(smem + 544);
                    float (*Z2s)[17] = (float(*)[17])(smem + 816);
                    float dot1 = 0.0f, dot2 = 0.0f;
                    for (int qc = 0; qc < 12; qc++) {
                        int q0 = qc * 16;
                        Ps[ty4][tx4] = (n < NR) ? ws[OFF_P1 + n * DIN + q0 + tx4] : 0.0f;
                        Rs[ty4][tx4] = (n < NR) ? ws[OFF_R1 + n * DIN + q0 + tx4] : 0.0f;
                        float z = Z[(by * 16 + ty4) * DIN + q0 + tx4];
                        Zs[ty4][tx4] = z; Z2s[ty4][tx4] = z * z;
                        __syncthreads();
                        #pragma unroll
                        for (int k = 0; k < 16; k++) {
                            dot1 = fmaf(Ps[ty4][k], Zs[tx4][k], dot1);
                            dot2 = fmaf(Rs[ty4][k], Z2s[tx4][k], dot2);
                        }
                        __syncthreads();
                    }
                    if (n < NR) ws[OFF_PSI1 + n * MM + m] = kv * __expf(ws[OFF_S1 + n] + dot1 - 0.5f * dot2);
                }
            } else {
                if (cnt2 != 0) {
                    int t = vb - (144 + 1128), bx = t % 94, by = t / 94;
                    int n = bx * 16 + ty4, m = by * 16 + tx4;
                    float (*Us)[17] = (float(*)[17])smem;
                    float (*Ws)[17] = (float(*)[17])(smem + 272);
                    float (*Zb)[17] = (float(*)[17])(smem + 544);
                    float dotB = 0.0f, dotC = 0.0f;
                    for (int qc = 0; qc < 12; qc++) {
                        int q0 = qc * 16;
                        Us[ty4][tx4] = (n < NR) ? ws[OFF_WU2 + n * DIN + q0 + tx4] : 0.0f;
                        Ws[ty4][tx4] = (n < NR) ? ws[OFF_W2  + n * DIN + q0 + tx4] : 0.0f;
                        Zb[ty4][tx4] = Z[(by * 16 + ty4) * DIN + q0 + tx4];
                        __syncthreads();
                        #pragma unroll
                        for (int k = 0; k < 16; k++) {
                            float z = Zb[tx4][k];
                            dotB = fmaf(z, Us[ty4][k], dotB);
                            dotC = fmaf(z * z, Ws[ty4][k], dotC);
                        }
                        __syncthreads();
                    }
                    if (n < NR) ws[OFF_F + n * MM + m] = fmaf(-0.25f, dotC, dotB);
                }
            }
        }
        grid.sync();
        // -------- Phase C: G rows + psi2 tiles (or exact-zero fill) --------
        for (int vb = blockIdx.x; vb < 192 + 36; vb += nblk) {
            if (vb < 192) {
                if (cnt1 != 0) {
                    int m = vb;
                    const float* psi1 = ws + OFF_PSI1;
                    float g[QD];
                    #pragma unroll
                    for (int d = 0; d < QD; d++) g[d] = 0.0f;
                    for (int n = tid; n < NR; n += 256) {
                        float p = psi1[n * MM + m];
                        const float* xr = X_mean + (LT + n) * QD;
                        #pragma unroll
                        for (int d = 0; d < QD; d++) g[d] = fmaf(p, xr[d], g[d]);
                    }
                    float* red = smem;   // 256 floats
                    bool any = false;
                    for (int d = 0; d < QD; d++) {
                        red[tid] = g[d]; __syncthreads();
                        if (tid < 128) red[tid] += red[tid + 128];
                        __syncthreads();
                        if (tid < 64) {
                            float s = red[tid] + red[tid + 64];
                            s = wave_reduce(s);
                            if (tid == 0) { ws[OFF_G + m * QD + d] = s; any |= (s != 0.0f); }
                        }
                        __syncthreads();
                    }
                    if (tid == 0 && any) atomicOr((int*)(ws + OFF_SCAL) + 14, 1);
                }
            } else {
                int t = vb - 192, bx = t / 6, by = t - 6 * bx;
                int m0 = bx * 32, p0 = by * 32;
                int mA = m0 + 2 * ty4, pA = p0 + 2 * tx4;
                float* P2 = ws + OFF_PSI2;
                if (cnt2 == 0) {   // slow path => cnt1>0; chol-C2 may read psi2
                    P2[(mA    ) * MM + pA    ] = 0.0f;
                    P2[(mA    ) * MM + pA + 1] = 0.0f;
                    P2[(mA + 1) * MM + pA    ] = 0.0f;
                    P2[(mA + 1) * MM + pA + 1] = 0.0f;
                    __syncthreads();
                } else {
                    float a00 = 0, a01 = 0, a10 = 0, a11 = 0;
                    float* Zm = smem;             // 32*ZR
                    float* Zp = smem + 32 * ZR;   // 32*ZR
                    for (int idx = tid; idx < 32 * DIN; idx += 256) {
                        int r = idx / DIN, q = idx - r * DIN;
                        Zm[r * ZR + q] = Z[(m0 + r) * DIN + q];
                        Zp[r * ZR + q] = Z[(p0 + r) * DIN + q];
                    }
                    __syncthreads();
                    const float* w2base = ws + OFF_W2;
                    const float* F      = ws + OFF_F;
                    const float* s2arr  = ws + OFF_S2;
                    const int* list     = (const int*)(ws + OFF_NLIST);
                    const float4* zm0 = (const float4*)(Zm + (2 * ty4    ) * ZR);
                    const float4* zm1 = (const float4*)(Zm + (2 * ty4 + 1) * ZR);
                    const float4* zp0 = (const float4*)(Zp + (2 * tx4    ) * ZR);
                    const float4* zp1 = (const float4*)(Zp + (2 * tx4 + 1) * ZR);
                    for (int li = 0; li < cnt2; li++) {
                        int n = list[li];
                        const float4* w2p = (const float4*)(w2base + n * DIN);
                        float e00 = 0, e01 = 0, e10 = 0, e11 = 0;
                        #pragma unroll 4
                        for (int g = 0; g < DIN / 4; g++) {
                            float4 w = w2p[g];
                            float4 a = zm0[g], b = zm1[g], c = zp0[g], d = zp1[g];
                            float wp0, wp1;
                            wp0 = w.x * c.x; wp1 = w.x * d.x;
                            e00 = fmaf(a.x, wp0, e00); e01 = fmaf(a.x, wp1, e01);
                            e10 = fmaf(b.x, wp0, e10); e11 = fmaf(b.x, wp1, e11);
                            wp0 = w.y * c.y; wp1 = w.y * d.y;
                            e00 = fmaf(a.y, wp0, e00); e01 = fmaf(a.y, wp1, e01);
                            e10 = fmaf(b.y, wp0, e10); e11 = fmaf(b.y, wp1, e11);
                            wp0 = w.z * c.z; wp1 = w.z * d.z;
                            e00 = fmaf(a.z, wp0, e00); e01 = fmaf(a.z, wp1, e01);
                            e10 = fmaf(b.z, wp0, e10); e11 = fmaf(b.z, wp1, e11);
                            wp0 = w.w * c.w; wp1 = w.w * d.w;
                            e00 = fmaf(a.w, wp0, e00); e01 = fmaf(a.w, wp1, e01);
                            e10 = fmaf(b.w, wp0, e10); e11 = fmaf(b.w, wp1, e11);
                        }
                        float s2n = s2arr[n];
                        float Fm0 = F[n * MM + mA], Fm1 = F[n * MM + mA + 1];
                        float Fp0 = F[n * MM + pA], Fp1 = F[n * MM + pA + 1];
                        a00 += __expf(s2n + Fm0 + Fp0 - 0.5f * e00);
                        a01 += __expf(s2n + Fm0 + Fp1 - 0.5f * e01);
                        a10 += __expf(s2n + Fm1 + Fp0 - 0.5f * e10);
                        a11 += __expf(s2n + Fm1 + Fp1 - 0.5f * e11);
                    }
                    float kv2 = kv * kv;
                    const float* dz = ws + OFF_D2ZZ;
                    P2[(mA    ) * MM + pA    ] = kv2 * __expf(-0.25f * dz[(mA    ) * MM + pA    ]) * a00;
                    P2[(mA    ) * MM + pA + 1] = kv2 * __expf(-0.25f * dz[(mA    ) * MM + pA + 1]) * a01;
                    P2[(mA + 1) * MM + pA    ] = kv2 * __expf(-0.25f * dz[(mA + 1) * MM + pA    ]) * a10;
                    P2[(mA + 1) * MM + pA + 1] = kv2 * __expf(-0.25f * dz[(mA + 1) * MM + pA + 1]) * a11;
                    __syncthreads();
                }
            }
        }
        grid.sync();
        const int gflag = LDWSI((const int*)(ws + OFF_SCAL) + 14);
        // -------- Phase D: dual blocked LDL^T (block 0: Kuu, block 1: C2) ----
        if (blockIdx.x < 2 && (cnt2 != 0 || gflag != 0)) {
            bool isC2 = (blockIdx.x == 1);
            float* A = smem;
            const float* Kuu  = ws + OFF_KUU;
            const float* psi2 = ws + OFF_PSI2;
            float inv_s2 = 1.0f / (*lik);
            for (int idx = tid; idx < MM * MM; idx += 256) {
                int i = idx / MM, j = idx - i * MM;
                float v = Kuu[idx];
                if (isC2) v = fmaf(psi2[idx], inv_s2, v);
                A[i * ALD + j] = v;
            }
            __syncthreads();
            float logacc = 0.0f;
            for (int p = 0; p < MM / NB; p++) {
                int k0 = p * NB;
                int e  = k0 + NB;
                if (tid < 64) {
                    int l64 = tid;
                    float P[3][NB];
                    #pragma unroll
                    for (int s = 0; s < 3; s++) {
                        int r = l64 + 64 * s;
                        #pragma unroll
                        for (int g = 0; g < NB / 4; g++) {
                            float4 v = *(const float4*)&A[r * ALD + k0 + 4 * g];
                            P[s][4*g] = v.x; P[s][4*g+1] = v.y; P[s][4*g+2] = v.z; P[s][4*g+3] = v.w;
                        }
                    }
                    int sD = k0 >> 6;
                    int lD = k0 & 63;
                    #pragma unroll
                    for (int c = 0; c < NB; c++) {
                        int k = k0 + c;
                        float colc = (sD == 0) ? P[0][c] : ((sD == 1) ? P[1][c] : P[2][c]);
                        float dkk = __shfl(colc, lD + c);
                        float inv = 1.0f / dkk;
                        logacc += logf(dkk);
                        float m0 = (l64       > k) ? P[0][c] * inv : 0.0f;
                        float m1 = (l64 + 64  > k) ? P[1][c] * inv : 0.0f;
                        float m2 = (l64 + 128 > k) ? P[2][c] * inv : 0.0f;
                        P[0][c] = (l64       > k) ? m0 : P[0][c];
                        P[1][c] = (l64 + 64  > k) ? m1 : P[1][c];
                        P[2][c] = (l64 + 128 > k) ? m2 : P[2][c];
                        #pragma unroll
                        for (int j = c + 1; j < NB; j++) {
                            float w = __shfl(colc, lD + j);
                            P[0][j] = fmaf(-m0, w, P[0][j]);
                            P[1][j] = fmaf(-m1, w, P[1][j]);
                            P[2][j] = fmaf(-m2, w, P[2][j]);
                        }
                    }
                    #pragma unroll
                    for (int s = 0; s < 3; s++) {
                        int r = l64 + 64 * s;
                        #pragma unroll
                        for (int g = 0; g < NB / 4; g++) {
                            float4 v = make_float4(P[s][4*g], P[s][4*g+1], P[s][4*g+2], P[s][4*g+3]);
                            *(float4*)&A[r * ALD + k0 + 4 * g] = v;
                        }
                    }
                }
                __syncthreads();
                int T = MM - e;
                if (T > 0) {
                    for (int idx = tid; idx < NB * T; idx += 256) {
                        int c = idx / T, j = e + (idx - c * T);
                        float d = A[(k0 + c) * ALD + (k0 + c)];
                        A[(k0 + c) * ALD + j] = A[j * ALD + k0 + c] * sqrtf(d);
                    }
                    __syncthreads();
                    int nT = (T + 127) / 128;
                    for (int bi = 0; bi < nT; bi++)
                    for (int bj = 0; bj < nT; bj++) {
                        int i0 = e + 128 * bi + 8 * ty4;
                        int j0 = e + 128 * bj + 8 * tx4;
                        int ic = (i0 < MM - 8) ? i0 : (MM - 8);
                        int jc = (j0 < MM - 8) ? j0 : (MM - 8);
                        float4 acc[8][2];
                        #pragma unroll
                        for (int r = 0; r < 8; r++) {
                            acc[r][0] = *(const float4*)&A[(ic + r) * ALD + jc];
                            acc[r][1] = *(const float4*)&A[(ic + r) * ALD + jc + 4];
                        }
                        #pragma unroll 4
                        for (int c = 0; c < NB; c++) {
                            const float* row = &A[(k0 + c) * ALD];
                            float4 av0 = *(const float4*)&row[ic];
                            float4 av1 = *(const float4*)&row[ic + 4];
                            float4 bv0 = *(const float4*)&row[jc];
                            float4 bv1 = *(const float4*)&row[jc + 4];
                            float avs[8] = {av0.x, av0.y, av0.z, av0.w, av1.x, av1.y, av1.z, av1.w};
                            #pragma unroll
                            for (int r = 0; r < 8; r++) {
                                float a = avs[r];
                                acc[r][0].x = fmaf(-a, bv0.x, acc[r][0].x);
                                acc[r][0].y = fmaf(-a, bv0.y, acc[r][0].y);
                                acc[r][0].z = fmaf(-a, bv0.z, acc[r][0].z);
                                acc[r][0].w = fmaf(-a, bv0.w, acc[r][0].w);
                                acc[r][1].x = fmaf(-a, bv1.x, acc[r][1].x);
                                acc[r][1].y = fmaf(-a, bv1.y, acc[r][1].y);
                                acc[r][1].z = fmaf(-a, bv1.z, acc[r][1].z);
                                acc[r][1].w = fmaf(-a, bv1.w, acc[r][1].w);
                            }
                        }
                        if (ic == i0 && jc == j0) {
                            #pragma unroll
                            for (int r = 0; r < 8; r++) {
                                *(float4*)&A[(i0 + r) * ALD + j0]     = acc[r][0];
                                *(float4*)&A[(i0 + r) * ALD + j0 + 4] = acc[r][1];
                            }
                        }
                    }
                    __syncthreads();
                }
            }
            float* dst = ws + (isC2 ? OFF_LC2 : OFF_LC);
            for (int idx = tid; idx < MM * MM; idx += 256) {
                int i = idx / MM, j = idx - i * MM;
                dst[idx] = A[i * ALD + j];
            }
            if (tid == 0) STWSF(&ws[OFF_SCAL + (isC2 ? 8 : 7)], 0.5f * logacc);
        }
        grid.sync();
        // -------- Phase E: triangular solves (wave-per-column) --------
        for (int u = blockIdx.x * 4 + wav; u < MM + QD; u += nblk * 4) {
            if (u < MM) {
                if (cnt2 != 0) {
                    const float* L = ws + OFF_LC;
                    float* V = ws + OFF_V;
                    int j = u;
                    int k0 = j + lane, k1 = k0 + 64, k2 = k0 + 128;
                    float x0 = 0, x1 = 0, x2 = 0;
                    for (int i = j; i < MM; i++) {
                        const float* Lr = L + i * MM;
                        float s = 0.0f;
                        if (k0 < i) s = fmaf(Lr[k0], x0, s);
                        if (k1 < i) s = fmaf(Lr[k1], x1, s);
                        if (k2 < i) s = fmaf(Lr[k2], x2, s);
                        #pragma unroll
                        for (int off = 1; off < 64; off <<= 1) s += __shfl_xor(s, off);
                        float xi = ((i == j) ? 1.0f : 0.0f) - s;
                        if (k0 == i) x0 = xi;
                        if (k1 == i) x1 = xi;
                        if (k2 == i) x2 = xi;
                        if (lane == 0) V[i * MM + j] = xi;
                    }
                }
            } else if (gflag != 0) {
                const float* L = ws + OFF_LC2;
                const float* G = ws + OFF_G;
                int c = u - MM;
                int k0 = lane, k1 = lane + 64, k2 = lane + 128;
                float x0 = 0, x1 = 0, x2 = 0, ss = 0;
                for (int i = 0; i < MM; i++) {
                    const float* Lr = L + i * MM;
                    float s = 0.0f;
                    if (k0 < i) s = fmaf(Lr[k0], x0, s);
                    if (k1 < i) s = fmaf(Lr[k1], x1, s);
                    if (k2 < i) s = fmaf(Lr[k2], x2, s);
                    #pragma unroll
                    for (int off = 1; off < 64; off <<= 1) s += __shfl_xor(s, off);
                    float xi = G[i * QD + c] - s;
                    if (k0 == i) x0 = xi;
                    if (k1 == i) x1 = xi;
                    if (k2 == i) x2 = xi;
                    if (lane == 0) ss += xi * xi / Lr[i];
                }
                if (lane == 0) atomicAdd(&ws[OFF_SCAL + 2], ss);
            }
        }
        grid.sync();
        // -------- Phase F: trace_raw --------
        if (cnt2 != 0) {
            for (int i = blockIdx.x; i < MM; i += nblk) {
                float* vrow = smem;         // 192
                float* red  = smem + 192;   // 256
                const float* V = ws + OFF_V;
                const float* P = ws + OFF_PSI2;
                for (int a = tid; a < MM; a += 256) vrow[a] = (a <= i) ? V[i * MM + a] : 0.0f;
                __syncthreads();
                float acc = 0.0f;
                for (int a = tid; a <= i; a += 256) {
                    const float* Pr = P + a * MM;
                    float inner = 0.0f;
                    for (int b = 0; b <= i; b++) inner = fmaf(Pr[b], vrow[b], inner);
                    acc = fmaf(vrow[a], inner, acc);
                }
                red[tid] = acc; __syncthreads();
                if (tid < 128) red[tid] += red[tid + 128];
                __syncthreads();
                if (tid < 64) {
                    float s = red[tid] + red[tid + 64];
                    s = wave_reduce(s);
                    if (tid == 0) { float di = ws[OFF_LC + i * MM + i]; atomicAdd(&ws[OFF_SCAL + 0], s / di); }
                }
                __syncthreads();
            }
        }
        grid.sync();
    }

    // ---------------- Final assembly (block 0) ----------------
    if (blockIdx.x == 0 && tid < 64) {
        float s0 = 0, s1 = 0, s2 = 0, s3 = 0;
        for (int b = tid; b < nblk; b += 64) {
            const float* bp = ws + OFF_BSUM + 4 * b;
            s0 += LDWSF(bp + 0); s1 += LDWSF(bp + 1); s2 += LDWSF(bp + 2); s3 += LDWSF(bp + 3);
        }
        s0 = bfly_sum(s0); s1 = bfly_sum(s1); s2 = bfly_sum(s2); s3 = bfly_sum(s3);
        if (tid == 0) {
            float Svo = s0, Smo2 = s1, Slog = s2, Smb = s3;
            float trRaw = LDWSF(ws + OFF_SCAL + 0);
            float ssY   = LDWSF(ws + OFF_SCAL + 2);
            float ldK   = LDWSF(ws + OFF_SCAL + 7);
            float ldC2  = LDWSF(ws + OFF_SCAL + 8);
            float kv = *kern_var, s2v = *lik;
            float inv_s2 = 1.0f / s2v;
            const float lp2pi = 1.8378770664093453f;  // log(2*pi)
            float trA = trRaw * inv_s2;
            float ldB = 2.0f * (ldC2 - ldK);
            float sc2 = ssY * inv_s2 * inv_s2;
            float ND = 18000.0f;   // (Nt-Lt)*D
            float Df = 12.0f;
            float bound = -0.5f * ND * (lp2pi + logf(s2v));
            bound += -0.5f * inv_s2 * (Svo + Smo2);
            bound += -0.5f * Df * ((kv * 1500.0f) * inv_s2 - trA);
            bound += -0.5f * Df * ldB;
            bound += 0.5f * sc2;
            bound += 0.5f * Slog + 0.5f * ND * lp2pi;      // ent
            bound += -96.0f * lp2pi - 0.5f * Smb;          // ent2 (Lt*D = 96)
            out[0] = bound;
        }
    }
}

// ============================================================================
// Fallback path: the original (verified) multi-kernel chain, used only if the
// cooperative launch is rejected (e.g. unsupported under graph capture).
// ============================================================================

__global__ __launch_bounds__(256) void k_prep(
    const float* __restrict__ Xm_m, const float* __restrict__ Xm_v,
    const float* __restrict__ X_mean, const float* __restrict__ X_var,
    const float* __restrict__ kern_ls, float* __restrict__ ws)
{
    int wave = threadIdx.x >> 6, lane = threadIdx.x & 63;
    int n = blockIdx.x * 4 + wave;            // 1500 = 375*4 exact
    float v0 = 0, v1 = 0, v2 = 0, v3 = 0;
    #pragma unroll
    for (int s = 0; s < 3; s++) {
        int q = lane + 64 * s;
        float u, v;
        if (q < 96) { u = X_mean[n * QD + q]; v = X_var[n * QD + q]; }
        else        { int j = q - 96; u = Xm_m[(1 + n) * QD + j]; v = Xm_v[(1 + n) * QD + j]; }
        float ls = kern_ls[q]; float l2 = ls * ls;
        float d1 = l2 + v, d2 = l2 + 2.0f * v;
        float i1 = 1.0f / d1, i2 = 1.0f / d2;
        ws[OFF_P1  + n * DIN + q] = u * i1;
        ws[OFF_R1  + n * DIN + q] = i1;
        ws[OFF_W2  + n * DIN + q] = i2;
        ws[OFF_WU2 + n * DIN + q] = u * i2;
        v0 += log1pf(v / l2);
        v1 += log1pf(2.0f * v / l2);
        v2 += u * u * i1;
        v3 += u * u * i2;
    }
    v0 = bfly_sum(v0); v1 = bfly_sum(v1); v2 = bfly_sum(v2); v3 = bfly_sum(v3);
    if (lane == 0) {
        ws[OFF_S1 + n] = -0.5f * (v0 + v2);
        ws[OFF_S2 + n] = -0.5f * v1 - v3;
        float ld1 = -0.5f * v0;
        float ld2 = -0.5f * v1;
        int* cnts = (int*)(ws + OFF_SCAL);
        if (ld1 > PRUNE_CUT) atomicAdd(&cnts[13], 1);
        if (ld2 > PRUNE_CUT) {
            int idx = atomicAdd(&cnts[12], 1);
            ((int*)(ws + OFF_NLIST))[idx] = n;
        }
    }
}

__global__ __launch_bounds__(256) void k_psi1bc(
    const float* __restrict__ Z, const float* __restrict__ kern_var,
    float* __restrict__ ws)
{
    int tx = threadIdx.x & 15, ty = threadIdx.x >> 4;
    int n = blockIdx.x * 16 + ty;
    int m = blockIdx.y * 16 + tx;
    if (blockIdx.z == 0) {
        if (rd_cnt(ws, 13) == 0) return;
        __shared__ float Ps[16][17], Rs[16][17], Zs[16][17], Z2s[16][17];
        float dot1 = 0.0f, dot2 = 0.0f;
        for (int qc = 0; qc < 12; qc++) {
            int q0 = qc * 16;
            Ps[ty][tx] = (n < NR) ? ws[OFF_P1 + n * DIN + q0 + tx] : 0.0f;
            Rs[ty][tx] = (n < NR) ? ws[OFF_R1 + n * DIN + q0 + tx] : 0.0f;
            float z = Z[(blockIdx.y * 16 + ty) * DIN + q0 + tx];
            Zs[ty][tx] = z; Z2s[ty][tx] = z * z;
            __syncthreads();
            #pragma unroll
            for (int k = 0; k < 16; k++) {
                dot1 = fmaf(Ps[ty][k], Zs[tx][k], dot1);
                dot2 = fmaf(Rs[ty][k], Z2s[tx][k], dot2);
            }
            __syncthreads();
        }
        if (n < NR) {
            float kv = *kern_var;
            ws[OFF_PSI1 + n * MM + m] = kv * __expf(ws[OFF_S1 + n] + dot1 - 0.5f * dot2);
        }
    } else {
        if (rd_cnt(ws, 12) == 0) return;
        __shared__ float Us[16][17], Ws[16][17], Zb[16][17];
        float dotB = 0.0f, dotC = 0.0f;
        for (int qc = 0; qc < 12; qc++) {
            int q0 = qc * 16;
            Us[ty][tx] = (n < NR) ? ws[OFF_WU2 + n * DIN + q0 + tx] : 0.0f;
            Ws[ty][tx] = (n < NR) ? ws[OFF_W2  + n * DIN + q0 + tx] : 0.0f;
            Zb[ty][tx] = Z[(blockIdx.y * 16 + ty) * DIN + q0 + tx];
            __syncthreads();
            #pragma unroll
            for (int k = 0; k < 16; k++) {
                float z = Zb[tx][k];
                dotB = fmaf(z, Us[ty][k], dotB);
                dotC = fmaf(z * z, Ws[ty][k], dotC);
            }
            __syncthreads();
        }
        if (n < NR) ws[OFF_F + n * MM + m] = fmaf(-0.25f, dotC, dotB);
    }
}

__global__ __launch_bounds__(256) void k_gkuu(
    const float* __restrict__ Z, const float* __restrict__ kern_ls,
    const float* __restrict__ kern_var, const float* __restrict__ X_mean,
    float* __restrict__ ws)
{
    if (blockIdx.x < MM) {
        if (rd_cnt(ws, 13) == 0) return;
        int m = blockIdx.x, tid = threadIdx.x;
        const float* psi1 = ws + OFF_PSI1;
        float g[QD];
        #pragma unroll
        for (int d = 0; d < QD; d++) g[d] = 0.0f;
        for (int n = tid; n < NR; n += 256) {
            float p = psi1[n * MM + m];
            const float* xr = X_mean + (LT + n) * QD;
            #pragma unroll
            for (int d = 0; d < QD; d++) g[d] = fmaf(p, xr[d], g[d]);
        }
        __shared__ float red[256];
        bool any = false;
        for (int d = 0; d < QD; d++) {
            red[tid] = g[d]; __syncthreads();
            if (tid < 128) red[tid] += red[tid + 128];
            __syncthreads();
            if (tid < 64) {
                float s = red[tid] + red[tid + 64];
                s = wave_reduce(s);
                if (tid == 0) { ws[OFF_G + m * QD + d] = s; any |= (s != 0.0f); }
            }
            __syncthreads();
        }
        if (tid == 0 && any) atomicOr((int*)(ws + OFF_SCAL) + 14, 1);
    } else {
        if (rd_cnt(ws, 12) == 0 && rd_cnt(ws, 13) == 0) return;
        int kb = blockIdx.x - MM;
        int bx = kb / 12, by = kb - bx * 12;
        int ty = threadIdx.x >> 4, tx = threadIdx.x & 15;
        int m = bx * 16 + ty, p = by * 16 + tx;
        __shared__ float Zm[16][17], Zp[16][17];
        float d = 0.0f;
        for (int qc = 0; qc < 12; qc++) {
            int q0 = qc * 16;
            float inv_ls = 1.0f / kern_ls[q0 + tx];
            Zm[ty][tx] = Z[(bx * 16 + ty) * DIN + q0 + tx] * inv_ls;
            Zp[ty][tx] = Z[(by * 16 + ty) * DIN + q0 + tx] * inv_ls;
            __syncthreads();
            #pragma unroll
            for (int k = 0; k < 16; k++) {
                float t = Zm[ty][k] - Zp[tx][k];
                d = fmaf(t, t, d);
            }
            __syncthreads();
        }
        ws[OFF_D2ZZ + m * MM + p] = d;
        float kv = *kern_var;
        ws[OFF_KUU + m * MM + p] = kv * __expf(-0.5f * d) + ((m == p) ? JITTER : 0.0f);
    }
}

__global__ __launch_bounds__(256) void k_psi2(
    const float* __restrict__ Z, const float* __restrict__ kern_var,
    float* __restrict__ ws)
{
    int count = rd_cnt(ws, 12);
    int gflag = rd_cnt(ws, 14);
    int tx = threadIdx.x & 15, ty = threadIdx.x >> 4;
    int m0 = blockIdx.x * 32, p0 = blockIdx.y * 32;
    int mA = m0 + 2 * ty, pA = p0 + 2 * tx;
    float* P2 = ws + OFF_PSI2;
    if (count == 0) {
        if (gflag != 0) {
            P2[(mA    ) * MM + pA    ] = 0.0f;
            P2[(mA    ) * MM + pA + 1] = 0.0f;
            P2[(mA + 1) * MM + pA    ] = 0.0f;
            P2[(mA + 1) * MM + pA + 1] = 0.0f;
        }
        return;
    }
    float a00 = 0, a01 = 0, a10 = 0, a11 = 0;
    {
        __shared__ __align__(16) float Zm[32 * ZR], Zp[32 * ZR];
        for (int idx = threadIdx.x; idx < 32 * DIN; idx += 256) {
            int r = idx / DIN, q = idx - r * DIN;
            Zm[r * ZR + q] = Z[(m0 + r) * DIN + q];
            Zp[r * ZR + q] = Z[(p0 + r) * DIN + q];
        }
        __syncthreads();
        const float* w2base = ws + OFF_W2;
        const float* F      = ws + OFF_F;
        const float* s2arr  = ws + OFF_S2;
        const int* list     = (const int*)(ws + OFF_NLIST);
        const float4* zm0 = (const float4*)(Zm + (2 * ty    ) * ZR);
        const float4* zm1 = (const float4*)(Zm + (2 * ty + 1) * ZR);
        const float4* zp0 = (const float4*)(Zp + (2 * tx    ) * ZR);
        const float4* zp1 = (const float4*)(Zp + (2 * tx + 1) * ZR);
        for (int li = 0; li < count; li++) {
            int n = list[li];
            const float4* w2p = (const float4*)(w2base + n * DIN);
            float e00 = 0, e01 = 0, e10 = 0, e11 = 0;
            #pragma unroll 4
            for (int g = 0; g < DIN / 4; g++) {
                float4 w  = w2p[g];
                float4 a  = zm0[g], b = zm1[g], c = zp0[g], d = zp1[g];
                float wp0, wp1;
                wp0 = w.x * c.x; wp1 = w.x * d.x;
                e00 = fmaf(a.x, wp0, e00); e01 = fmaf(a.x, wp1, e01);
                e10 = fmaf(b.x, wp0, e10); e11 = fmaf(b.x, wp1, e11);
                wp0 = w.y * c.y; wp1 = w.y * d.y;
                e00 = fmaf(a.y, wp0, e00); e01 = fmaf(a.y, wp1, e01);
                e10 = fmaf(b.y, wp0, e10); e11 = fmaf(b.y, wp1, e11);
                wp0 = w.z * c.z; wp1 = w.z * d.z;
                e00 = fmaf(a.z, wp0, e00); e01 = fmaf(a.z, wp1, e01);
                e10 = fmaf(b.z, wp0, e10); e11 = fmaf(b.z, wp1, e11);
                wp0 = w.w * c.w; wp1 = w.w * d.w;
                e00 = fmaf(a.w, wp0, e00); e01 = fmaf(a.w, wp1, e01);
                e10 = fmaf(b.w, wp0, e10); e11 = fmaf(b.w, wp1, e11);
            }
            float s2n = s2arr[n];
            float Fm0 = F[n * MM + mA], Fm1 = F[n * MM + mA + 1];
            float Fp0 = F[n * MM + pA], Fp1 = F[n * MM + pA + 1];
            a00 += __expf(s2n + Fm0 + Fp0 - 0.5f * e00);
            a01 += __expf(s2n + Fm0 + Fp1 - 0.5f * e01);
            a10 += __expf(s2n + Fm1 + Fp0 - 0.5f * e10);
            a11 += __expf(s2n + Fm1 + Fp1 - 0.5f * e11);
        }
    }
    float kv = *kern_var; float kv2 = kv * kv;
    const float* dz = ws + OFF_D2ZZ;
    P2[(mA    ) * MM + pA    ] = kv2 * __expf(-0.25f * dz[(mA    ) * MM + pA    ]) * a00;
    P2[(mA    ) * MM + pA + 1] = kv2 * __expf(-0.25f * dz[(mA    ) * MM + pA + 1]) * a01;
    P2[(mA + 1) * MM + pA    ] = kv2 * __expf(-0.25f * dz[(mA + 1) * MM + pA    ]) * a10;
    P2[(mA + 1) * MM + pA + 1] = kv2 * __expf(-0.25f * dz[(mA + 1) * MM + pA + 1]) * a11;
}

__global__ __launch_bounds__(256) void k_chol2(float* __restrict__ ws,
                                               const float* __restrict__ lik)
{
    if (rd_cnt(ws, 12) == 0 && rd_cnt(ws, 14) == 0) return;
    __shared__ __align__(16) float A[MM * ALD];
    int tid = threadIdx.x;
    bool isC2 = (blockIdx.x == 1);
    const float* Kuu  = ws + OFF_KUU;
    const float* psi2 = ws + OFF_PSI2;
    float inv_s2 = 1.0f / (*lik);
    for (int idx = tid; idx < MM * MM; idx += 256) {
        int i = idx / MM, j = idx - i * MM;
        float v = Kuu[idx];
        if (isC2) v = fmaf(psi2[idx], inv_s2, v);
        A[i * ALD + j] = v;
    }
    __syncthreads();

    float logacc = 0.0f;
    int ty = tid >> 4, tx = tid & 15;
    for (int p = 0; p < MM / NB; p++) {
        int k0 = p * NB;
        int e  = k0 + NB;
        if (tid < 64) {
            int lane = tid;
            float P[3][NB];
            #pragma unroll
            for (int s = 0; s < 3; s++) {
                int r = lane + 64 * s;
                #pragma unroll
                for (int g = 0; g < NB / 4; g++) {
                    float4 v = *(const float4*)&A[r * ALD + k0 + 4 * g];
                    P[s][4*g] = v.x; P[s][4*g+1] = v.y; P[s][4*g+2] = v.z; P[s][4*g+3] = v.w;
                }
            }
            int sD = k0 >> 6;
            int lD = k0 & 63;
            #pragma unroll
            for (int c = 0; c < NB; c++) {
                int k = k0 + c;
                float colc = (sD == 0) ? P[0][c] : ((sD == 1) ? P[1][c] : P[2][c]);
                float dkk = __shfl(colc, lD + c);
                float inv = 1.0f / dkk;
                logacc += logf(dkk);
                float m0 = (lane       > k) ? P[0][c] * inv : 0.0f;
                float m1 = (lane + 64  > k) ? P[1][c] * inv : 0.0f;
                float m2 = (lane + 128 > k) ? P[2][c] * inv : 0.0f;
                P[0][c] = (lane       > k) ? m0 : P[0][c];
                P[1][c] = (lane + 64  > k) ? m1 : P[1][c];
                P[2][c] = (lane + 128 > k) ? m2 : P[2][c];
                #pragma unroll
                for (int j = c + 1; j < NB; j++) {
                    float w = __shfl(colc, lD + j);
                    P[0][j] = fmaf(-m0, w, P[0][j]);
                    P[1][j] = fmaf(-m1, w, P[1][j]);
                    P[2][j] = fmaf(-m2, w, P[2][j]);
                }
            }
            #pragma unroll
            for (int s = 0; s < 3; s++) {
                int r = lane + 64 * s;
                #pragma unroll
                for (int g = 0; g < NB / 4; g++) {
                    float4 v = make_float4(P[s][4*g], P[s][4*g+1], P[s][4*g+2], P[s][4*g+3]);
                    *(float4*)&A[r * ALD + k0 + 4 * g] = v;
                }
            }
        }
        __syncthreads();
        int T = MM - e;
        if (T > 0) {
            for (int idx = tid; idx < NB * T; idx += 256) {
                int c = idx / T, j = e + (idx - c * T);
                float d = A[(k0 + c) * ALD + (k0 + c)];
                A[(k0 + c) * ALD + j] = A[j * ALD + k0 + c] * sqrtf(d);
            }
            __syncthreads();
            int nT = (T + 127) / 128;
            for (int bi = 0; bi < nT; bi++)
            for (int bj = 0; bj < nT; bj++) {
                int i0 = e + 128 * bi + 8 * ty;
                int j0 = e + 128 * bj + 8 * tx;
                int ic = (i0 < MM - 8) ? i0 : (MM - 8);
                int jc = (j0 < MM - 8) ? j0 : (MM - 8);
                float4 acc[8][2];
                #pragma unroll
                for (int r = 0; r < 8; r++) {
                    acc[r][0] = *(const float4*)&A[(ic + r) * ALD + jc];
                    acc[r][1] = *(const float4*)&A[(ic + r) * ALD + jc + 4];
                }
                #pragma unroll 4
                for (int c = 0; c < NB; c++) {
                    const float* row = &A[(k0 + c) * ALD];
                    float4 av0 = *(const float4*)&row[ic];
                    float4 av1 = *(const float4*)&row[ic + 4];
                    float4 bv0 = *(const float4*)&row[jc];
                    float4 bv1 = *(const float4*)&row[jc + 4];
                    float avs[8] = {av0.x, av0.y, av0.z, av0.w, av1.x, av1.y, av1.z, av1.w};
                    #pragma unroll
                    for (int r = 0; r < 8; r++) {
                        float a = avs[r];
                        acc[r][0].x = fmaf(-a, bv0.x, acc[r][0].x);
                        acc[r][0].y = fmaf(-a, bv0.y, acc[r][0].y);
                        acc[r][0].z = fmaf(-a, bv0.z, acc[r][0].z);
                        acc[r][0].w = fmaf(-a, bv0.w, acc[r][0].w);
                        acc[r][1].x = fmaf(-a, bv1.x, acc[r][1].x);
                        acc[r][1].y = fmaf(-a, bv1.y, acc[r][1].y);
                        acc[r][1].z = fmaf(-a, bv1.z, acc[r][1].z);
                        acc[r][1].w = fmaf(-a, bv1.w, acc[r][1].w);
                    }
                }
                if (ic == i0 && jc == j0) {
                    #pragma unroll
                    for (int r = 0; r < 8; r++) {
                        *(float4*)&A[(i0 + r) * ALD + j0]     = acc[r][0];
                        *(float4*)&A[(i0 + r) * ALD + j0 + 4] = acc[r][1];
                    }
                }
            }
            __syncthreads();
        }
    }
    float* dst = ws + (isC2 ? OFF_LC2 : OFF_LC);
    for (int idx = tid; idx < MM * MM; idx += 256) {
        int i = idx / MM, j = idx - i * MM;
        dst[idx] = A[i * ALD + j];
    }
    if (tid == 0) ws[OFF_SCAL + (isC2 ? 8 : 7)] = 0.5f * logacc;
}

__global__ __launch_bounds__(64) void k_trinvsolve(float* __restrict__ ws)
{
    if (blockIdx.x < MM) {
        if (rd_cnt(ws, 12) == 0) return;
        const float* L = ws + OFF_LC;
        float* V = ws + OFF_V;
        int j = blockIdx.x, l = threadIdx.x;
        int k0 = j + l, k1 = k0 + 64, k2 = k0 + 128;
        float x0 = 0, x1 = 0, x2 = 0;
        for (int i = j; i < MM; i++) {
            const float* Lr = L + i * MM;
            float s = 0.0f;
            if (k0 < i) s = fmaf(Lr[k0], x0, s);
            if (k1 < i) s = fmaf(Lr[k1], x1, s);
            if (k2 < i) s = fmaf(Lr[k2], x2, s);
            #pragma unroll
            for (int off = 1; off < 64; off <<= 1) s += __shfl_xor(s, off);
            float xi = ((i == j) ? 1.0f : 0.0f) - s;
            if (k0 == i) x0 = xi;
            if (k1 == i) x1 = xi;
            if (k2 == i) x2 = xi;
            if (l == 0) V[i * MM + j] = xi;
        }
    } else {
        if (rd_cnt(ws, 14) == 0) return;
        const float* L = ws + OFF_LC2;
        const float* G = ws + OFF_G;
        int c = blockIdx.x - MM, l = threadIdx.x;
        int k0 = l, k1 = l + 64, k2 = l + 128;
        float x0 = 0, x1 = 0, x2 = 0, ss = 0;
        for (int i = 0; i < MM; i++) {
            const float* Lr = L + i * MM;
            float s = 0.0f;
            if (k0 < i) s = fmaf(Lr[k0], x0, s);
            if (k1 < i) s = fmaf(Lr[k1], x1, s);
            if (k2 < i) s = fmaf(Lr[k2], x2, s);
            #pragma unroll
            for (int off = 1; off < 64; off <<= 1) s += __shfl_xor(s, off);
            float xi = G[i * QD + c] - s;
            if (k0 == i) x0 = xi;
            if (k1 == i) x1 = xi;
            if (k2 == i) x2 = xi;
            if (l == 0) ss += xi * xi / Lr[i];
        }
        if (l == 0) atomicAdd(&ws[OFF_SCAL + 2], ss);
    }
}

__global__ __launch_bounds__(256) void k_tracedot(float* __restrict__ ws)
{
    if (rd_cnt(ws, 12) == 0) return;
    int i = blockIdx.x, tid = threadIdx.x;
    __shared__ float vrow[MM];
    const float* V = ws + OFF_V;
    const float* P = ws + OFF_PSI2;
    for (int a = tid; a < MM; a += 256) vrow[a] = (a <= i) ? V[i * MM + a] : 0.0f;
    __syncthreads();
    float acc = 0.0f;
    for (int a = tid; a <= i; a += 256) {
        const float* Pr = P + a * MM;
        float inner = 0.0f;
        for (int b = 0; b <= i; b++) inner = fmaf(Pr[b], vrow[b], inner);
        acc = fmaf(vrow[a], inner, acc);
    }
    __shared__ float red[256];
    red[tid] = acc; __syncthreads();
    if (tid < 128) red[tid] += red[tid + 128];
    __syncthreads();
    if (tid < 64) {
        float s = red[tid] + red[tid + 64];
        s = wave_reduce(s);
        if (tid == 0) {
            float di = ws[OFF_LC + i * MM + i];
            atomicAdd(&ws[OFF_SCAL + 0], s / di);
        }
    }
}

#define SF_BLOCKS 72
__global__ __launch_bounds__(256) void k_sumsfinal(
    const float* __restrict__ X_mean, const float* __restrict__ X_var,
    const float* __restrict__ kern_var, const float* __restrict__ lik,
    float* __restrict__ ws, float* __restrict__ out)
{
    int idx = blockIdx.x * 256 + threadIdx.x;
    float pVo = 0, pMo = 0, pLg = 0, pMb = 0;
    if (idx < NTT * QD) {
        float xm = X_mean[idx], xv = X_var[idx];
        if (idx >= LT * QD) { pVo = xv; pMo = xm * xm; pLg = logf(xv); }
        else                { pMb = xm * xm + xv; }
    }
    pVo = bfly_sum(pVo); pMo = bfly_sum(pMo); pLg = bfly_sum(pLg); pMb = bfly_sum(pMb);
    __shared__ float part[4][4];
    if ((threadIdx.x & 63) == 0) {
        int w = threadIdx.x >> 6;
        part[w][0] = pVo; part[w][1] = pMo; part[w][2] = pLg; part[w][3] = pMb;
    }
    __syncthreads();
    __shared__ int amLast;
    if (threadIdx.x == 0) {
        #pragma unroll
        for (int t = 0; t < 4; t++)
            atomicAdd(&ws[OFF_SCAL + 3 + t],
                      part[0][t] + part[1][t] + part[2][t] + part[3][t]);
        __threadfence();
        int tkt = atomicAdd((int*)(ws + OFF_SCAL) + 15, 1);
        amLast = (tkt == SF_BLOCKS - 1);
    }
    __syncthreads();
    if (!amLast || threadIdx.x != 0) return;

    float trRaw = atomicAdd(&ws[OFF_SCAL + 0], 0.0f);
    float ssY   = atomicAdd(&ws[OFF_SCAL + 2], 0.0f);
    float Svo   = atomicAdd(&ws[OFF_SCAL + 3], 0.0f);
    float Smo2  = atomicAdd(&ws[OFF_SCAL + 4], 0.0f);
    float Slog  = atomicAdd(&ws[OFF_SCAL + 5], 0.0f);
    float Smb   = atomicAdd(&ws[OFF_SCAL + 6], 0.0f);
    float ldK   = atomicAdd(&ws[OFF_SCAL + 7], 0.0f);
    float ldC2  = atomicAdd(&ws[OFF_SCAL + 8], 0.0f);
    float kv = *kern_var, s2v = *lik;
    float inv_s2 = 1.0f / s2v;
    const float lp2pi = 1.8378770664093453f;
    float trA = trRaw * inv_s2;
    float ldB = 2.0f * (ldC2 - ldK);
    float sc2 = ssY * inv_s2 * inv_s2;
    float ND = 18000.0f;
    float Df = 12.0f;
    float bound = -0.5f * ND * (lp2pi + logf(s2v));
    bound += -0.5f * inv_s2 * (Svo + Smo2);
    bound += -0.5f * Df * ((kv * 1500.0f) * inv_s2 - trA);
    bound += -0.5f * Df * ldB;
    bound += 0.5f * sc2;
    bound += 0.5f * Slog + 0.5f * ND * lp2pi;
    bound += -96.0f * lp2pi - 0.5f * Smb;
    out[0] = bound;
}

extern "C" void kernel_launch(void* const* d_in, const int* in_sizes, int n_in,
                              void* d_out, int out_size, void* d_ws, size_t ws_size,
                              hipStream_t stream)
{
    const float* Xm_m    = (const float*)d_in[1];
    const float* Xm_v    = (const float*)d_in[2];
    const float* Z       = (const float*)d_in[3];
    const float* X_mean  = (const float*)d_in[4];
    const float* X_var   = (const float*)d_in[5];
    const float* kern_var= (const float*)d_in[6];
    const float* kern_ls = (const float*)d_in[7];
    const float* lik_var = (const float*)d_in[8];
    float* ws  = (float*)d_ws;
    float* out = (float*)d_out;

    // zero G + scalar slots/flags/ticket (contiguous region)
    hipMemsetAsync(ws + OFF_G, 0, (MM * QD + 16) * sizeof(float), stream);

    void* kArgs[] = { (void*)&Xm_m, (void*)&Xm_v, (void*)&Z, (void*)&X_mean,
                      (void*)&X_var, (void*)&kern_var, (void*)&kern_ls,
                      (void*)&lik_var, (void*)&ws, (void*)&out };
    hipError_t cerr = hipLaunchCooperativeKernel((const void*)k_fused,
                                                 dim3(FGRID), dim3(256),
                                                 kArgs, 0, stream);
    if (cerr != hipSuccess) {
        (void)hipGetLastError();   // clear sticky error, fall back to chain
        k_prep<<<NR / 4, 256, 0, stream>>>(Xm_m, Xm_v, X_mean, X_var, kern_ls, ws);
        k_psi1bc<<<dim3(94, 12, 2), 256, 0, stream>>>(Z, kern_var, ws);
        k_gkuu<<<MM + 144, 256, 0, stream>>>(Z, kern_ls, kern_var, X_mean, ws);
        k_psi2<<<dim3(6, 6), 256, 0, stream>>>(Z, kern_var, ws);
        k_chol2<<<2, 256, 0, stream>>>(ws, lik_var);
        k_trinvsolve<<<MM + QD, 64, 0, stream>>>(ws);
        k_tracedot<<<MM, 256, 0, stream>>>(ws);
        k_sumsfinal<<<SF_BLOCKS, 256, 0, stream>>>(X_mean, X_var, kern_var, lik_var, ws, out);
    }
}

// Round 2
// 115.422 us; speedup vs baseline: 1.1387x; 1.1387x over previous
//
#include <hip/hip_runtime.h>
#include <math.h>

// Problem dims (fixed by setup_inputs)
#define NR   1500     // rows of X_m  (Nt - Lt)
#define NTT  1508     // Nt
#define QD   12       // D
#define LT   8
#define DIN  192      // 2*Lt*Q
#define MM   192      // M
#define JITTER 1e-6f
// Exact per-row suprema: psi1 expo <= logdet1[n], psi2 expo <= logdet2[n].
// Rows below this cut contribute < e^-30 ~ 1e-13 each -> provably < 1e-6 relative.
#define PRUNE_CUT -30.0f

// ---- workspace layout (float offsets) ----
#define OFF_W2    0
#define OFF_WU2   288000
#define OFF_P1    576000
#define OFF_R1    864000
#define OFF_S1    1152000
#define OFF_S2    1153500
#define OFF_V     1155000
#define OFF_D2ZZ  1191864
#define OFF_KUU   1228728
#define OFF_PSI1  1265592
#define OFF_PSI2  1553592
#define OFF_LC    1590456
#define OFF_LC2   1627320
#define OFF_G     1664184
#define OFF_SCAL  1666488     // 16 floats
#define OFF_BAR   1666504     // 8 ints: [0]=cnt, [1]=gen (zeroed by memset)
#define OFF_NLIST 1666512     // 1500 ints: surviving-n list for psi2
#define OFF_BSUM  1668016     // 256 blocks x 4 per-block input-sum partials
#define OFF_F     1670016     // 288000 floats (de-aliased from P1)
#define OFF_CHA   1958016     // 2 x MM*ALD global scratch for Phase D chol
// scal slots: 0 trace_raw, 2 ||Y||^2, 7 0.5*logdetKuu, 8 0.5*logdetC2,
//             12 cnt2 (psi2 survivors), 13 cnt1 (psi1 survivors), 14 gflag

#define LDWSF(p)   __hip_atomic_load((p), __ATOMIC_RELAXED, __HIP_MEMORY_SCOPE_AGENT)
#define LDWSI(p)   __hip_atomic_load((p), __ATOMIC_RELAXED, __HIP_MEMORY_SCOPE_AGENT)
#define STWSF(p,v) __hip_atomic_store((p), (v), __ATOMIC_RELAXED, __HIP_MEMORY_SCOPE_AGENT)

__device__ __forceinline__ float wave_reduce(float s) {
    s += __shfl_down(s, 32); s += __shfl_down(s, 16); s += __shfl_down(s, 8);
    s += __shfl_down(s, 4);  s += __shfl_down(s, 2);  s += __shfl_down(s, 1);
    return s;
}
__device__ __forceinline__ float bfly_sum(float s) {
    s += __shfl_xor(s, 32); s += __shfl_xor(s, 16); s += __shfl_xor(s, 8);
    s += __shfl_xor(s, 4);  s += __shfl_xor(s, 2);  s += __shfl_xor(s, 1);
    return s;
}

// Hand-rolled grid barrier (graph-capturable, unlike hipLaunchCooperativeKernel).
// State (cnt, gen) zeroed by the memset node before every replay. All blocks
// are co-resident: grid=256 <= 256 CUs, ~49KB LDS -> >=1 block/CU capacity,
// device idle during replay, so the spin cannot deadlock.
__device__ __forceinline__ void grid_sync(float* ws) {
    __syncthreads();
    if (threadIdx.x == 0) {
        __threadfence();   // device-scope: publish prior writes across XCD L2s
        int* bar = (int*)(ws + OFF_BAR);
        int g = __hip_atomic_load(&bar[1], __ATOMIC_RELAXED, __HIP_MEMORY_SCOPE_AGENT);
        int t = __hip_atomic_fetch_add(&bar[0], 1, __ATOMIC_ACQ_REL, __HIP_MEMORY_SCOPE_AGENT);
        if (t == (int)gridDim.x - 1) {
            __hip_atomic_store(&bar[0], 0, __ATOMIC_RELAXED, __HIP_MEMORY_SCOPE_AGENT);
            __hip_atomic_store(&bar[1], g + 1, __ATOMIC_RELEASE, __HIP_MEMORY_SCOPE_AGENT);
        } else {
            while (__hip_atomic_load(&bar[1], __ATOMIC_ACQUIRE, __HIP_MEMORY_SCOPE_AGENT) == g)
                __builtin_amdgcn_s_sleep(1);
        }
        __threadfence();
    }
    __syncthreads();
}

#define ALD 196
#define NB  32
#define ZR  196
#define FGRID 256

// ============================================================================
// Fused kernel: the whole dependency chain in ONE ordinary dispatch.
// Fast path (cnt1==cnt2==0, true for the bench data): prep+sums -> 1 grid
// sync -> final assembly. Slow path keeps all phases, separated by grid syncs.
// Phase D (chol) uses global-ws scratch so static LDS stays at 49 KB.
// ============================================================================
__global__ __launch_bounds__(256) void k_fused(
    const float* __restrict__ Xm_m, const float* __restrict__ Xm_v,
    const float* __restrict__ Z, const float* __restrict__ X_mean,
    const float* __restrict__ X_var, const float* __restrict__ kern_var,
    const float* __restrict__ kern_ls, const float* __restrict__ lik,
    float* __restrict__ ws, float* __restrict__ out)
{
    __shared__ __align__(16) float smem[2 * 32 * ZR];   // 49 KB, union for all phases
    const int tid  = threadIdx.x;
    const int lane = tid & 63;
    const int wav  = tid >> 6;
    const int nblk = gridDim.x;
    const int ty4  = tid >> 4, tx4 = tid & 15;

    // ---------------- Phase A: per-n prep + input sums ----------------
    for (int n = blockIdx.x * 4 + wav; n < NR; n += nblk * 4) {
        float v0 = 0, v1 = 0, v2 = 0, v3 = 0;
        #pragma unroll
        for (int s = 0; s < 3; s++) {
            int q = lane + 64 * s;
            float u, v;
            if (q < 96) { u = X_mean[n * QD + q]; v = X_var[n * QD + q]; }
            else        { int j = q - 96; u = Xm_m[(1 + n) * QD + j]; v = Xm_v[(1 + n) * QD + j]; }
            float ls = kern_ls[q]; float l2 = ls * ls;
            float d1 = l2 + v, d2 = l2 + 2.0f * v;
            float i1 = 1.0f / d1, i2 = 1.0f / d2;
            ws[OFF_P1  + n * DIN + q] = u * i1;
            ws[OFF_R1  + n * DIN + q] = i1;
            ws[OFF_W2  + n * DIN + q] = i2;
            ws[OFF_WU2 + n * DIN + q] = u * i2;
            v0 += log1pf(v / l2);
            v1 += log1pf(2.0f * v / l2);
            v2 += u * u * i1;
            v3 += u * u * i2;
        }
        v0 = bfly_sum(v0); v1 = bfly_sum(v1); v2 = bfly_sum(v2); v3 = bfly_sum(v3);
        if (lane == 0) {
            ws[OFF_S1 + n] = -0.5f * (v0 + v2);
            ws[OFF_S2 + n] = -0.5f * v1 - v3;
            float ld1 = -0.5f * v0;                // exact sup of psi1 exponent
            float ld2 = -0.5f * v1;                // exact sup of psi2 exponent
            int* cnts = (int*)(ws + OFF_SCAL);
            if (ld1 > PRUNE_CUT) atomicAdd(&cnts[13], 1);
            if (ld2 > PRUNE_CUT) {
                int idx = atomicAdd(&cnts[12], 1);
                ((int*)(ws + OFF_NLIST))[idx] = n;
            }
        }
    }
    {   // input sums (Svo, Smo2, Slog, Smb) -> per-block partials, no atomics
        float pVo = 0, pMo = 0, pLg = 0, pMb = 0;
        for (int idx = blockIdx.x * 256 + tid; idx < NTT * QD; idx += nblk * 256) {
            float xm = X_mean[idx], xv = X_var[idx];
            if (idx >= LT * QD) { pVo += xv; pMo += xm * xm; pLg += logf(xv); }
            else                { pMb += xm * xm + xv; }
        }
        pVo = bfly_sum(pVo); pMo = bfly_sum(pMo); pLg = bfly_sum(pLg); pMb = bfly_sum(pMb);
        float* part = smem;   // 16 floats
        if (lane == 0) { part[wav*4+0] = pVo; part[wav*4+1] = pMo; part[wav*4+2] = pLg; part[wav*4+3] = pMb; }
        __syncthreads();
        if (tid < 4) {
            float s = part[tid] + part[4 + tid] + part[8 + tid] + part[12 + tid];
            STWSF(&ws[OFF_BSUM + blockIdx.x * 4 + tid], s);
        }
        __syncthreads();
    }
    grid_sync(ws);

    const int* scal_i = (const int*)(ws + OFF_SCAL);
    const int cnt1 = LDWSI(scal_i + 13);
    const int cnt2 = LDWSI(scal_i + 12);

    if ((cnt1 | cnt2) != 0) {
        // =================== SLOW PATH (not exercised by bench data) =========
        float kv = *kern_var;
        // -------- Phase B: Kuu/d2zz tiles + psi1 tiles + F tiles --------
        for (int vb = blockIdx.x; vb < 144 + 2 * 1128; vb += nblk) {
            if (vb < 144) {
                int bx = vb / 12, by = vb - bx * 12;
                float (*Zm)[17] = (float(*)[17])smem;
                float (*Zp)[17] = (float(*)[17])(smem + 272);
                int m = bx * 16 + ty4, p = by * 16 + tx4;
                float d = 0.0f;
                for (int qc = 0; qc < 12; qc++) {
                    int q0 = qc * 16;
                    float inv_ls = 1.0f / kern_ls[q0 + tx4];
                    Zm[ty4][tx4] = Z[(bx * 16 + ty4) * DIN + q0 + tx4] * inv_ls;
                    Zp[ty4][tx4] = Z[(by * 16 + ty4) * DIN + q0 + tx4] * inv_ls;
                    __syncthreads();
                    #pragma unroll
                    for (int k = 0; k < 16; k++) { float t = Zm[ty4][k] - Zp[tx4][k]; d = fmaf(t, t, d); }
                    __syncthreads();
                }
                ws[OFF_D2ZZ + m * MM + p] = d;
                ws[OFF_KUU  + m * MM + p] = kv * __expf(-0.5f * d) + ((m == p) ? JITTER : 0.0f);
            } else if (vb < 144 + 1128) {
                if (cnt1 != 0) {
                    int t = vb - 144, bx = t % 94, by = t / 94;
                    int n = bx * 16 + ty4, m = by * 16 + tx4;
                    float (*Ps)[17]  = (float(*)[17])smem;
                    float (*Rs)[17]  = (float(*)[17])(smem + 272);
                    float (*Zs)[17]  = (float(*)[17])(smem + 544);
                    float (*Z2s)[17] = (float(*)[17])(smem + 816);
                    float dot1 = 0.0f, dot2 = 0.0f;
                    for (int qc = 0; qc < 12; qc++) {
                        int q0 = qc * 16;
                        Ps[ty4][tx4] = (n < NR) ? ws[OFF_P1 + n * DIN + q0 + tx4] : 0.0f;
                        Rs[ty4][tx4] = (n < NR) ? ws[OFF_R1 + n * DIN + q0 + tx4] : 0.0f;
                        float z = Z[(by * 16 + ty4) * DIN + q0 + tx4];
                        Zs[ty4][tx4] = z; Z2s[ty4][tx4] = z * z;
                        __syncthreads();
                        #pragma unroll
                        for (int k = 0; k < 16; k++) {
                            dot1 = fmaf(Ps[ty4][k], Zs[tx4][k], dot1);
                            dot2 = fmaf(Rs[ty4][k], Z2s[tx4][k], dot2);
                        }
                        __syncthreads();
                    }
                    if (n < NR) ws[OFF_PSI1 + n * MM + m] = kv * __expf(ws[OFF_S1 + n] + dot1 - 0.5f * dot2);
                }
            } else {
                if (cnt2 != 0) {
                    int t = vb - (144 + 1128), bx = t % 94, by = t / 94;
                    int n = bx * 16 + ty4, m = by * 16 + tx4;
                    float (*Us)[17] = (float(*)[17])smem;
                    float (*Ws)[17] = (float(*)[17])(smem + 272);
                    float (*Zb)[17] = (float(*)[17])(smem + 544);
                    float dotB = 0.0f, dotC = 0.0f;
                    for (int qc = 0; qc < 12; qc++) {
                        int q0 = qc * 16;
                        Us[ty4][tx4] = (n < NR) ? ws[OFF_WU2 + n * DIN + q0 + tx4] : 0.0f;
                        Ws[ty4][tx4] = (n < NR) ? ws[OFF_W2  + n * DIN + q0 + tx4] : 0.0f;
                        Zb[ty4][tx4] = Z[(by * 16 + ty4) * DIN + q0 + tx4];
                        __syncthreads();
                        #pragma unroll
                        for (int k = 0; k < 16; k++) {
                            float z = Zb[tx4][k];
                            dotB = fmaf(z, Us[ty4][k], dotB);
                            dotC = fmaf(z * z, Ws[ty4][k], dotC);
                        }
                        __syncthreads();
                    }
                    if (n < NR) ws[OFF_F + n * MM + m] = fmaf(-0.25f, dotC, dotB);
                }
            }
        }
        grid_sync(ws);
        // -------- Phase C: G rows + psi2 tiles (or exact-zero fill) --------
        for (int vb = blockIdx.x; vb < 192 + 36; vb += nblk) {
            if (vb < 192) {
                if (cnt1 != 0) {
                    int m = vb;
                    const float* psi1 = ws + OFF_PSI1;
                    float g[QD];
                    #pragma unroll
                    for (int d = 0; d < QD; d++) g[d] = 0.0f;
                    for (int n = tid; n < NR; n += 256) {
                        float p = psi1[n * MM + m];
                        const float* xr = X_mean + (LT + n) * QD;
                        #pragma unroll
                        for (int d = 0; d < QD; d++) g[d] = fmaf(p, xr[d], g[d]);
                    }
                    float* red = smem;   // 256 floats
                    bool any = false;
                    for (int d = 0; d < QD; d++) {
                        red[tid] = g[d]; __syncthreads();
                        if (tid < 128) red[tid] += red[tid + 128];
                        __syncthreads();
                        if (tid < 64) {
                            float s = red[tid] + red[tid + 64];
                            s = wave_reduce(s);
                            if (tid == 0) { ws[OFF_G + m * QD + d] = s; any |= (s != 0.0f); }
                        }
                        __syncthreads();
                    }
                    if (tid == 0 && any) atomicOr((int*)(ws + OFF_SCAL) + 14, 1);
                }
            } else {
                int t = vb - 192, bx = t / 6, by = t - 6 * bx;
                int m0 = bx * 32, p0 = by * 32;
                int mA = m0 + 2 * ty4, pA = p0 + 2 * tx4;
                float* P2 = ws + OFF_PSI2;
                if (cnt2 == 0) {   // slow path => cnt1>0; chol-C2 may read psi2
                    P2[(mA    ) * MM + pA    ] = 0.0f;
                    P2[(mA    ) * MM + pA + 1] = 0.0f;
                    P2[(mA + 1) * MM + pA    ] = 0.0f;
                    P2[(mA + 1) * MM + pA + 1] = 0.0f;
                    __syncthreads();
                } else {
                    float a00 = 0, a01 = 0, a10 = 0, a11 = 0;
                    float* Zm = smem;             // 32*ZR
                    float* Zp = smem + 32 * ZR;   // 32*ZR
                    for (int idx = tid; idx < 32 * DIN; idx += 256) {
                        int r = idx / DIN, q = idx - r * DIN;
                        Zm[r * ZR + q] = Z[(m0 + r) * DIN + q];
                        Zp[r * ZR + q] = Z[(p0 + r) * DIN + q];
                    }
                    __syncthreads();
                    const float* w2base = ws + OFF_W2;
                    const float* F      = ws + OFF_F;
                    const float* s2arr  = ws + OFF_S2;
                    const int* list     = (const int*)(ws + OFF_NLIST);
                    const float4* zm0 = (const float4*)(Zm + (2 * ty4    ) * ZR);
                    const float4* zm1 = (const float4*)(Zm + (2 * ty4 + 1) * ZR);
                    const float4* zp0 = (const float4*)(Zp + (2 * tx4    ) * ZR);
                    const float4* zp1 = (const float4*)(Zp + (2 * tx4 + 1) * ZR);
                    for (int li = 0; li < cnt2; li++) {
                        int n = list[li];
                        const float4* w2p = (const float4*)(w2base + n * DIN);
                        float e00 = 0, e01 = 0, e10 = 0, e11 = 0;
                        #pragma unroll 4
                        for (int g = 0; g < DIN / 4; g++) {
                            float4 w = w2p[g];
                            float4 a = zm0[g], b = zm1[g], c = zp0[g], d = zp1[g];
                            float wp0, wp1;
                            wp0 = w.x * c.x; wp1 = w.x * d.x;
                            e00 = fmaf(a.x, wp0, e00); e01 = fmaf(a.x, wp1, e01);
                            e10 = fmaf(b.x, wp0, e10); e11 = fmaf(b.x, wp1, e11);
                            wp0 = w.y * c.y; wp1 = w.y * d.y;
                            e00 = fmaf(a.y, wp0, e00); e01 = fmaf(a.y, wp1, e01);
                            e10 = fmaf(b.y, wp0, e10); e11 = fmaf(b.y, wp1, e11);
                            wp0 = w.z * c.z; wp1 = w.z * d.z;
                            e00 = fmaf(a.z, wp0, e00); e01 = fmaf(a.z, wp1, e01);
                            e10 = fmaf(b.z, wp0, e10); e11 = fmaf(b.z, wp1, e11);
                            wp0 = w.w * c.w; wp1 = w.w * d.w;
                            e00 = fmaf(a.w, wp0, e00); e01 = fmaf(a.w, wp1, e01);
                            e10 = fmaf(b.w, wp0, e10); e11 = fmaf(b.w, wp1, e11);
                        }
                        float s2n = s2arr[n];
                        float Fm0 = F[n * MM + mA], Fm1 = F[n * MM + mA + 1];
                        float Fp0 = F[n * MM + pA], Fp1 = F[n * MM + pA + 1];
                        a00 += __expf(s2n + Fm0 + Fp0 - 0.5f * e00);
                        a01 += __expf(s2n + Fm0 + Fp1 - 0.5f * e01);
                        a10 += __expf(s2n + Fm1 + Fp0 - 0.5f * e10);
                        a11 += __expf(s2n + Fm1 + Fp1 - 0.5f * e11);
                    }
                    float kv2 = kv * kv;
                    const float* dz = ws + OFF_D2ZZ;
                    P2[(mA    ) * MM + pA    ] = kv2 * __expf(-0.25f * dz[(mA    ) * MM + pA    ]) * a00;
                    P2[(mA    ) * MM + pA + 1] = kv2 * __expf(-0.25f * dz[(mA    ) * MM + pA + 1]) * a01;
                    P2[(mA + 1) * MM + pA    ] = kv2 * __expf(-0.25f * dz[(mA + 1) * MM + pA    ]) * a10;
                    P2[(mA + 1) * MM + pA + 1] = kv2 * __expf(-0.25f * dz[(mA + 1) * MM + pA + 1]) * a11;
                    __syncthreads();
                }
            }
        }
        grid_sync(ws);
        const int gflag = LDWSI((const int*)(ws + OFF_SCAL) + 14);
        // -------- Phase D: dual blocked LDL^T in GLOBAL scratch --------
        if (blockIdx.x < 2 && (cnt2 != 0 || gflag != 0)) {
            bool isC2 = (blockIdx.x == 1);
            float* A = ws + OFF_CHA + (size_t)blockIdx.x * (MM * ALD);
            const float* Kuu  = ws + OFF_KUU;
            const float* psi2 = ws + OFF_PSI2;
            float inv_s2 = 1.0f / (*lik);
            for (int idx = tid; idx < MM * MM; idx += 256) {
                int i = idx / MM, j = idx - i * MM;
                float v = Kuu[idx];
                if (isC2) v = fmaf(psi2[idx], inv_s2, v);
                A[i * ALD + j] = v;
            }
            __syncthreads();
            float logacc = 0.0f;
            for (int p = 0; p < MM / NB; p++) {
                int k0 = p * NB;
                int e  = k0 + NB;
                if (tid < 64) {
                    int l64 = tid;
                    float P[3][NB];
                    #pragma unroll
                    for (int s = 0; s < 3; s++) {
                        int r = l64 + 64 * s;
                        #pragma unroll
                        for (int g = 0; g < NB / 4; g++) {
                            float4 v = *(const float4*)&A[r * ALD + k0 + 4 * g];
                            P[s][4*g] = v.x; P[s][4*g+1] = v.y; P[s][4*g+2] = v.z; P[s][4*g+3] = v.w;
                        }
                    }
                    int sD = k0 >> 6;
                    int lD = k0 & 63;
                    #pragma unroll
                    for (int c = 0; c < NB; c++) {
                        int k = k0 + c;
                        float colc = (sD == 0) ? P[0][c] : ((sD == 1) ? P[1][c] : P[2][c]);
                        float dkk = __shfl(colc, lD + c);
                        float inv = 1.0f / dkk;
                        logacc += logf(dkk);
                        float m0 = (l64       > k) ? P[0][c] * inv : 0.0f;
                        float m1 = (l64 + 64  > k) ? P[1][c] * inv : 0.0f;
                        float m2 = (l64 + 128 > k) ? P[2][c] * inv : 0.0f;
                        P[0][c] = (l64       > k) ? m0 : P[0][c];
                        P[1][c] = (l64 + 64  > k) ? m1 : P[1][c];
                        P[2][c] = (l64 + 128 > k) ? m2 : P[2][c];
                        #pragma unroll
                        for (int j = c + 1; j < NB; j++) {
                            float w = __shfl(colc, lD + j);
                            P[0][j] = fmaf(-m0, w, P[0][j]);
                            P[1][j] = fmaf(-m1, w, P[1][j]);
                            P[2][j] = fmaf(-m2, w, P[2][j]);
                        }
                    }
                    #pragma unroll
                    for (int s = 0; s < 3; s++) {
                        int r = l64 + 64 * s;
                        #pragma unroll
                        for (int g = 0; g < NB / 4; g++) {
                            float4 v = make_float4(P[s][4*g], P[s][4*g+1], P[s][4*g+2], P[s][4*g+3]);
                            *(float4*)&A[r * ALD + k0 + 4 * g] = v;
                        }
                    }
                }
                __syncthreads();
                int T = MM - e;
                if (T > 0) {
                    for (int idx = tid; idx < NB * T; idx += 256) {
                        int c = idx / T, j = e + (idx - c * T);
                        float d = A[(k0 + c) * ALD + (k0 + c)];
                        A[(k0 + c) * ALD + j] = A[j * ALD + k0 + c] * sqrtf(d);
                    }
                    __syncthreads();
                    int nT = (T + 127) / 128;
                    for (int bi = 0; bi < nT; bi++)
                    for (int bj = 0; bj < nT; bj++) {
                        int i0 = e + 128 * bi + 8 * ty4;
                        int j0 = e + 128 * bj + 8 * tx4;
                        int ic = (i0 < MM - 8) ? i0 : (MM - 8);
                        int jc = (j0 < MM - 8) ? j0 : (MM - 8);
                        float4 acc[8][2];
                        #pragma unroll
                        for (int r = 0; r < 8; r++) {
                            acc[r][0] = *(const float4*)&A[(ic + r) * ALD + jc];
                            acc[r][1] = *(const float4*)&A[(ic + r) * ALD + jc + 4];
                        }
                        #pragma unroll 4
                        for (int c = 0; c < NB; c++) {
                            const float* row = &A[(k0 + c) * ALD];
                            float4 av0 = *(const float4*)&row[ic];
                            float4 av1 = *(const float4*)&row[ic + 4];
                            float4 bv0 = *(const float4*)&row[jc];
                            float4 bv1 = *(const float4*)&row[jc + 4];
                            float avs[8] = {av0.x, av0.y, av0.z, av0.w, av1.x, av1.y, av1.z, av1.w};
                            #pragma unroll
                            for (int r = 0; r < 8; r++) {
                                float a = avs[r];
                                acc[r][0].x = fmaf(-a, bv0.x, acc[r][0].x);
                                acc[r][0].y = fmaf(-a, bv0.y, acc[r][0].y);
                                acc[r][0].z = fmaf(-a, bv0.z, acc[r][0].z);
                                acc[r][0].w = fmaf(-a, bv0.w, acc[r][0].w);
                                acc[r][1].x = fmaf(-a, bv1.x, acc[r][1].x);
                                acc[r][1].y = fmaf(-a, bv1.y, acc[r][1].y);
                                acc[r][1].z = fmaf(-a, bv1.z, acc[r][1].z);
                                acc[r][1].w = fmaf(-a, bv1.w, acc[r][1].w);
                            }
                        }
                        if (ic == i0 && jc == j0) {
                            #pragma unroll
                            for (int r = 0; r < 8; r++) {
                                *(float4*)&A[(i0 + r) * ALD + j0]     = acc[r][0];
                                *(float4*)&A[(i0 + r) * ALD + j0 + 4] = acc[r][1];
                            }
                        }
                    }
                    __syncthreads();
                }
            }
            float* dst = ws + (isC2 ? OFF_LC2 : OFF_LC);
            for (int idx = tid; idx < MM * MM; idx += 256) {
                int i = idx / MM, j = idx - i * MM;
                dst[idx] = A[i * ALD + j];
            }
            if (tid == 0) STWSF(&ws[OFF_SCAL + (isC2 ? 8 : 7)], 0.5f * logacc);
        }
        grid_sync(ws);
        // -------- Phase E: triangular solves (wave-per-column) --------
        for (int u = blockIdx.x * 4 + wav; u < MM + QD; u += nblk * 4) {
            if (u < MM) {
                if (cnt2 != 0) {
                    const float* L = ws + OFF_LC;
                    float* V = ws + OFF_V;
                    int j = u;
                    int k0 = j + lane, k1 = k0 + 64, k2 = k0 + 128;
                    float x0 = 0, x1 = 0, x2 = 0;
                    for (int i = j; i < MM; i++) {
                        const float* Lr = L + i * MM;
                        float s = 0.0f;
                        if (k0 < i) s = fmaf(Lr[k0], x0, s);
                        if (k1 < i) s = fmaf(Lr[k1], x1, s);
                        if (k2 < i) s = fmaf(Lr[k2], x2, s);
                        #pragma unroll
                        for (int off = 1; off < 64; off <<= 1) s += __shfl_xor(s, off);
                        float xi = ((i == j) ? 1.0f : 0.0f) - s;
                        if (k0 == i) x0 = xi;
                        if (k1 == i) x1 = xi;
                        if (k2 == i) x2 = xi;
                        if (lane == 0) V[i * MM + j] = xi;
                    }
                }
            } else if (gflag != 0) {
                const float* L = ws + OFF_LC2;
                const float* G = ws + OFF_G;
                int c = u - MM;
                int k0 = lane, k1 = lane + 64, k2 = lane + 128;
                float x0 = 0, x1 = 0, x2 = 0, ss = 0;
                for (int i = 0; i < MM; i++) {
                    const float* Lr = L + i * MM;
                    float s = 0.0f;
                    if (k0 < i) s = fmaf(Lr[k0], x0, s);
                    if (k1 < i) s = fmaf(Lr[k1], x1, s);
                    if (k2 < i) s = fmaf(Lr[k2], x2, s);
                    #pragma unroll
                    for (int off = 1; off < 64; off <<= 1) s += __shfl_xor(s, off);
                    float xi = G[i * QD + c] - s;
                    if (k0 == i) x0 = xi;
                    if (k1 == i) x1 = xi;
                    if (k2 == i) x2 = xi;
                    if (lane == 0) ss += xi * xi / Lr[i];
                }
                if (lane == 0) atomicAdd(&ws[OFF_SCAL + 2], ss);
            }
        }
        grid_sync(ws);
        // -------- Phase F: trace_raw --------
        if (cnt2 != 0) {
            for (int i = blockIdx.x; i < MM; i += nblk) {
                float* vrow = smem;         // 192
                float* red  = smem + 192;   // 256
                const float* V = ws + OFF_V;
                const float* P = ws + OFF_PSI2;
                for (int a = tid; a < MM; a += 256) vrow[a] = (a <= i) ? V[i * MM + a] : 0.0f;
                __syncthreads();
                float acc = 0.0f;
                for (int a = tid; a <= i; a += 256) {
                    const float* Pr = P + a * MM;
                    float inner = 0.0f;
                    for (int b = 0; b <= i; b++) inner = fmaf(Pr[b], vrow[b], inner);
                    acc = fmaf(vrow[a], inner, acc);
                }
                red[tid] = acc; __syncthreads();
                if (tid < 128) red[tid] += red[tid + 128];
                __syncthreads();
                if (tid < 64) {
                    float s = red[tid] + red[tid + 64];
                    s = wave_reduce(s);
                    if (tid == 0) { float di = ws[OFF_LC + i * MM + i]; atomicAdd(&ws[OFF_SCAL + 0], s / di); }
                }
                __syncthreads();
            }
        }
        grid_sync(ws);
    }

    // ---------------- Final assembly (block 0) ----------------
    if (blockIdx.x == 0 && tid < 64) {
        float s0 = 0, s1 = 0, s2 = 0, s3 = 0;
        for (int b = tid; b < nblk; b += 64) {
            const float* bp = ws + OFF_BSUM + 4 * b;
            s0 += LDWSF(bp + 0); s1 += LDWSF(bp + 1); s2 += LDWSF(bp + 2); s3 += LDWSF(bp + 3);
        }
        s0 = bfly_sum(s0); s1 = bfly_sum(s1); s2 = bfly_sum(s2); s3 = bfly_sum(s3);
        if (tid == 0) {
            float Svo = s0, Smo2 = s1, Slog = s2, Smb = s3;
            // slots 0/2/7/8 are memset-zeroed; nonzero only if slow path ran
            float trRaw = LDWSF(ws + OFF_SCAL + 0);
            float ssY   = LDWSF(ws + OFF_SCAL + 2);
            float ldK   = LDWSF(ws + OFF_SCAL + 7);
            float ldC2  = LDWSF(ws + OFF_SCAL + 8);
            float kv = *kern_var, s2v = *lik;
            float inv_s2 = 1.0f / s2v;
            const float lp2pi = 1.8378770664093453f;  // log(2*pi)
            float trA = trRaw * inv_s2;
            float ldB = 2.0f * (ldC2 - ldK);
            float sc2 = ssY * inv_s2 * inv_s2;
            float ND = 18000.0f;   // (Nt-Lt)*D
            float Df = 12.0f;
            float bound = -0.5f * ND * (lp2pi + logf(s2v));
            bound += -0.5f * inv_s2 * (Svo + Smo2);
            bound += -0.5f * Df * ((kv * 1500.0f) * inv_s2 - trA);
            bound += -0.5f * Df * ldB;
            bound += 0.5f * sc2;
            bound += 0.5f * Slog + 0.5f * ND * lp2pi;      // ent
            bound += -96.0f * lp2pi - 0.5f * Smb;          // ent2 (Lt*D = 96)
            out[0] = bound;
        }
    }
}

extern "C" void kernel_launch(void* const* d_in, const int* in_sizes, int n_in,
                              void* d_out, int out_size, void* d_ws, size_t ws_size,
                              hipStream_t stream)
{
    const float* Xm_m    = (const float*)d_in[1];
    const float* Xm_v    = (const float*)d_in[2];
    const float* Z       = (const float*)d_in[3];
    const float* X_mean  = (const float*)d_in[4];
    const float* X_var   = (const float*)d_in[5];
    const float* kern_var= (const float*)d_in[6];
    const float* kern_ls = (const float*)d_in[7];
    const float* lik_var = (const float*)d_in[8];
    float* ws  = (float*)d_ws;
    float* out = (float*)d_out;

    // zero scalar slots (0..15) + barrier state (cnt, gen) — 24 floats
    hipMemsetAsync(ws + OFF_SCAL, 0, 24 * sizeof(float), stream);

    k_fused<<<FGRID, 256, 0, stream>>>(Xm_m, Xm_v, Z, X_mean, X_var,
                                       kern_var, kern_ls, lik_var, ws, out);
}

// Round 3
// 93.600 us; speedup vs baseline: 1.4042x; 1.2331x over previous
//
#include <hip/hip_runtime.h>
#include <math.h>

// Problem dims (fixed by setup_inputs)
#define NR   1500     // rows of X_m  (Nt - Lt)
#define NTT  1508     // Nt
#define QD   12       // D
#define LT   8
#define DIN  192      // 2*Lt*Q
#define MM   192      // M
#define JITTER 1e-6f
// Exact per-row suprema: psi1 expo <= logdet1[n], psi2 expo <= logdet2[n].
// Rows below this cut contribute < e^-30 ~ 1e-13 each -> provably < 1e-6 relative.
#define PRUNE_CUT -30.0f

// ---- workspace layout (float offsets) ----
#define OFF_W2    0
#define OFF_WU2   288000
#define OFF_P1    576000
#define OFF_R1    864000
#define OFF_S1    1152000
#define OFF_S2    1153500
#define OFF_V     1155000
#define OFF_D2ZZ  1191864
#define OFF_KUU   1228728
#define OFF_PSI1  1265592
#define OFF_PSI2  1553592
#define OFF_LC    1590456
#define OFF_LC2   1627320
#define OFF_G     1664184
#define OFF_SCAL  1666488     // 16 floats
#define OFF_BAR   1666504     // 16 ints: 7 barriers x {arriveCnt, doneFlag} (memset 0)
#define OFF_NLIST 1666520     // 1500 ints: surviving-n list for psi2
#define OFF_BSUM  1668032     // 256 blocks x 4 per-block input-sum partials
#define OFF_F     1669056     // 288000 floats (de-aliased from P1)
#define OFF_CHA   1957056     // 2 x MM*ALD global scratch for Phase D chol
// scal slots: 0 trace_raw, 2 ||Y||^2, 7 0.5*logdetKuu, 8 0.5*logdetC2,
//             12 cnt2 (psi2 survivors), 13 cnt1 (psi1 survivors), 14 gflag

#define LDWSF(p)   __hip_atomic_load((p), __ATOMIC_RELAXED, __HIP_MEMORY_SCOPE_AGENT)
#define LDWSI(p)   __hip_atomic_load((p), __ATOMIC_RELAXED, __HIP_MEMORY_SCOPE_AGENT)
#define STWSF(p,v) __hip_atomic_store((p), (v), __ATOMIC_RELAXED, __HIP_MEMORY_SCOPE_AGENT)

__device__ __forceinline__ float wave_reduce(float s) {
    s += __shfl_down(s, 32); s += __shfl_down(s, 16); s += __shfl_down(s, 8);
    s += __shfl_down(s, 4);  s += __shfl_down(s, 2);  s += __shfl_down(s, 1);
    return s;
}
__device__ __forceinline__ float bfly_sum(float s) {
    s += __shfl_xor(s, 32); s += __shfl_xor(s, 16); s += __shfl_xor(s, 8);
    s += __shfl_xor(s, 4);  s += __shfl_xor(s, 2);  s += __shfl_xor(s, 1);
    return s;
}

// Grid barrier, storm-free version.
//  - monotonic per-phase counters (no sense reversal; memset zeroes them)
//  - arrival: relaxed RMW on A; last arriver bumps done-flag B (separate addr,
//    so polls don't contend with arrivals)
//  - poll: relaxed fetch_add(B,0) — agent-scope RMWs bypass the local XCD L2
//    (always fresh) WITHOUT the per-poll L2-invalidate an ACQUIRE load emits
//  - exactly one release fence before arrival / one acquire fence after.
// Co-residency: grid=256 <= 256 CUs, 49KB LDS -> all blocks resident, no deadlock.
__device__ __forceinline__ void grid_sync(float* ws, int k) {
    __syncthreads();
    if (threadIdx.x == 0) {
        int* A = (int*)(ws + OFF_BAR) + 2 * k;
        int* B = A + 1;
        __builtin_amdgcn_fence(__ATOMIC_RELEASE, "agent");
        if (__hip_atomic_fetch_add(A, 1, __ATOMIC_RELAXED, __HIP_MEMORY_SCOPE_AGENT)
            == (int)gridDim.x - 1) {
            __hip_atomic_fetch_add(B, 1, __ATOMIC_RELAXED, __HIP_MEMORY_SCOPE_AGENT);
        } else {
            while (__hip_atomic_fetch_add(B, 0, __ATOMIC_RELAXED, __HIP_MEMORY_SCOPE_AGENT) == 0)
                __builtin_amdgcn_s_sleep(32);
        }
        __builtin_amdgcn_fence(__ATOMIC_ACQUIRE, "agent");
    }
    __syncthreads();
}

#define ALD 196
#define NB  32
#define ZR  196
#define FGRID 256

// ============================================================================
// Fused kernel: the whole dependency chain in ONE ordinary dispatch.
// Fast path (cnt1==cnt2==0, true for the bench data): prep+sums -> 1 grid
// sync -> final assembly. Slow path keeps all phases, separated by grid syncs.
// Phase D (chol) uses global-ws scratch so static LDS stays at 49 KB.
// ============================================================================
__global__ __launch_bounds__(256) void k_fused(
    const float* __restrict__ Xm_m, const float* __restrict__ Xm_v,
    const float* __restrict__ Z, const float* __restrict__ X_mean,
    const float* __restrict__ X_var, const float* __restrict__ kern_var,
    const float* __restrict__ kern_ls, const float* __restrict__ lik,
    float* __restrict__ ws, float* __restrict__ out)
{
    __shared__ __align__(16) float smem[2 * 32 * ZR];   // 49 KB, union for all phases
    const int tid  = threadIdx.x;
    const int lane = tid & 63;
    const int wav  = tid >> 6;
    const int nblk = gridDim.x;
    const int ty4  = tid >> 4, tx4 = tid & 15;

    // ---------------- Phase A: per-n prep + input sums ----------------
    for (int n = blockIdx.x * 4 + wav; n < NR; n += nblk * 4) {
        float v0 = 0, v1 = 0, v2 = 0, v3 = 0;
        #pragma unroll
        for (int s = 0; s < 3; s++) {
            int q = lane + 64 * s;
            float u, v;
            if (q < 96) { u = X_mean[n * QD + q]; v = X_var[n * QD + q]; }
            else        { int j = q - 96; u = Xm_m[(1 + n) * QD + j]; v = Xm_v[(1 + n) * QD + j]; }
            float ls = kern_ls[q]; float l2 = ls * ls;
            float d1 = l2 + v, d2 = l2 + 2.0f * v;
            float i1 = 1.0f / d1, i2 = 1.0f / d2;
            ws[OFF_P1  + n * DIN + q] = u * i1;
            ws[OFF_R1  + n * DIN + q] = i1;
            ws[OFF_W2  + n * DIN + q] = i2;
            ws[OFF_WU2 + n * DIN + q] = u * i2;
            v0 += log1pf(v / l2);
            v1 += log1pf(2.0f * v / l2);
            v2 += u * u * i1;
            v3 += u * u * i2;
        }
        v0 = bfly_sum(v0); v1 = bfly_sum(v1); v2 = bfly_sum(v2); v3 = bfly_sum(v3);
        if (lane == 0) {
            ws[OFF_S1 + n] = -0.5f * (v0 + v2);
            ws[OFF_S2 + n] = -0.5f * v1 - v3;
            float ld1 = -0.5f * v0;                // exact sup of psi1 exponent
            float ld2 = -0.5f * v1;                // exact sup of psi2 exponent
            int* cnts = (int*)(ws + OFF_SCAL);
            if (ld1 > PRUNE_CUT) atomicAdd(&cnts[13], 1);
            if (ld2 > PRUNE_CUT) {
                int idx = atomicAdd(&cnts[12], 1);
                ((int*)(ws + OFF_NLIST))[idx] = n;
            }
        }
    }
    {   // input sums (Svo, Smo2, Slog, Smb) -> per-block partials, no atomics
        float pVo = 0, pMo = 0, pLg = 0, pMb = 0;
        for (int idx = blockIdx.x * 256 + tid; idx < NTT * QD; idx += nblk * 256) {
            float xm = X_mean[idx], xv = X_var[idx];
            if (idx >= LT * QD) { pVo += xv; pMo += xm * xm; pLg += logf(xv); }
            else                { pMb += xm * xm + xv; }
        }
        pVo = bfly_sum(pVo); pMo = bfly_sum(pMo); pLg = bfly_sum(pLg); pMb = bfly_sum(pMb);
        float* part = smem;   // 16 floats
        if (lane == 0) { part[wav*4+0] = pVo; part[wav*4+1] = pMo; part[wav*4+2] = pLg; part[wav*4+3] = pMb; }
        __syncthreads();
        if (tid < 4) {
            float s = part[tid] + part[4 + tid] + part[8 + tid] + part[12 + tid];
            STWSF(&ws[OFF_BSUM + blockIdx.x * 4 + tid], s);
        }
        __syncthreads();
    }
    grid_sync(ws, 0);

    const int* scal_i = (const int*)(ws + OFF_SCAL);
    const int cnt1 = LDWSI(scal_i + 13);
    const int cnt2 = LDWSI(scal_i + 12);

    if ((cnt1 | cnt2) != 0) {
        // =================== SLOW PATH (not exercised by bench data) =========
        float kv = *kern_var;
        // -------- Phase B: Kuu/d2zz tiles + psi1 tiles + F tiles --------
        for (int vb = blockIdx.x; vb < 144 + 2 * 1128; vb += nblk) {
            if (vb < 144) {
                int bx = vb / 12, by = vb - bx * 12;
                float (*Zm)[17] = (float(*)[17])smem;
                float (*Zp)[17] = (float(*)[17])(smem + 272);
                int m = bx * 16 + ty4, p = by * 16 + tx4;
                float d = 0.0f;
                for (int qc = 0; qc < 12; qc++) {
                    int q0 = qc * 16;
                    float inv_ls = 1.0f / kern_ls[q0 + tx4];
                    Zm[ty4][tx4] = Z[(bx * 16 + ty4) * DIN + q0 + tx4] * inv_ls;
                    Zp[ty4][tx4] = Z[(by * 16 + ty4) * DIN + q0 + tx4] * inv_ls;
                    __syncthreads();
                    #pragma unroll
                    for (int k = 0; k < 16; k++) { float t = Zm[ty4][k] - Zp[tx4][k]; d = fmaf(t, t, d); }
                    __syncthreads();
                }
                ws[OFF_D2ZZ + m * MM + p] = d;
                ws[OFF_KUU  + m * MM + p] = kv * __expf(-0.5f * d) + ((m == p) ? JITTER : 0.0f);
            } else if (vb < 144 + 1128) {
                if (cnt1 != 0) {
                    int t = vb - 144, bx = t % 94, by = t / 94;
                    int n = bx * 16 + ty4, m = by * 16 + tx4;
                    float (*Ps)[17]  = (float(*)[17])smem;
                    float (*Rs)[17]  = (float(*)[17])(smem + 272);
                    float (*Zs)[17]  = (float(*)[17])(smem + 544);
                    float (*Z2s)[17] = (float(*)[17])(smem + 816);
                    float dot1 = 0.0f, dot2 = 0.0f;
                    for (int qc = 0; qc < 12; qc++) {
                        int q0 = qc * 16;
                        Ps[ty4][tx4] = (n < NR) ? ws[OFF_P1 + n * DIN + q0 + tx4] : 0.0f;
                        Rs[ty4][tx4] = (n < NR) ? ws[OFF_R1 + n * DIN + q0 + tx4] : 0.0f;
                        float z = Z[(by * 16 + ty4) * DIN + q0 + tx4];
                        Zs[ty4][tx4] = z; Z2s[ty4][tx4] = z * z;
                        __syncthreads();
                        #pragma unroll
                        for (int k = 0; k < 16; k++) {
                            dot1 = fmaf(Ps[ty4][k], Zs[tx4][k], dot1);
                            dot2 = fmaf(Rs[ty4][k], Z2s[tx4][k], dot2);
                        }
                        __syncthreads();
                    }
                    if (n < NR) ws[OFF_PSI1 + n * MM + m] = kv * __expf(ws[OFF_S1 + n] + dot1 - 0.5f * dot2);
                }
            } else {
                if (cnt2 != 0) {
                    int t = vb - (144 + 1128), bx = t % 94, by = t / 94;
                    int n = bx * 16 + ty4, m = by * 16 + tx4;
                    float (*Us)[17] = (float(*)[17])smem;
                    float (*Ws)[17] = (float(*)[17])(smem + 272);
                    float (*Zb)[17] = (float(*)[17])(smem + 544);
                    float dotB = 0.0f, dotC = 0.0f;
                    for (int qc = 0; qc < 12; qc++) {
                        int q0 = qc * 16;
                        Us[ty4][tx4] = (n < NR) ? ws[OFF_WU2 + n * DIN + q0 + tx4] : 0.0f;
                        Ws[ty4][tx4] = (n < NR) ? ws[OFF_W2  + n * DIN + q0 + tx4] : 0.0f;
                        Zb[ty4][tx4] = Z[(by * 16 + ty4) * DIN + q0 + tx4];
                        __syncthreads();
                        #pragma unroll
                        for (int k = 0; k < 16; k++) {
                            float z = Zb[tx4][k];
                            dotB = fmaf(z, Us[ty4][k], dotB);
                            dotC = fmaf(z * z, Ws[ty4][k], dotC);
                        }
                        __syncthreads();
                    }
                    if (n < NR) ws[OFF_F + n * MM + m] = fmaf(-0.25f, dotC, dotB);
                }
            }
        }
        grid_sync(ws, 1);
        // -------- Phase C: G rows + psi2 tiles (or exact-zero fill) --------
        for (int vb = blockIdx.x; vb < 192 + 36; vb += nblk) {
            if (vb < 192) {
                if (cnt1 != 0) {
                    int m = vb;
                    const float* psi1 = ws + OFF_PSI1;
                    float g[QD];
                    #pragma unroll
                    for (int d = 0; d < QD; d++) g[d] = 0.0f;
                    for (int n = tid; n < NR; n += 256) {
                        float p = psi1[n * MM + m];
                        const float* xr = X_mean + (LT + n) * QD;
                        #pragma unroll
                        for (int d = 0; d < QD; d++) g[d] = fmaf(p, xr[d], g[d]);
                    }
                    float* red = smem;   // 256 floats
                    bool any = false;
                    for (int d = 0; d < QD; d++) {
                        red[tid] = g[d]; __syncthreads();
                        if (tid < 128) red[tid] += red[tid + 128];
                        __syncthreads();
                        if (tid < 64) {
                            float s = red[tid] + red[tid + 64];
                            s = wave_reduce(s);
                            if (tid == 0) { ws[OFF_G + m * QD + d] = s; any |= (s != 0.0f); }
                        }
                        __syncthreads();
                    }
                    if (tid == 0 && any) atomicOr((int*)(ws + OFF_SCAL) + 14, 1);
                }
            } else {
                int t = vb - 192, bx = t / 6, by = t - 6 * bx;
                int m0 = bx * 32, p0 = by * 32;
                int mA = m0 + 2 * ty4, pA = p0 + 2 * tx4;
                float* P2 = ws + OFF_PSI2;
                if (cnt2 == 0) {   // slow path => cnt1>0; chol-C2 may read psi2
                    P2[(mA    ) * MM + pA    ] = 0.0f;
                    P2[(mA    ) * MM + pA + 1] = 0.0f;
                    P2[(mA + 1) * MM + pA    ] = 0.0f;
                    P2[(mA + 1) * MM + pA + 1] = 0.0f;
                    __syncthreads();
                } else {
                    float a00 = 0, a01 = 0, a10 = 0, a11 = 0;
                    float* Zm = smem;             // 32*ZR
                    float* Zp = smem + 32 * ZR;   // 32*ZR
                    for (int idx = tid; idx < 32 * DIN; idx += 256) {
                        int r = idx / DIN, q = idx - r * DIN;
                        Zm[r * ZR + q] = Z[(m0 + r) * DIN + q];
                        Zp[r * ZR + q] = Z[(p0 + r) * DIN + q];
                    }
                    __syncthreads();
                    const float* w2base = ws + OFF_W2;
                    const float* F      = ws + OFF_F;
                    const float* s2arr  = ws + OFF_S2;
                    const int* list     = (const int*)(ws + OFF_NLIST);
                    const float4* zm0 = (const float4*)(Zm + (2 * ty4    ) * ZR);
                    const float4* zm1 = (const float4*)(Zm + (2 * ty4 + 1) * ZR);
                    const float4* zp0 = (const float4*)(Zp + (2 * tx4    ) * ZR);
                    const float4* zp1 = (const float4*)(Zp + (2 * tx4 + 1) * ZR);
                    for (int li = 0; li < cnt2; li++) {
                        int n = list[li];
                        const float4* w2p = (const float4*)(w2base + n * DIN);
                        float e00 = 0, e01 = 0, e10 = 0, e11 = 0;
                        #pragma unroll 4
                        for (int g = 0; g < DIN / 4; g++) {
                            float4 w = w2p[g];
                            float4 a = zm0[g], b = zm1[g], c = zp0[g], d = zp1[g];
                            float wp0, wp1;
                            wp0 = w.x * c.x; wp1 = w.x * d.x;
                            e00 = fmaf(a.x, wp0, e00); e01 = fmaf(a.x, wp1, e01);
                            e10 = fmaf(b.x, wp0, e10); e11 = fmaf(b.x, wp1, e11);
                            wp0 = w.y * c.y; wp1 = w.y * d.y;
                            e00 = fmaf(a.y, wp0, e00); e01 = fmaf(a.y, wp1, e01);
                            e10 = fmaf(b.y, wp0, e10); e11 = fmaf(b.y, wp1, e11);
                            wp0 = w.z * c.z; wp1 = w.z * d.z;
                            e00 = fmaf(a.z, wp0, e00); e01 = fmaf(a.z, wp1, e01);
                            e10 = fmaf(b.z, wp0, e10); e11 = fmaf(b.z, wp1, e11);
                            wp0 = w.w * c.w; wp1 = w.w * d.w;
                            e00 = fmaf(a.w, wp0, e00); e01 = fmaf(a.w, wp1, e01);
                            e10 = fmaf(b.w, wp0, e10); e11 = fmaf(b.w, wp1, e11);
                        }
                        float s2n = s2arr[n];
                        float Fm0 = F[n * MM + mA], Fm1 = F[n * MM + mA + 1];
                        float Fp0 = F[n * MM + pA], Fp1 = F[n * MM + pA + 1];
                        a00 += __expf(s2n + Fm0 + Fp0 - 0.5f * e00);
                        a01 += __expf(s2n + Fm0 + Fp1 - 0.5f * e01);
                        a10 += __expf(s2n + Fm1 + Fp0 - 0.5f * e10);
                        a11 += __expf(s2n + Fm1 + Fp1 - 0.5f * e11);
                    }
                    float kv2 = kv * kv;
                    const float* dz = ws + OFF_D2ZZ;
                    P2[(mA    ) * MM + pA    ] = kv2 * __expf(-0.25f * dz[(mA    ) * MM + pA    ]) * a00;
                    P2[(mA    ) * MM + pA + 1] = kv2 * __expf(-0.25f * dz[(mA    ) * MM + pA + 1]) * a01;
                    P2[(mA + 1) * MM + pA    ] = kv2 * __expf(-0.25f * dz[(mA + 1) * MM + pA    ]) * a10;
                    P2[(mA + 1) * MM + pA + 1] = kv2 * __expf(-0.25f * dz[(mA + 1) * MM + pA + 1]) * a11;
                    __syncthreads();
                }
            }
        }
        grid_sync(ws, 2);
        const int gflag = LDWSI((const int*)(ws + OFF_SCAL) + 14);
        // -------- Phase D: dual blocked LDL^T in GLOBAL scratch --------
        if (blockIdx.x < 2 && (cnt2 != 0 || gflag != 0)) {
            bool isC2 = (blockIdx.x == 1);
            float* A = ws + OFF_CHA + (size_t)blockIdx.x * (MM * ALD);
            const float* Kuu  = ws + OFF_KUU;
            const float* psi2 = ws + OFF_PSI2;
            float inv_s2 = 1.0f / (*lik);
            for (int idx = tid; idx < MM * MM; idx += 256) {
                int i = idx / MM, j = idx - i * MM;
                float v = Kuu[idx];
                if (isC2) v = fmaf(psi2[idx], inv_s2, v);
                A[i * ALD + j] = v;
            }
            __syncthreads();
            float logacc = 0.0f;
            for (int p = 0; p < MM / NB; p++) {
                int k0 = p * NB;
                int e  = k0 + NB;
                if (tid < 64) {
                    int l64 = tid;
                    float P[3][NB];
                    #pragma unroll
                    for (int s = 0; s < 3; s++) {
                        int r = l64 + 64 * s;
                        #pragma unroll
                        for (int g = 0; g < NB / 4; g++) {
                            float4 v = *(const float4*)&A[r * ALD + k0 + 4 * g];
                            P[s][4*g] = v.x; P[s][4*g+1] = v.y; P[s][4*g+2] = v.z; P[s][4*g+3] = v.w;
                        }
                    }
                    int sD = k0 >> 6;
                    int lD = k0 & 63;
                    #pragma unroll
                    for (int c = 0; c < NB; c++) {
                        int k = k0 + c;
                        float colc = (sD == 0) ? P[0][c] : ((sD == 1) ? P[1][c] : P[2][c]);
                        float dkk = __shfl(colc, lD + c);
                        float inv = 1.0f / dkk;
                        logacc += logf(dkk);
                        float m0 = (l64       > k) ? P[0][c] * inv : 0.0f;
                        float m1 = (l64 + 64  > k) ? P[1][c] * inv : 0.0f;
                        float m2 = (l64 + 128 > k) ? P[2][c] * inv : 0.0f;
                        P[0][c] = (l64       > k) ? m0 : P[0][c];
                        P[1][c] = (l64 + 64  > k) ? m1 : P[1][c];
                        P[2][c] = (l64 + 128 > k) ? m2 : P[2][c];
                        #pragma unroll
                        for (int j = c + 1; j < NB; j++) {
                            float w = __shfl(colc, lD + j);
                            P[0][j] = fmaf(-m0, w, P[0][j]);
                            P[1][j] = fmaf(-m1, w, P[1][j]);
                            P[2][j] = fmaf(-m2, w, P[2][j]);
                        }
                    }
                    #pragma unroll
                    for (int s = 0; s < 3; s++) {
                        int r = l64 + 64 * s;
                        #pragma unroll
                        for (int g = 0; g < NB / 4; g++) {
                            float4 v = make_float4(P[s][4*g], P[s][4*g+1], P[s][4*g+2], P[s][4*g+3]);
                            *(float4*)&A[r * ALD + k0 + 4 * g] = v;
                        }
                    }
                }
                __syncthreads();
                int T = MM - e;
                if (T > 0) {
                    for (int idx = tid; idx < NB * T; idx += 256) {
                        int c = idx / T, j = e + (idx - c * T);
                        float d = A[(k0 + c) * ALD + (k0 + c)];
                        A[(k0 + c) * ALD + j] = A[j * ALD + k0 + c] * sqrtf(d);
                    }
                    __syncthreads();
                    int nT = (T + 127) / 128;
                    for (int bi = 0; bi < nT; bi++)
                    for (int bj = 0; bj < nT; bj++) {
                        int i0 = e + 128 * bi + 8 * ty4;
                        int j0 = e + 128 * bj + 8 * tx4;
                        int ic = (i0 < MM - 8) ? i0 : (MM - 8);
                        int jc = (j0 < MM - 8) ? j0 : (MM - 8);
                        float4 acc[8][2];
                        #pragma unroll
                        for (int r = 0; r < 8; r++) {
                            acc[r][0] = *(const float4*)&A[(ic + r) * ALD + jc];
                            acc[r][1] = *(const float4*)&A[(ic + r) * ALD + jc + 4];
                        }
                        #pragma unroll 4
                        for (int c = 0; c < NB; c++) {
                            const float* row = &A[(k0 + c) * ALD];
                            float4 av0 = *(const float4*)&row[ic];
                            float4 av1 = *(const float4*)&row[ic + 4];
                            float4 bv0 = *(const float4*)&row[jc];
                            float4 bv1 = *(const float4*)&row[jc + 4];
                            float avs[8] = {av0.x, av0.y, av0.z, av0.w, av1.x, av1.y, av1.z, av1.w};
                            #pragma unroll
                            for (int r = 0; r < 8; r++) {
                                float a = avs[r];
                                acc[r][0].x = fmaf(-a, bv0.x, acc[r][0].x);
                                acc[r][0].y = fmaf(-a, bv0.y, acc[r][0].y);
                                acc[r][0].z = fmaf(-a, bv0.z, acc[r][0].z);
                                acc[r][0].w = fmaf(-a, bv0.w, acc[r][0].w);
                                acc[r][1].x = fmaf(-a, bv1.x, acc[r][1].x);
                                acc[r][1].y = fmaf(-a, bv1.y, acc[r][1].y);
                                acc[r][1].z = fmaf(-a, bv1.z, acc[r][1].z);
                                acc[r][1].w = fmaf(-a, bv1.w, acc[r][1].w);
                            }
                        }
                        if (ic == i0 && jc == j0) {
                            #pragma unroll
                            for (int r = 0; r < 8; r++) {
                                *(float4*)&A[(i0 + r) * ALD + j0]     = acc[r][0];
                                *(float4*)&A[(i0 + r) * ALD + j0 + 4] = acc[r][1];
                            }
                        }
                    }
                    __syncthreads();
                }
            }
            float* dst = ws + (isC2 ? OFF_LC2 : OFF_LC);
            for (int idx = tid; idx < MM * MM; idx += 256) {
                int i = idx / MM, j = idx - i * MM;
                dst[idx] = A[i * ALD + j];
            }
            if (tid == 0) STWSF(&ws[OFF_SCAL + (isC2 ? 8 : 7)], 0.5f * logacc);
        }
        grid_sync(ws, 3);
        // -------- Phase E: triangular solves (wave-per-column) --------
        for (int u = blockIdx.x * 4 + wav; u < MM + QD; u += nblk * 4) {
            if (u < MM) {
                if (cnt2 != 0) {
                    const float* L = ws + OFF_LC;
                    float* V = ws + OFF_V;
                    int j = u;
                    int k0 = j + lane, k1 = k0 + 64, k2 = k0 + 128;
                    float x0 = 0, x1 = 0, x2 = 0;
                    for (int i = j; i < MM; i++) {
                        const float* Lr = L + i * MM;
                        float s = 0.0f;
                        if (k0 < i) s = fmaf(Lr[k0], x0, s);
                        if (k1 < i) s = fmaf(Lr[k1], x1, s);
                        if (k2 < i) s = fmaf(Lr[k2], x2, s);
                        #pragma unroll
                        for (int off = 1; off < 64; off <<= 1) s += __shfl_xor(s, off);
                        float xi = ((i == j) ? 1.0f : 0.0f) - s;
                        if (k0 == i) x0 = xi;
                        if (k1 == i) x1 = xi;
                        if (k2 == i) x2 = xi;
                        if (lane == 0) V[i * MM + j] = xi;
                    }
                }
            } else if (gflag != 0) {
                const float* L = ws + OFF_LC2;
                const float* G = ws + OFF_G;
                int c = u - MM;
                int k0 = lane, k1 = lane + 64, k2 = lane + 128;
                float x0 = 0, x1 = 0, x2 = 0, ss = 0;
                for (int i = 0; i < MM; i++) {
                    const float* Lr = L + i * MM;
                    float s = 0.0f;
                    if (k0 < i) s = fmaf(Lr[k0], x0, s);
                    if (k1 < i) s = fmaf(Lr[k1], x1, s);
                    if (k2 < i) s = fmaf(Lr[k2], x2, s);
                    #pragma unroll
                    for (int off = 1; off < 64; off <<= 1) s += __shfl_xor(s, off);
                    float xi = G[i * QD + c] - s;
                    if (k0 == i) x0 = xi;
                    if (k1 == i) x1 = xi;
                    if (k2 == i) x2 = xi;
                    if (lane == 0) ss += xi * xi / Lr[i];
                }
                if (lane == 0) atomicAdd(&ws[OFF_SCAL + 2], ss);
            }
        }
        grid_sync(ws, 4);
        // -------- Phase F: trace_raw --------
        if (cnt2 != 0) {
            for (int i = blockIdx.x; i < MM; i += nblk) {
                float* vrow = smem;         // 192
                float* red  = smem + 192;   // 256
                const float* V = ws + OFF_V;
                const float* P = ws + OFF_PSI2;
                for (int a = tid; a < MM; a += 256) vrow[a] = (a <= i) ? V[i * MM + a] : 0.0f;
                __syncthreads();
                float acc = 0.0f;
                for (int a = tid; a <= i; a += 256) {
                    const float* Pr = P + a * MM;
                    float inner = 0.0f;
                    for (int b = 0; b <= i; b++) inner = fmaf(Pr[b], vrow[b], inner);
                    acc = fmaf(vrow[a], inner, acc);
                }
                red[tid] = acc; __syncthreads();
                if (tid < 128) red[tid] += red[tid + 128];
                __syncthreads();
                if (tid < 64) {
                    float s = red[tid] + red[tid + 64];
                    s = wave_reduce(s);
                    if (tid == 0) { float di = ws[OFF_LC + i * MM + i]; atomicAdd(&ws[OFF_SCAL + 0], s / di); }
                }
                __syncthreads();
            }
        }
        grid_sync(ws, 5);
    }

    // ---------------- Final assembly (block 0) ----------------
    if (blockIdx.x == 0 && tid < 64) {
        float s0 = 0, s1 = 0, s2 = 0, s3 = 0;
        for (int b = tid; b < nblk; b += 64) {
            const float* bp = ws + OFF_BSUM + 4 * b;
            s0 += LDWSF(bp + 0); s1 += LDWSF(bp + 1); s2 += LDWSF(bp + 2); s3 += LDWSF(bp + 3);
        }
        s0 = bfly_sum(s0); s1 = bfly_sum(s1); s2 = bfly_sum(s2); s3 = bfly_sum(s3);
        if (tid == 0) {
            float Svo = s0, Smo2 = s1, Slog = s2, Smb = s3;
            // slots 0/2/7/8 are memset-zeroed; nonzero only if slow path ran
            float trRaw = LDWSF(ws + OFF_SCAL + 0);
            float ssY   = LDWSF(ws + OFF_SCAL + 2);
            float ldK   = LDWSF(ws + OFF_SCAL + 7);
            float ldC2  = LDWSF(ws + OFF_SCAL + 8);
            float kv = *kern_var, s2v = *lik;
            float inv_s2 = 1.0f / s2v;
            const float lp2pi = 1.8378770664093453f;  // log(2*pi)
            float trA = trRaw * inv_s2;
            float ldB = 2.0f * (ldC2 - ldK);
            float sc2 = ssY * inv_s2 * inv_s2;
            float ND = 18000.0f;   // (Nt-Lt)*D
            float Df = 12.0f;
            float bound = -0.5f * ND * (lp2pi + logf(s2v));
            bound += -0.5f * inv_s2 * (Svo + Smo2);
            bound += -0.5f * Df * ((kv * 1500.0f) * inv_s2 - trA);
            bound += -0.5f * Df * ldB;
            bound += 0.5f * sc2;
            bound += 0.5f * Slog + 0.5f * ND * lp2pi;      // ent
            bound += -96.0f * lp2pi - 0.5f * Smb;          // ent2 (Lt*D = 96)
            out[0] = bound;
        }
    }
}

extern "C" void kernel_launch(void* const* d_in, const int* in_sizes, int n_in,
                              void* d_out, int out_size, void* d_ws, size_t ws_size,
                              hipStream_t stream)
{
    const float* Xm_m    = (const float*)d_in[1];
    const float* Xm_v    = (const float*)d_in[2];
    const float* Z       = (const float*)d_in[3];
    const float* X_mean  = (const float*)d_in[4];
    const float* X_var   = (const float*)d_in[5];
    const float* kern_var= (const float*)d_in[6];
    const float* kern_ls = (const float*)d_in[7];
    const float* lik_var = (const float*)d_in[8];
    float* ws  = (float*)d_ws;
    float* out = (float*)d_out;

    // zero scalar slots (16 floats) + barrier counters (16 ints) — 32 floats
    hipMemsetAsync(ws + OFF_SCAL, 0, 32 * sizeof(float), stream);

    k_fused<<<FGRID, 256, 0, stream>>>(Xm_m, Xm_v, Z, X_mean, X_var,
                                       kern_var, kern_ls, lik_var, ws, out);
}

// Round 4
// 83.531 us; speedup vs baseline: 1.5734x; 1.1205x over previous
//
#include <hip/hip_runtime.h>
#include <math.h>

// Problem dims (fixed by setup_inputs)
#define NR   1500     // rows of X_m  (Nt - Lt)
#define NTT  1508     // Nt
#define QD   12       // D
#define LT   8
#define DIN  192      // 2*Lt*Q
#define MM   192      // M
#define JITTER 1e-6f
// Exact per-row suprema: psi1 expo <= logdet1[n], psi2 expo <= logdet2[n].
// Rows below this cut contribute < e^-30 ~ 1e-13 each -> provably < 1e-6 relative.
#define PRUNE_CUT -30.0f

// ---- workspace layout (float offsets) ----
#define OFF_W2    0
#define OFF_WU2   288000
#define OFF_P1    576000
#define OFF_R1    864000
#define OFF_S1    1152000
#define OFF_S2    1153500
#define OFF_V     1155000
#define OFF_D2ZZ  1191864
#define OFF_KUU   1228728
#define OFF_PSI1  1265592
#define OFF_PSI2  1553592
#define OFF_LC    1590456
#define OFF_LC2   1627320
#define OFF_G     1664184
#define OFF_NLIST 1666520     // 1500 ints: surviving-n list for psi2 (no zeroing needed)
#define OFF_BSUM  1668032     // 256 blocks x 4 per-block input-sum partials (all written)
#define OFF_F     1669056     // 288000 floats (de-aliased from P1)
#define OFF_CHA   1957056     // 2 x MM*ALD global scratch for Phase D chol
#define OFF_SCAL  2032384     // 16 floats (zeroed each replay)
#define OFF_BARX  2032448     // tree-barrier state: 7 phases x 65 lines x 64 ints (zeroed)
// scal slots: 0 trace_raw, 2 ||Y||^2, 7 0.5*logdetKuu, 8 0.5*logdetC2,
//             12 cnt2 (psi2 survivors), 13 cnt1 (psi1 survivors), 14 gflag

#define BAR_STRIDE 4160       // ints per barrier phase: (32 leaf + 1 root + 32 flag) x 64

#define LDWSF(p)   __hip_atomic_load((p), __ATOMIC_RELAXED, __HIP_MEMORY_SCOPE_AGENT)
#define LDWSI(p)   __hip_atomic_load((p), __ATOMIC_RELAXED, __HIP_MEMORY_SCOPE_AGENT)
#define STWSF(p,v) __hip_atomic_store((p), (v), __ATOMIC_RELAXED, __HIP_MEMORY_SCOPE_AGENT)

__device__ __forceinline__ float wave_reduce(float s) {
    s += __shfl_down(s, 32); s += __shfl_down(s, 16); s += __shfl_down(s, 8);
    s += __shfl_down(s, 4);  s += __shfl_down(s, 2);  s += __shfl_down(s, 1);
    return s;
}
__device__ __forceinline__ float bfly_sum(float s) {
    s += __shfl_xor(s, 32); s += __shfl_xor(s, 16); s += __shfl_xor(s, 8);
    s += __shfl_xor(s, 4);  s += __shfl_xor(s, 2);  s += __shfl_xor(s, 1);
    return s;
}

// Grid barrier v3: contention-free two-level tree.
//  - 32 leaf counters (one per blockIdx&31), each on its own 256B cacheline:
//    8 arrivals per leaf, parallel across 32 L2 banks.
//  - leaf-last arrives at root (32 arrivals); root-last bumps 32 per-group
//    done flags (RMW -> executed at home point, cross-XCD coherent).
//  - pollers spread 8-per-flag-line, RMW-poll with s_sleep(8) (~0.2us);
//    poll lines are disjoint from arrival lines -> no queueing interference.
//  - one agent release fence before arrival, one acquire after flag observed
//    (recipe validated rounds 2-3: relaxed RMWs + explicit fences).
// Monotonic counters; memset zeroes all 7 phases' state before each replay.
// Co-residency: grid=256 <= 256 CUs, 49KB LDS (3 blk/CU cap) -> no deadlock.
__device__ __forceinline__ void grid_sync(float* ws, int k) {
    __syncthreads();
    if (threadIdx.x == 0) {
        int* base  = (int*)(ws + OFF_BARX) + k * BAR_STRIDE;
        int  g     = (int)(blockIdx.x & 31);
        int* leaf  = base + g * 64;
        int* root  = base + 32 * 64;
        int* dflag = base + (33 + g) * 64;
        __builtin_amdgcn_fence(__ATOMIC_RELEASE, "agent");
        if (__hip_atomic_fetch_add(leaf, 1, __ATOMIC_RELAXED, __HIP_MEMORY_SCOPE_AGENT) == 7) {
            if (__hip_atomic_fetch_add(root, 1, __ATOMIC_RELAXED, __HIP_MEMORY_SCOPE_AGENT) == 31) {
                #pragma unroll
                for (int i = 0; i < 32; i++)
                    __hip_atomic_fetch_add(base + (33 + i) * 64, 1,
                                           __ATOMIC_RELAXED, __HIP_MEMORY_SCOPE_AGENT);
            }
        }
        while (__hip_atomic_fetch_add(dflag, 0, __ATOMIC_RELAXED, __HIP_MEMORY_SCOPE_AGENT) == 0)
            __builtin_amdgcn_s_sleep(8);
        __builtin_amdgcn_fence(__ATOMIC_ACQUIRE, "agent");
    }
    __syncthreads();
}

#define ALD 196
#define NB  32
#define ZR  196
#define FGRID 256

// ============================================================================
// Fused kernel: the whole dependency chain in ONE ordinary dispatch.
// Fast path (cnt1==cnt2==0, true for the bench data): prep+sums -> 1 grid
// sync -> final assembly. Slow path keeps all phases, separated by grid syncs.
// Phase D (chol) uses global-ws scratch so static LDS stays at 49 KB.
// ============================================================================
__global__ __launch_bounds__(256) void k_fused(
    const float* __restrict__ Xm_m, const float* __restrict__ Xm_v,
    const float* __restrict__ Z, const float* __restrict__ X_mean,
    const float* __restrict__ X_var, const float* __restrict__ kern_var,
    const float* __restrict__ kern_ls, const float* __restrict__ lik,
    float* __restrict__ ws, float* __restrict__ out)
{
    __shared__ __align__(16) float smem[2 * 32 * ZR];   // 49 KB, union for all phases
    const int tid  = threadIdx.x;
    const int lane = tid & 63;
    const int wav  = tid >> 6;
    const int nblk = gridDim.x;
    const int ty4  = tid >> 4, tx4 = tid & 15;

    // ---------------- Phase A: per-n prep + input sums ----------------
    for (int n = blockIdx.x * 4 + wav; n < NR; n += nblk * 4) {
        float v0 = 0, v1 = 0, v2 = 0, v3 = 0;
        #pragma unroll
        for (int s = 0; s < 3; s++) {
            int q = lane + 64 * s;
            float u, v;
            if (q < 96) { u = X_mean[n * QD + q]; v = X_var[n * QD + q]; }
            else        { int j = q - 96; u = Xm_m[(1 + n) * QD + j]; v = Xm_v[(1 + n) * QD + j]; }
            float ls = kern_ls[q]; float l2 = ls * ls;
            float d1 = l2 + v, d2 = l2 + 2.0f * v;
            float i1 = 1.0f / d1, i2 = 1.0f / d2;
            ws[OFF_P1  + n * DIN + q] = u * i1;
            ws[OFF_R1  + n * DIN + q] = i1;
            ws[OFF_W2  + n * DIN + q] = i2;
            ws[OFF_WU2 + n * DIN + q] = u * i2;
            v0 += log1pf(v / l2);
            v1 += log1pf(2.0f * v / l2);
            v2 += u * u * i1;
            v3 += u * u * i2;
        }
        v0 = bfly_sum(v0); v1 = bfly_sum(v1); v2 = bfly_sum(v2); v3 = bfly_sum(v3);
        if (lane == 0) {
            ws[OFF_S1 + n] = -0.5f * (v0 + v2);
            ws[OFF_S2 + n] = -0.5f * v1 - v3;
            float ld1 = -0.5f * v0;                // exact sup of psi1 exponent
            float ld2 = -0.5f * v1;                // exact sup of psi2 exponent
            int* cnts = (int*)(ws + OFF_SCAL);
            if (ld1 > PRUNE_CUT) atomicAdd(&cnts[13], 1);
            if (ld2 > PRUNE_CUT) {
                int idx = atomicAdd(&cnts[12], 1);
                ((int*)(ws + OFF_NLIST))[idx] = n;
            }
        }
    }
    {   // input sums (Svo, Smo2, Slog, Smb) -> per-block partials, no atomics
        float pVo = 0, pMo = 0, pLg = 0, pMb = 0;
        for (int idx = blockIdx.x * 256 + tid; idx < NTT * QD; idx += nblk * 256) {
            float xm = X_mean[idx], xv = X_var[idx];
            if (idx >= LT * QD) { pVo += xv; pMo += xm * xm; pLg += logf(xv); }
            else                { pMb += xm * xm + xv; }
        }
        pVo = bfly_sum(pVo); pMo = bfly_sum(pMo); pLg = bfly_sum(pLg); pMb = bfly_sum(pMb);
        float* part = smem;   // 16 floats
        if (lane == 0) { part[wav*4+0] = pVo; part[wav*4+1] = pMo; part[wav*4+2] = pLg; part[wav*4+3] = pMb; }
        __syncthreads();
        if (tid < 4) {
            float s = part[tid] + part[4 + tid] + part[8 + tid] + part[12 + tid];
            STWSF(&ws[OFF_BSUM + blockIdx.x * 4 + tid], s);
        }
        __syncthreads();
    }
    grid_sync(ws, 0);

    const int* scal_i = (const int*)(ws + OFF_SCAL);
    const int cnt1 = LDWSI(scal_i + 13);
    const int cnt2 = LDWSI(scal_i + 12);

    if ((cnt1 | cnt2) != 0) {
        // =================== SLOW PATH (not exercised by bench data) =========
        float kv = *kern_var;
        // -------- Phase B: Kuu/d2zz tiles + psi1 tiles + F tiles --------
        for (int vb = blockIdx.x; vb < 144 + 2 * 1128; vb += nblk) {
            if (vb < 144) {
                int bx = vb / 12, by = vb - bx * 12;
                float (*Zm)[17] = (float(*)[17])smem;
                float (*Zp)[17] = (float(*)[17])(smem + 272);
                int m = bx * 16 + ty4, p = by * 16 + tx4;
                float d = 0.0f;
                for (int qc = 0; qc < 12; qc++) {
                    int q0 = qc * 16;
                    float inv_ls = 1.0f / kern_ls[q0 + tx4];
                    Zm[ty4][tx4] = Z[(bx * 16 + ty4) * DIN + q0 + tx4] * inv_ls;
                    Zp[ty4][tx4] = Z[(by * 16 + ty4) * DIN + q0 + tx4] * inv_ls;
                    __syncthreads();
                    #pragma unroll
                    for (int k = 0; k < 16; k++) { float t = Zm[ty4][k] - Zp[tx4][k]; d = fmaf(t, t, d); }
                    __syncthreads();
                }
                ws[OFF_D2ZZ + m * MM + p] = d;
                ws[OFF_KUU  + m * MM + p] = kv * __expf(-0.5f * d) + ((m == p) ? JITTER : 0.0f);
            } else if (vb < 144 + 1128) {
                if (cnt1 != 0) {
                    int t = vb - 144, bx = t % 94, by = t / 94;
                    int n = bx * 16 + ty4, m = by * 16 + tx4;
                    float (*Ps)[17]  = (float(*)[17])smem;
                    float (*Rs)[17]  = (float(*)[17])(smem + 272);
                    float (*Zs)[17]  = (float(*)[17])(smem + 544);
                    float (*Z2s)[17] = (float(*)[17])(smem + 816);
                    float dot1 = 0.0f, dot2 = 0.0f;
                    for (int qc = 0; qc < 12; qc++) {
                        int q0 = qc * 16;
                        Ps[ty4][tx4] = (n < NR) ? ws[OFF_P1 + n * DIN + q0 + tx4] : 0.0f;
                        Rs[ty4][tx4] = (n < NR) ? ws[OFF_R1 + n * DIN + q0 + tx4] : 0.0f;
                        float z = Z[(by * 16 + ty4) * DIN + q0 + tx4];
                        Zs[ty4][tx4] = z; Z2s[ty4][tx4] = z * z;
                        __syncthreads();
                        #pragma unroll
                        for (int k = 0; k < 16; k++) {
                            dot1 = fmaf(Ps[ty4][k], Zs[tx4][k], dot1);
                            dot2 = fmaf(Rs[ty4][k], Z2s[tx4][k], dot2);
                        }
                        __syncthreads();
                    }
                    if (n < NR) ws[OFF_PSI1 + n * MM + m] = kv * __expf(ws[OFF_S1 + n] + dot1 - 0.5f * dot2);
                }
            } else {
                if (cnt2 != 0) {
                    int t = vb - (144 + 1128), bx = t % 94, by = t / 94;
                    int n = bx * 16 + ty4, m = by * 16 + tx4;
                    float (*Us)[17] = (float(*)[17])smem;
                    float (*Ws)[17] = (float(*)[17])(smem + 272);
                    float (*Zb)[17] = (float(*)[17])(smem + 544);
                    float dotB = 0.0f, dotC = 0.0f;
                    for (int qc = 0; qc < 12; qc++) {
                        int q0 = qc * 16;
                        Us[ty4][tx4] = (n < NR) ? ws[OFF_WU2 + n * DIN + q0 + tx4] : 0.0f;
                        Ws[ty4][tx4] = (n < NR) ? ws[OFF_W2  + n * DIN + q0 + tx4] : 0.0f;
                        Zb[ty4][tx4] = Z[(by * 16 + ty4) * DIN + q0 + tx4];
                        __syncthreads();
                        #pragma unroll
                        for (int k = 0; k < 16; k++) {
                            float z = Zb[tx4][k];
                            dotB = fmaf(z, Us[ty4][k], dotB);
                            dotC = fmaf(z * z, Ws[ty4][k], dotC);
                        }
                        __syncthreads();
                    }
                    if (n < NR) ws[OFF_F + n * MM + m] = fmaf(-0.25f, dotC, dotB);
                }
            }
        }
        grid_sync(ws, 1);
        // -------- Phase C: G rows + psi2 tiles (or exact-zero fill) --------
        for (int vb = blockIdx.x; vb < 192 + 36; vb += nblk) {
            if (vb < 192) {
                if (cnt1 != 0) {
                    int m = vb;
                    const float* psi1 = ws + OFF_PSI1;
                    float g[QD];
                    #pragma unroll
                    for (int d = 0; d < QD; d++) g[d] = 0.0f;
                    for (int n = tid; n < NR; n += 256) {
                        float p = psi1[n * MM + m];
                        const float* xr = X_mean + (LT + n) * QD;
                        #pragma unroll
                        for (int d = 0; d < QD; d++) g[d] = fmaf(p, xr[d], g[d]);
                    }
                    float* red = smem;   // 256 floats
                    bool any = false;
                    for (int d = 0; d < QD; d++) {
                        red[tid] = g[d]; __syncthreads();
                        if (tid < 128) red[tid] += red[tid + 128];
                        __syncthreads();
                        if (tid < 64) {
                            float s = red[tid] + red[tid + 64];
                            s = wave_reduce(s);
                            if (tid == 0) { ws[OFF_G + m * QD + d] = s; any |= (s != 0.0f); }
                        }
                        __syncthreads();
                    }
                    if (tid == 0 && any) atomicOr((int*)(ws + OFF_SCAL) + 14, 1);
                }
            } else {
                int t = vb - 192, bx = t / 6, by = t - 6 * bx;
                int m0 = bx * 32, p0 = by * 32;
                int mA = m0 + 2 * ty4, pA = p0 + 2 * tx4;
                float* P2 = ws + OFF_PSI2;
                if (cnt2 == 0) {   // slow path => cnt1>0; chol-C2 may read psi2
                    P2[(mA    ) * MM + pA    ] = 0.0f;
                    P2[(mA    ) * MM + pA + 1] = 0.0f;
                    P2[(mA + 1) * MM + pA    ] = 0.0f;
                    P2[(mA + 1) * MM + pA + 1] = 0.0f;
                    __syncthreads();
                } else {
                    float a00 = 0, a01 = 0, a10 = 0, a11 = 0;
                    float* Zm = smem;             // 32*ZR
                    float* Zp = smem + 32 * ZR;   // 32*ZR
                    for (int idx = tid; idx < 32 * DIN; idx += 256) {
                        int r = idx / DIN, q = idx - r * DIN;
                        Zm[r * ZR + q] = Z[(m0 + r) * DIN + q];
                        Zp[r * ZR + q] = Z[(p0 + r) * DIN + q];
                    }
                    __syncthreads();
                    const float* w2base = ws + OFF_W2;
                    const float* F      = ws + OFF_F;
                    const float* s2arr  = ws + OFF_S2;
                    const int* list     = (const int*)(ws + OFF_NLIST);
                    const float4* zm0 = (const float4*)(Zm + (2 * ty4    ) * ZR);
                    const float4* zm1 = (const float4*)(Zm + (2 * ty4 + 1) * ZR);
                    const float4* zp0 = (const float4*)(Zp + (2 * tx4    ) * ZR);
                    const float4* zp1 = (const float4*)(Zp + (2 * tx4 + 1) * ZR);
                    for (int li = 0; li < cnt2; li++) {
                        int n = list[li];
                        const float4* w2p = (const float4*)(w2base + n * DIN);
                        float e00 = 0, e01 = 0, e10 = 0, e11 = 0;
                        #pragma unroll 4
                        for (int g = 0; g < DIN / 4; g++) {
                            float4 w = w2p[g];
                            float4 a = zm0[g], b = zm1[g], c = zp0[g], d = zp1[g];
                            float wp0, wp1;
                            wp0 = w.x * c.x; wp1 = w.x * d.x;
                            e00 = fmaf(a.x, wp0, e00); e01 = fmaf(a.x, wp1, e01);
                            e10 = fmaf(b.x, wp0, e10); e11 = fmaf(b.x, wp1, e11);
                            wp0 = w.y * c.y; wp1 = w.y * d.y;
                            e00 = fmaf(a.y, wp0, e00); e01 = fmaf(a.y, wp1, e01);
                            e10 = fmaf(b.y, wp0, e10); e11 = fmaf(b.y, wp1, e11);
                            wp0 = w.z * c.z; wp1 = w.z * d.z;
                            e00 = fmaf(a.z, wp0, e00); e01 = fmaf(a.z, wp1, e01);
                            e10 = fmaf(b.z, wp0, e10); e11 = fmaf(b.z, wp1, e11);
                            wp0 = w.w * c.w; wp1 = w.w * d.w;
                            e00 = fmaf(a.w, wp0, e00); e01 = fmaf(a.w, wp1, e01);
                            e10 = fmaf(b.w, wp0, e10); e11 = fmaf(b.w, wp1, e11);
                        }
                        float s2n = s2arr[n];
                        float Fm0 = F[n * MM + mA], Fm1 = F[n * MM + mA + 1];
                        float Fp0 = F[n * MM + pA], Fp1 = F[n * MM + pA + 1];
                        a00 += __expf(s2n + Fm0 + Fp0 - 0.5f * e00);
                        a01 += __expf(s2n + Fm0 + Fp1 - 0.5f * e01);
                        a10 += __expf(s2n + Fm1 + Fp0 - 0.5f * e10);
                        a11 += __expf(s2n + Fm1 + Fp1 - 0.5f * e11);
                    }
                    float kv2 = kv * kv;
                    const float* dz = ws + OFF_D2ZZ;
                    P2[(mA    ) * MM + pA    ] = kv2 * __expf(-0.25f * dz[(mA    ) * MM + pA    ]) * a00;
                    P2[(mA    ) * MM + pA + 1] = kv2 * __expf(-0.25f * dz[(mA    ) * MM + pA + 1]) * a01;
                    P2[(mA + 1) * MM + pA    ] = kv2 * __expf(-0.25f * dz[(mA + 1) * MM + pA    ]) * a10;
                    P2[(mA + 1) * MM + pA + 1] = kv2 * __expf(-0.25f * dz[(mA + 1) * MM + pA + 1]) * a11;
                    __syncthreads();
                }
            }
        }
        grid_sync(ws, 2);
        const int gflag = LDWSI((const int*)(ws + OFF_SCAL) + 14);
        // -------- Phase D: dual blocked LDL^T in GLOBAL scratch --------
        if (blockIdx.x < 2 && (cnt2 != 0 || gflag != 0)) {
            bool isC2 = (blockIdx.x == 1);
            float* A = ws + OFF_CHA + (size_t)blockIdx.x * (MM * ALD);
            const float* Kuu  = ws + OFF_KUU;
            const float* psi2 = ws + OFF_PSI2;
            float inv_s2 = 1.0f / (*lik);
            for (int idx = tid; idx < MM * MM; idx += 256) {
                int i = idx / MM, j = idx - i * MM;
                float v = Kuu[idx];
                if (isC2) v = fmaf(psi2[idx], inv_s2, v);
                A[i * ALD + j] = v;
            }
            __syncthreads();
            float logacc = 0.0f;
            for (int p = 0; p < MM / NB; p++) {
                int k0 = p * NB;
                int e  = k0 + NB;
                if (tid < 64) {
                    int l64 = tid;
                    float P[3][NB];
                    #pragma unroll
                    for (int s = 0; s < 3; s++) {
                        int r = l64 + 64 * s;
                        #pragma unroll
                        for (int g = 0; g < NB / 4; g++) {
                            float4 v = *(const float4*)&A[r * ALD + k0 + 4 * g];
                            P[s][4*g] = v.x; P[s][4*g+1] = v.y; P[s][4*g+2] = v.z; P[s][4*g+3] = v.w;
                        }
                    }
                    int sD = k0 >> 6;
                    int lD = k0 & 63;
                    #pragma unroll
                    for (int c = 0; c < NB; c++) {
                        int k = k0 + c;
                        float colc = (sD == 0) ? P[0][c] : ((sD == 1) ? P[1][c] : P[2][c]);
                        float dkk = __shfl(colc, lD + c);
                        float inv = 1.0f / dkk;
                        logacc += logf(dkk);
                        float m0 = (l64       > k) ? P[0][c] * inv : 0.0f;
                        float m1 = (l64 + 64  > k) ? P[1][c] * inv : 0.0f;
                        float m2 = (l64 + 128 > k) ? P[2][c] * inv : 0.0f;
                        P[0][c] = (l64       > k) ? m0 : P[0][c];
                        P[1][c] = (l64 + 64  > k) ? m1 : P[1][c];
                        P[2][c] = (l64 + 128 > k) ? m2 : P[2][c];
                        #pragma unroll
                        for (int j = c + 1; j < NB; j++) {
                            float w = __shfl(colc, lD + j);
                            P[0][j] = fmaf(-m0, w, P[0][j]);
                            P[1][j] = fmaf(-m1, w, P[1][j]);
                            P[2][j] = fmaf(-m2, w, P[2][j]);
                        }
                    }
                    #pragma unroll
                    for (int s = 0; s < 3; s++) {
                        int r = l64 + 64 * s;
                        #pragma unroll
                        for (int g = 0; g < NB / 4; g++) {
                            float4 v = make_float4(P[s][4*g], P[s][4*g+1], P[s][4*g+2], P[s][4*g+3]);
                            *(float4*)&A[r * ALD + k0 + 4 * g] = v;
                        }
                    }
                }
                __syncthreads();
                int T = MM - e;
                if (T > 0) {
                    for (int idx = tid; idx < NB * T; idx += 256) {
                        int c = idx / T, j = e + (idx - c * T);
                        float d = A[(k0 + c) * ALD + (k0 + c)];
                        A[(k0 + c) * ALD + j] = A[j * ALD + k0 + c] * sqrtf(d);
                    }
                    __syncthreads();
                    int nT = (T + 127) / 128;
                    for (int bi = 0; bi < nT; bi++)
                    for (int bj = 0; bj < nT; bj++) {
                        int i0 = e + 128 * bi + 8 * ty4;
                        int j0 = e + 128 * bj + 8 * tx4;
                        int ic = (i0 < MM - 8) ? i0 : (MM - 8);
                        int jc = (j0 < MM - 8) ? j0 : (MM - 8);
                        float4 acc[8][2];
                        #pragma unroll
                        for (int r = 0; r < 8; r++) {
                            acc[r][0] = *(const float4*)&A[(ic + r) * ALD + jc];
                            acc[r][1] = *(const float4*)&A[(ic + r) * ALD + jc + 4];
                        }
                        #pragma unroll 4
                        for (int c = 0; c < NB; c++) {
                            const float* row = &A[(k0 + c) * ALD];
                            float4 av0 = *(const float4*)&row[ic];
                            float4 av1 = *(const float4*)&row[ic + 4];
                            float4 bv0 = *(const float4*)&row[jc];
                            float4 bv1 = *(const float4*)&row[jc + 4];
                            float avs[8] = {av0.x, av0.y, av0.z, av0.w, av1.x, av1.y, av1.z, av1.w};
                            #pragma unroll
                            for (int r = 0; r < 8; r++) {
                                float a = avs[r];
                                acc[r][0].x = fmaf(-a, bv0.x, acc[r][0].x);
                                acc[r][0].y = fmaf(-a, bv0.y, acc[r][0].y);
                                acc[r][0].z = fmaf(-a, bv0.z, acc[r][0].z);
                                acc[r][0].w = fmaf(-a, bv0.w, acc[r][0].w);
                                acc[r][1].x = fmaf(-a, bv1.x, acc[r][1].x);
                                acc[r][1].y = fmaf(-a, bv1.y, acc[r][1].y);
                                acc[r][1].z = fmaf(-a, bv1.z, acc[r][1].z);
                                acc[r][1].w = fmaf(-a, bv1.w, acc[r][1].w);
                            }
                        }
                        if (ic == i0 && jc == j0) {
                            #pragma unroll
                            for (int r = 0; r < 8; r++) {
                                *(float4*)&A[(i0 + r) * ALD + j0]     = acc[r][0];
                                *(float4*)&A[(i0 + r) * ALD + j0 + 4] = acc[r][1];
                            }
                        }
                    }
                    __syncthreads();
                }
            }
            float* dst = ws + (isC2 ? OFF_LC2 : OFF_LC);
            for (int idx = tid; idx < MM * MM; idx += 256) {
                int i = idx / MM, j = idx - i * MM;
                dst[idx] = A[i * ALD + j];
            }
            if (tid == 0) STWSF(&ws[OFF_SCAL + (isC2 ? 8 : 7)], 0.5f * logacc);
        }
        grid_sync(ws, 3);
        // -------- Phase E: triangular solves (wave-per-column) --------
        for (int u = blockIdx.x * 4 + wav; u < MM + QD; u += nblk * 4) {
            if (u < MM) {
                if (cnt2 != 0) {
                    const float* L = ws + OFF_LC;
                    float* V = ws + OFF_V;
                    int j = u;
                    int k0 = j + lane, k1 = k0 + 64, k2 = k0 + 128;
                    float x0 = 0, x1 = 0, x2 = 0;
                    for (int i = j; i < MM; i++) {
                        const float* Lr = L + i * MM;
                        float s = 0.0f;
                        if (k0 < i) s = fmaf(Lr[k0], x0, s);
                        if (k1 < i) s = fmaf(Lr[k1], x1, s);
                        if (k2 < i) s = fmaf(Lr[k2], x2, s);
                        #pragma unroll
                        for (int off = 1; off < 64; off <<= 1) s += __shfl_xor(s, off);
                        float xi = ((i == j) ? 1.0f : 0.0f) - s;
                        if (k0 == i) x0 = xi;
                        if (k1 == i) x1 = xi;
                        if (k2 == i) x2 = xi;
                        if (lane == 0) V[i * MM + j] = xi;
                    }
                }
            } else if (gflag != 0) {
                const float* L = ws + OFF_LC2;
                const float* G = ws + OFF_G;
                int c = u - MM;
                int k0 = lane, k1 = lane + 64, k2 = lane + 128;
                float x0 = 0, x1 = 0, x2 = 0, ss = 0;
                for (int i = 0; i < MM; i++) {
                    const float* Lr = L + i * MM;
                    float s = 0.0f;
                    if (k0 < i) s = fmaf(Lr[k0], x0, s);
                    if (k1 < i) s = fmaf(Lr[k1], x1, s);
                    if (k2 < i) s = fmaf(Lr[k2], x2, s);
                    #pragma unroll
                    for (int off = 1; off < 64; off <<= 1) s += __shfl_xor(s, off);
                    float xi = G[i * QD + c] - s;
                    if (k0 == i) x0 = xi;
                    if (k1 == i) x1 = xi;
                    if (k2 == i) x2 = xi;
                    if (lane == 0) ss += xi * xi / Lr[i];
                }
                if (lane == 0) atomicAdd(&ws[OFF_SCAL + 2], ss);
            }
        }
        grid_sync(ws, 4);
        // -------- Phase F: trace_raw --------
        if (cnt2 != 0) {
            for (int i = blockIdx.x; i < MM; i += nblk) {
                float* vrow = smem;         // 192
                float* red  = smem + 192;   // 256
                const float* V = ws + OFF_V;
                const float* P = ws + OFF_PSI2;
                for (int a = tid; a < MM; a += 256) vrow[a] = (a <= i) ? V[i * MM + a] : 0.0f;
                __syncthreads();
                float acc = 0.0f;
                for (int a = tid; a <= i; a += 256) {
                    const float* Pr = P + a * MM;
                    float inner = 0.0f;
                    for (int b = 0; b <= i; b++) inner = fmaf(Pr[b], vrow[b], inner);
                    acc = fmaf(vrow[a], inner, acc);
                }
                red[tid] = acc; __syncthreads();
                if (tid < 128) red[tid] += red[tid + 128];
                __syncthreads();
                if (tid < 64) {
                    float s = red[tid] + red[tid + 64];
                    s = wave_reduce(s);
                    if (tid == 0) { float di = ws[OFF_LC + i * MM + i]; atomicAdd(&ws[OFF_SCAL + 0], s / di); }
                }
                __syncthreads();
            }
        }
        grid_sync(ws, 5);
    }

    // ---------------- Final assembly (block 0, all 256 threads) ----------------
    if (blockIdx.x == 0) {
        // thread t reads BSUM[t], [t+256], [t+512], [t+768] -> component t&3
        float s = 0.0f;
        #pragma unroll
        for (int r = 0; r < 4; r++) s += LDWSF(ws + OFF_BSUM + tid + 256 * r);
        // sum over lanes with equal (lane & 3) within the wave
        s += __shfl_xor(s, 4); s += __shfl_xor(s, 8);
        s += __shfl_xor(s, 16); s += __shfl_xor(s, 32);
        float* fin = smem;   // 16 floats: [wave][component]
        __syncthreads();
        if (lane < 4) fin[wav * 4 + lane] = s;
        __syncthreads();
        if (tid == 0) {
            float Svo  = fin[0] + fin[4] + fin[8]  + fin[12];
            float Smo2 = fin[1] + fin[5] + fin[9]  + fin[13];
            float Slog = fin[2] + fin[6] + fin[10] + fin[14];
            float Smb  = fin[3] + fin[7] + fin[11] + fin[15];
            // slots 0/2/7/8 are memset-zeroed; nonzero only if slow path ran
            float trRaw = LDWSF(ws + OFF_SCAL + 0);
            float ssY   = LDWSF(ws + OFF_SCAL + 2);
            float ldK   = LDWSF(ws + OFF_SCAL + 7);
            float ldC2  = LDWSF(ws + OFF_SCAL + 8);
            float kv = *kern_var, s2v = *lik;
            float inv_s2 = 1.0f / s2v;
            const float lp2pi = 1.8378770664093453f;  // log(2*pi)
            float trA = trRaw * inv_s2;
            float ldB = 2.0f * (ldC2 - ldK);
            float sc2 = ssY * inv_s2 * inv_s2;
            float ND = 18000.0f;   // (Nt-Lt)*D
            float Df = 12.0f;
            float bound = -0.5f * ND * (lp2pi + logf(s2v));
            bound += -0.5f * inv_s2 * (Svo + Smo2);
            bound += -0.5f * Df * ((kv * 1500.0f) * inv_s2 - trA);
            bound += -0.5f * Df * ldB;
            bound += 0.5f * sc2;
            bound += 0.5f * Slog + 0.5f * ND * lp2pi;      // ent
            bound += -96.0f * lp2pi - 0.5f * Smb;          // ent2 (Lt*D = 96)
            out[0] = bound;
        }
    }
}

extern "C" void kernel_launch(void* const* d_in, const int* in_sizes, int n_in,
                              void* d_out, int out_size, void* d_ws, size_t ws_size,
                              hipStream_t stream)
{
    const float* Xm_m    = (const float*)d_in[1];
    const float* Xm_v    = (const float*)d_in[2];
    const float* Z       = (const float*)d_in[3];
    const float* X_mean  = (const float*)d_in[4];
    const float* X_var   = (const float*)d_in[5];
    const float* kern_var= (const float*)d_in[6];
    const float* kern_ls = (const float*)d_in[7];
    const float* lik_var = (const float*)d_in[8];
    float* ws  = (float*)d_ws;
    float* out = (float*)d_out;

    // zero scalar slots (64 floats incl. pad) + 7 phases of tree-barrier state
    hipMemsetAsync(ws + OFF_SCAL, 0, (64 + 7 * BAR_STRIDE) * sizeof(float), stream);

    k_fused<<<FGRID, 256, 0, stream>>>(Xm_m, Xm_v, Z, X_mean, X_var,
                                       kern_var, kern_ls, lik_var, ws, out);
}

// Round 5
// 79.347 us; speedup vs baseline: 1.6564x; 1.0527x over previous
//
#include <hip/hip_runtime.h>
#include <math.h>

// Problem dims (fixed by setup_inputs)
#define NR   1500     // rows of X_m  (Nt - Lt)
#define NTT  1508     // Nt
#define QD   12       // D
#define LT   8
#define DIN  192      // 2*Lt*Q
#define MM   192      // M
#define JITTER 1e-6f
// Exact per-row suprema: psi1 expo <= logdet1[n], psi2 expo <= logdet2[n].
// Rows below this cut contribute < e^-30 ~ 1e-13 each -> provably < 1e-6 relative.
#define PRUNE_CUT -30.0f

// ---- workspace layout (float offsets) ----
#define OFF_W2    0
#define OFF_WU2   288000
#define OFF_P1    576000
#define OFF_R1    864000
#define OFF_S1    1152000
#define OFF_S2    1153500
#define OFF_V     1155000
#define OFF_D2ZZ  1191864
#define OFF_KUU   1228728
#define OFF_PSI1  1265592
#define OFF_PSI2  1553592
#define OFF_LC    1590456
#define OFF_LC2   1627320
#define OFF_G     1664184
#define OFF_NLIST 1666520     // 1500 ints: surviving-n list for psi2 (no zeroing needed)
#define OFF_BSUM  1668032     // 256 blocks x 4 per-block input-sum partials (all written)
#define OFF_F     1669056     // 288000 floats (de-aliased from P1)
#define OFF_CHA   1957056     // 2 x MM*ALD global scratch for Phase D chol
#define OFF_SCAL  2032384     // 16 floats (zeroed each replay by memset)
#define OFF_BARX  2032448     // tree-barrier state: 7 phases x 65 lines x 64 ints
                              // phase 0 zeroed by memset; phases 1-6 zeroed in-kernel
// scal slots: 0 trace_raw, 2 ||Y||^2, 7 0.5*logdetKuu, 8 0.5*logdetC2,
//             12 cnt2 (psi2 survivors), 13 cnt1 (psi1 survivors), 14 gflag

#define BAR_STRIDE 4160       // ints per barrier phase: (32 leaf + 1 root + 32 flag) x 64

// Agent-scope relaxed atomics: on gfx940+ these carry sc1 (execute/read at the
// coherent point, bypassing the non-coherent per-XCD L2) -> cross-block coherent
// WITHOUT fences. All fast-path cross-block traffic uses these.
#define LDWSF(p)    __hip_atomic_load((p), __ATOMIC_RELAXED, __HIP_MEMORY_SCOPE_AGENT)
#define LDWSI(p)    __hip_atomic_load((p), __ATOMIC_RELAXED, __HIP_MEMORY_SCOPE_AGENT)
#define STWSF(p,v)  __hip_atomic_store((p), (v), __ATOMIC_RELAXED, __HIP_MEMORY_SCOPE_AGENT)
#define STWSI(p,v)  __hip_atomic_store((p), (v), __ATOMIC_RELAXED, __HIP_MEMORY_SCOPE_AGENT)

__device__ __forceinline__ float wave_reduce(float s) {
    s += __shfl_down(s, 32); s += __shfl_down(s, 16); s += __shfl_down(s, 8);
    s += __shfl_down(s, 4);  s += __shfl_down(s, 2);  s += __shfl_down(s, 1);
    return s;
}
__device__ __forceinline__ float bfly_sum(float s) {
    s += __shfl_xor(s, 32); s += __shfl_xor(s, 16); s += __shfl_xor(s, 8);
    s += __shfl_xor(s, 4);  s += __shfl_xor(s, 2);  s += __shfl_xor(s, 1);
    return s;
}

// Grid barrier v4: fence-FREE two-level tree (fast-path critical).
//  - all barrier state accessed via agent-scope RMWs (coherent point; no L2
//    writeback/invalidate needed -> removes 256x {wbl2+invl2} vs v3)
//  - __syncthreads before arrival drains vmcnt -> this block's sc1 stores
//    (BSUM) and device-scope atomicAdds (cnts) are globally visible before
//    its arrival RMW: message-passing-via-coherent-point pattern
//  - returns is_last (global last arriver) so the last block can run the
//    fast-path final assembly immediately (no poll-wake hop)
//  - plain (non-sc1) stores are NOT published by this barrier; the slow path
//    wraps its syncs with agent fences (slow_sync) before reading them.
// Co-residency: grid=256 <= 256 CUs, 49KB LDS -> all blocks resident.
__device__ __forceinline__ bool grid_sync(float* ws, int k, int* s_last) {
    __syncthreads();   // compiler emits s_waitcnt vmcnt(0) lgkmcnt(0) + s_barrier
    if (threadIdx.x == 0) {
        int* base  = (int*)(ws + OFF_BARX) + k * BAR_STRIDE;
        int  g     = (int)(blockIdx.x & 31);
        int* leaf  = base + g * 64;
        int* root  = base + 32 * 64;
        int* dflag = base + (33 + g) * 64;
        int last = 0;
        if (__hip_atomic_fetch_add(leaf, 1, __ATOMIC_RELAXED, __HIP_MEMORY_SCOPE_AGENT) == 7) {
            if (__hip_atomic_fetch_add(root, 1, __ATOMIC_RELAXED, __HIP_MEMORY_SCOPE_AGENT) == 31) {
                last = 1;
                #pragma unroll
                for (int i = 0; i < 32; i++)
                    __hip_atomic_fetch_add(base + (33 + i) * 64, 1,
                                           __ATOMIC_RELAXED, __HIP_MEMORY_SCOPE_AGENT);
            }
        }
        if (!last) {
            while (__hip_atomic_fetch_add(dflag, 0, __ATOMIC_RELAXED, __HIP_MEMORY_SCOPE_AGENT) == 0)
                __builtin_amdgcn_s_sleep(4);
        }
        *s_last = last;
    }
    __syncthreads();
    return *s_last != 0;
}

// Slow-path sync: full publish semantics for plain stores (release: L2 wb;
// acquire: L2 inv). Only used when cnt1|cnt2 != 0 (never on bench data).
__device__ __forceinline__ void slow_sync(float* ws, int k, int* s_last) {
    __builtin_amdgcn_fence(__ATOMIC_RELEASE, "agent");
    grid_sync(ws, k, s_last);
    __builtin_amdgcn_fence(__ATOMIC_ACQUIRE, "agent");
}

#define ALD 196
#define NB  32
#define ZR  196
#define FGRID 256

// ============================================================================
// Fused kernel: the whole dependency chain in ONE ordinary dispatch.
// Fast path (cnt1==cnt2==0, true for the bench data): prep+sums -> 1 fence-free
// grid sync -> final assembly by the last arriver. Slow path keeps all phases,
// separated by fenced syncs. Phase D (chol) uses global-ws scratch (49KB LDS).
// ============================================================================
__global__ __launch_bounds__(256) void k_fused(
    const float* __restrict__ Xm_m, const float* __restrict__ Xm_v,
    const float* __restrict__ Z, const float* __restrict__ X_mean,
    const float* __restrict__ X_var, const float* __restrict__ kern_var,
    const float* __restrict__ kern_ls, const float* __restrict__ lik,
    float* __restrict__ ws, float* __restrict__ out)
{
    __shared__ __align__(16) float smem[2 * 32 * ZR];   // 49 KB, union for all phases
    __shared__ int s_last;
    const int tid  = threadIdx.x;
    const int lane = tid & 63;
    const int wav  = tid >> 6;
    const int nblk = gridDim.x;
    const int ty4  = tid >> 4, tx4 = tid & 15;

    // ---- zero barrier phases 1-6 (sc1 stores; drained before sync-0 arrival,
    //      consumed only after sync 0 -> ordered) ----
    {
        int idx = blockIdx.x * 256 + tid;
        if (idx < 6 * BAR_STRIDE)
            STWSI((int*)(ws + OFF_BARX) + BAR_STRIDE + idx, 0);
    }

    // ---------------- Phase A: per-n prep + input sums ----------------
    for (int n = blockIdx.x * 4 + wav; n < NR; n += nblk * 4) {
        float v0 = 0, v1 = 0, v2 = 0, v3 = 0;
        #pragma unroll
        for (int s = 0; s < 3; s++) {
            int q = lane + 64 * s;
            float u, v;
            if (q < 96) { u = X_mean[n * QD + q]; v = X_var[n * QD + q]; }
            else        { int j = q - 96; u = Xm_m[(1 + n) * QD + j]; v = Xm_v[(1 + n) * QD + j]; }
            float ls = kern_ls[q]; float l2 = ls * ls;
            float d1 = l2 + v, d2 = l2 + 2.0f * v;
            float i1 = 1.0f / d1, i2 = 1.0f / d2;
            ws[OFF_P1  + n * DIN + q] = u * i1;
            ws[OFF_R1  + n * DIN + q] = i1;
            ws[OFF_W2  + n * DIN + q] = i2;
            ws[OFF_WU2 + n * DIN + q] = u * i2;
            v0 += log1pf(v / l2);
            v1 += log1pf(2.0f * v / l2);
            v2 += u * u * i1;
            v3 += u * u * i2;
        }
        v0 = bfly_sum(v0); v1 = bfly_sum(v1); v2 = bfly_sum(v2); v3 = bfly_sum(v3);
        if (lane == 0) {
            ws[OFF_S1 + n] = -0.5f * (v0 + v2);
            ws[OFF_S2 + n] = -0.5f * v1 - v3;
            float ld1 = -0.5f * v0;                // exact sup of psi1 exponent
            float ld2 = -0.5f * v1;                // exact sup of psi2 exponent
            int* cnts = (int*)(ws + OFF_SCAL);
            if (ld1 > PRUNE_CUT) atomicAdd(&cnts[13], 1);
            if (ld2 > PRUNE_CUT) {
                int idx = atomicAdd(&cnts[12], 1);
                ((int*)(ws + OFF_NLIST))[idx] = n;
            }
        }
    }
    {   // input sums (Svo, Smo2, Slog, Smb) -> per-block partials, no atomics
        float pVo = 0, pMo = 0, pLg = 0, pMb = 0;
        for (int idx = blockIdx.x * 256 + tid; idx < NTT * QD; idx += nblk * 256) {
            float xm = X_mean[idx], xv = X_var[idx];
            if (idx >= LT * QD) { pVo += xv; pMo += xm * xm; pLg += logf(xv); }
            else                { pMb += xm * xm + xv; }
        }
        pVo = bfly_sum(pVo); pMo = bfly_sum(pMo); pLg = bfly_sum(pLg); pMb = bfly_sum(pMb);
        float* part = smem;   // 16 floats
        if (lane == 0) { part[wav*4+0] = pVo; part[wav*4+1] = pMo; part[wav*4+2] = pLg; part[wav*4+3] = pMb; }
        __syncthreads();
        if (tid < 4) {
            float s = part[tid] + part[4 + tid] + part[8 + tid] + part[12 + tid];
            STWSF(&ws[OFF_BSUM + blockIdx.x * 4 + tid], s);   // sc1 store
        }
        __syncthreads();
    }
    const bool last0 = grid_sync(ws, 0, &s_last);   // fence-free

    const int* scal_i = (const int*)(ws + OFF_SCAL);
    const int cnt1 = LDWSI(scal_i + 13);
    const int cnt2 = LDWSI(scal_i + 12);

    bool do_final = last0;

    if ((cnt1 | cnt2) != 0) {
        // =================== SLOW PATH (not exercised by bench data) =========
        do_final = (blockIdx.x == 0);
        // publish Phase A's plain stores (P1/R1/W2/WU2/S1/S2/NLIST) grid-wide
        slow_sync(ws, 6, &s_last);
        float kv = *kern_var;
        // -------- Phase B: Kuu/d2zz tiles + psi1 tiles + F tiles --------
        for (int vb = blockIdx.x; vb < 144 + 2 * 1128; vb += nblk) {
            if (vb < 144) {
                int bx = vb / 12, by = vb - bx * 12;
                float (*Zm)[17] = (float(*)[17])smem;
                float (*Zp)[17] = (float(*)[17])(smem + 272);
                int m = bx * 16 + ty4, p = by * 16 + tx4;
                float d = 0.0f;
                for (int qc = 0; qc < 12; qc++) {
                    int q0 = qc * 16;
                    float inv_ls = 1.0f / kern_ls[q0 + tx4];
                    Zm[ty4][tx4] = Z[(bx * 16 + ty4) * DIN + q0 + tx4] * inv_ls;
                    Zp[ty4][tx4] = Z[(by * 16 + ty4) * DIN + q0 + tx4] * inv_ls;
                    __syncthreads();
                    #pragma unroll
                    for (int k = 0; k < 16; k++) { float t = Zm[ty4][k] - Zp[tx4][k]; d = fmaf(t, t, d); }
                    __syncthreads();
                }
                ws[OFF_D2ZZ + m * MM + p] = d;
                ws[OFF_KUU  + m * MM + p] = kv * __expf(-0.5f * d) + ((m == p) ? JITTER : 0.0f);
            } else if (vb < 144 + 1128) {
                if (cnt1 != 0) {
                    int t = vb - 144, bx = t % 94, by = t / 94;
                    int n = bx * 16 + ty4, m = by * 16 + tx4;
                    float (*Ps)[17]  = (float(*)[17])smem;
                    float (*Rs)[17]  = (float(*)[17])(smem + 272);
                    float (*Zs)[17]  = (float(*)[17])(smem + 544);
                    float (*Z2s)[17] = (float(*)[17])(smem + 816);
                    float dot1 = 0.0f, dot2 = 0.0f;
                    for (int qc = 0; qc < 12; qc++) {
                        int q0 = qc * 16;
                        Ps[ty4][tx4] = (n < NR) ? ws[OFF_P1 + n * DIN + q0 + tx4] : 0.0f;
                        Rs[ty4][tx4] = (n < NR) ? ws[OFF_R1 + n * DIN + q0 + tx4] : 0.0f;
                        float z = Z[(by * 16 + ty4) * DIN + q0 + tx4];
                        Zs[ty4][tx4] = z; Z2s[ty4][tx4] = z * z;
                        __syncthreads();
                        #pragma unroll
                        for (int k = 0; k < 16; k++) {
                            dot1 = fmaf(Ps[ty4][k], Zs[tx4][k], dot1);
                            dot2 = fmaf(Rs[ty4][k], Z2s[tx4][k], dot2);
                        }
                        __syncthreads();
                    }
                    if (n < NR) ws[OFF_PSI1 + n * MM + m] = kv * __expf(ws[OFF_S1 + n] + dot1 - 0.5f * dot2);
                }
            } else {
                if (cnt2 != 0) {
                    int t = vb - (144 + 1128), bx = t % 94, by = t / 94;
                    int n = bx * 16 + ty4, m = by * 16 + tx4;
                    float (*Us)[17] = (float(*)[17])smem;
                    float (*Ws)[17] = (float(*)[17])(smem + 272);
                    float (*Zb)[17] = (float(*)[17])(smem + 544);
                    float dotB = 0.0f, dotC = 0.0f;
                    for (int qc = 0; qc < 12; qc++) {
                        int q0 = qc * 16;
                        Us[ty4][tx4] = (n < NR) ? ws[OFF_WU2 + n * DIN + q0 + tx4] : 0.0f;
                        Ws[ty4][tx4] = (n < NR) ? ws[OFF_W2  + n * DIN + q0 + tx4] : 0.0f;
                        Zb[ty4][tx4] = Z[(by * 16 + ty4) * DIN + q0 + tx4];
                        __syncthreads();
                        #pragma unroll
                        for (int k = 0; k < 16; k++) {
                            float z = Zb[tx4][k];
                            dotB = fmaf(z, Us[ty4][k], dotB);
                            dotC = fmaf(z * z, Ws[ty4][k], dotC);
                        }
                        __syncthreads();
                    }
                    if (n < NR) ws[OFF_F + n * MM + m] = fmaf(-0.25f, dotC, dotB);
                }
            }
        }
        slow_sync(ws, 1, &s_last);
        // -------- Phase C: G rows + psi2 tiles (or exact-zero fill) --------
        for (int vb = blockIdx.x; vb < 192 + 36; vb += nblk) {
            if (vb < 192) {
                if (cnt1 != 0) {
                    int m = vb;
                    const float* psi1 = ws + OFF_PSI1;
                    float g[QD];
                    #pragma unroll
                    for (int d = 0; d < QD; d++) g[d] = 0.0f;
                    for (int n = tid; n < NR; n += 256) {
                        float p = psi1[n * MM + m];
                        const float* xr = X_mean + (LT + n) * QD;
                        #pragma unroll
                        for (int d = 0; d < QD; d++) g[d] = fmaf(p, xr[d], g[d]);
                    }
                    float* red = smem;   // 256 floats
                    bool any = false;
                    for (int d = 0; d < QD; d++) {
                        red[tid] = g[d]; __syncthreads();
                        if (tid < 128) red[tid] += red[tid + 128];
                        __syncthreads();
                        if (tid < 64) {
                            float s = red[tid] + red[tid + 64];
                            s = wave_reduce(s);
                            if (tid == 0) { ws[OFF_G + m * QD + d] = s; any |= (s != 0.0f); }
                        }
                        __syncthreads();
                    }
                    if (tid == 0 && any) atomicOr((int*)(ws + OFF_SCAL) + 14, 1);
                }
            } else {
                int t = vb - 192, bx = t / 6, by = t - 6 * bx;
                int m0 = bx * 32, p0 = by * 32;
                int mA = m0 + 2 * ty4, pA = p0 + 2 * tx4;
                float* P2 = ws + OFF_PSI2;
                if (cnt2 == 0) {   // slow path => cnt1>0; chol-C2 may read psi2
                    P2[(mA    ) * MM + pA    ] = 0.0f;
                    P2[(mA    ) * MM + pA + 1] = 0.0f;
                    P2[(mA + 1) * MM + pA    ] = 0.0f;
                    P2[(mA + 1) * MM + pA + 1] = 0.0f;
                    __syncthreads();
                } else {
                    float a00 = 0, a01 = 0, a10 = 0, a11 = 0;
                    float* Zm = smem;             // 32*ZR
                    float* Zp = smem + 32 * ZR;   // 32*ZR
                    for (int idx = tid; idx < 32 * DIN; idx += 256) {
                        int r = idx / DIN, q = idx - r * DIN;
                        Zm[r * ZR + q] = Z[(m0 + r) * DIN + q];
                        Zp[r * ZR + q] = Z[(p0 + r) * DIN + q];
                    }
                    __syncthreads();
                    const float* w2base = ws + OFF_W2;
                    const float* F      = ws + OFF_F;
                    const float* s2arr  = ws + OFF_S2;
                    const int* list     = (const int*)(ws + OFF_NLIST);
                    const float4* zm0 = (const float4*)(Zm + (2 * ty4    ) * ZR);
                    const float4* zm1 = (const float4*)(Zm + (2 * ty4 + 1) * ZR);
                    const float4* zp0 = (const float4*)(Zp + (2 * tx4    ) * ZR);
                    const float4* zp1 = (const float4*)(Zp + (2 * tx4 + 1) * ZR);
                    for (int li = 0; li < cnt2; li++) {
                        int n = list[li];
                        const float4* w2p = (const float4*)(w2base + n * DIN);
                        float e00 = 0, e01 = 0, e10 = 0, e11 = 0;
                        #pragma unroll 4
                        for (int g = 0; g < DIN / 4; g++) {
                            float4 w = w2p[g];
                            float4 a = zm0[g], b = zm1[g], c = zp0[g], d = zp1[g];
                            float wp0, wp1;
                            wp0 = w.x * c.x; wp1 = w.x * d.x;
                            e00 = fmaf(a.x, wp0, e00); e01 = fmaf(a.x, wp1, e01);
                            e10 = fmaf(b.x, wp0, e10); e11 = fmaf(b.x, wp1, e11);
                            wp0 = w.y * c.y; wp1 = w.y * d.y;
                            e00 = fmaf(a.y, wp0, e00); e01 = fmaf(a.y, wp1, e01);
                            e10 = fmaf(b.y, wp0, e10); e11 = fmaf(b.y, wp1, e11);
                            wp0 = w.z * c.z; wp1 = w.z * d.z;
                            e00 = fmaf(a.z, wp0, e00); e01 = fmaf(a.z, wp1, e01);
                            e10 = fmaf(b.z, wp0, e10); e11 = fmaf(b.z, wp1, e11);
                            wp0 = w.w * c.w; wp1 = w.w * d.w;
                            e00 = fmaf(a.w, wp0, e00); e01 = fmaf(a.w, wp1, e01);
                            e10 = fmaf(b.w, wp0, e10); e11 = fmaf(b.w, wp1, e11);
                        }
                        float s2n = s2arr[n];
                        float Fm0 = F[n * MM + mA], Fm1 = F[n * MM + mA + 1];
                        float Fp0 = F[n * MM + pA], Fp1 = F[n * MM + pA + 1];
                        a00 += __expf(s2n + Fm0 + Fp0 - 0.5f * e00);
                        a01 += __expf(s2n + Fm0 + Fp1 - 0.5f * e01);
                        a10 += __expf(s2n + Fm1 + Fp0 - 0.5f * e10);
                        a11 += __expf(s2n + Fm1 + Fp1 - 0.5f * e11);
                    }
                    float kv2 = kv * kv;
                    const float* dz = ws + OFF_D2ZZ;
                    P2[(mA    ) * MM + pA    ] = kv2 * __expf(-0.25f * dz[(mA    ) * MM + pA    ]) * a00;
                    P2[(mA    ) * MM + pA + 1] = kv2 * __expf(-0.25f * dz[(mA    ) * MM + pA + 1]) * a01;
                    P2[(mA + 1) * MM + pA    ] = kv2 * __expf(-0.25f * dz[(mA + 1) * MM + pA    ]) * a10;
                    P2[(mA + 1) * MM + pA + 1] = kv2 * __expf(-0.25f * dz[(mA + 1) * MM + pA + 1]) * a11;
                    __syncthreads();
                }
            }
        }
        slow_sync(ws, 2, &s_last);
        const int gflag = LDWSI((const int*)(ws + OFF_SCAL) + 14);
        // -------- Phase D: dual blocked LDL^T in GLOBAL scratch --------
        if (blockIdx.x < 2 && (cnt2 != 0 || gflag != 0)) {
            bool isC2 = (blockIdx.x == 1);
            float* A = ws + OFF_CHA + (size_t)blockIdx.x * (MM * ALD);
            const float* Kuu  = ws + OFF_KUU;
            const float* psi2 = ws + OFF_PSI2;
            float inv_s2 = 1.0f / (*lik);
            for (int idx = tid; idx < MM * MM; idx += 256) {
                int i = idx / MM, j = idx - i * MM;
                float v = Kuu[idx];
                if (isC2) v = fmaf(psi2[idx], inv_s2, v);
                A[i * ALD + j] = v;
            }
            __syncthreads();
            float logacc = 0.0f;
            for (int p = 0; p < MM / NB; p++) {
                int k0 = p * NB;
                int e  = k0 + NB;
                if (tid < 64) {
                    int l64 = tid;
                    float P[3][NB];
                    #pragma unroll
                    for (int s = 0; s < 3; s++) {
                        int r = l64 + 64 * s;
                        #pragma unroll
                        for (int g = 0; g < NB / 4; g++) {
                            float4 v = *(const float4*)&A[r * ALD + k0 + 4 * g];
                            P[s][4*g] = v.x; P[s][4*g+1] = v.y; P[s][4*g+2] = v.z; P[s][4*g+3] = v.w;
                        }
                    }
                    int sD = k0 >> 6;
                    int lD = k0 & 63;
                    #pragma unroll
                    for (int c = 0; c < NB; c++) {
                        int k = k0 + c;
                        float colc = (sD == 0) ? P[0][c] : ((sD == 1) ? P[1][c] : P[2][c]);
                        float dkk = __shfl(colc, lD + c);
                        float inv = 1.0f / dkk;
                        logacc += logf(dkk);
                        float m0 = (l64       > k) ? P[0][c] * inv : 0.0f;
                        float m1 = (l64 + 64  > k) ? P[1][c] * inv : 0.0f;
                        float m2 = (l64 + 128 > k) ? P[2][c] * inv : 0.0f;
                        P[0][c] = (l64       > k) ? m0 : P[0][c];
                        P[1][c] = (l64 + 64  > k) ? m1 : P[1][c];
                        P[2][c] = (l64 + 128 > k) ? m2 : P[2][c];
                        #pragma unroll
                        for (int j = c + 1; j < NB; j++) {
                            float w = __shfl(colc, lD + j);
                            P[0][j] = fmaf(-m0, w, P[0][j]);
                            P[1][j] = fmaf(-m1, w, P[1][j]);
                            P[2][j] = fmaf(-m2, w, P[2][j]);
                        }
                    }
                    #pragma unroll
                    for (int s = 0; s < 3; s++) {
                        int r = l64 + 64 * s;
                        #pragma unroll
                        for (int g = 0; g < NB / 4; g++) {
                            float4 v = make_float4(P[s][4*g], P[s][4*g+1], P[s][4*g+2], P[s][4*g+3]);
                            *(float4*)&A[r * ALD + k0 + 4 * g] = v;
                        }
                    }
                }
                __syncthreads();
                int T = MM - e;
                if (T > 0) {
                    for (int idx = tid; idx < NB * T; idx += 256) {
                        int c = idx / T, j = e + (idx - c * T);
                        float d = A[(k0 + c) * ALD + (k0 + c)];
                        A[(k0 + c) * ALD + j] = A[j * ALD + k0 + c] * sqrtf(d);
                    }
                    __syncthreads();
                    int nT = (T + 127) / 128;
                    for (int bi = 0; bi < nT; bi++)
                    for (int bj = 0; bj < nT; bj++) {
                        int i0 = e + 128 * bi + 8 * ty4;
                        int j0 = e + 128 * bj + 8 * tx4;
                        int ic = (i0 < MM - 8) ? i0 : (MM - 8);
                        int jc = (j0 < MM - 8) ? j0 : (MM - 8);
                        float4 acc[8][2];
                        #pragma unroll
                        for (int r = 0; r < 8; r++) {
                            acc[r][0] = *(const float4*)&A[(ic + r) * ALD + jc];
                            acc[r][1] = *(const float4*)&A[(ic + r) * ALD + jc + 4];
                        }
                        #pragma unroll 4
                        for (int c = 0; c < NB; c++) {
                            const float* row = &A[(k0 + c) * ALD];
                            float4 av0 = *(const float4*)&row[ic];
                            float4 av1 = *(const float4*)&row[ic + 4];
                            float4 bv0 = *(const float4*)&row[jc];
                            float4 bv1 = *(const float4*)&row[jc + 4];
                            float avs[8] = {av0.x, av0.y, av0.z, av0.w, av1.x, av1.y, av1.z, av1.w};
                            #pragma unroll
                            for (int r = 0; r < 8; r++) {
                                float a = avs[r];
                                acc[r][0].x = fmaf(-a, bv0.x, acc[r][0].x);
                                acc[r][0].y = fmaf(-a, bv0.y, acc[r][0].y);
                                acc[r][0].z = fmaf(-a, bv0.z, acc[r][0].z);
                                acc[r][0].w = fmaf(-a, bv0.w, acc[r][0].w);
                                acc[r][1].x = fmaf(-a, bv1.x, acc[r][1].x);
                                acc[r][1].y = fmaf(-a, bv1.y, acc[r][1].y);
                                acc[r][1].z = fmaf(-a, bv1.z, acc[r][1].z);
                                acc[r][1].w = fmaf(-a, bv1.w, acc[r][1].w);
                            }
                        }
                        if (ic == i0 && jc == j0) {
                            #pragma unroll
                            for (int r = 0; r < 8; r++) {
                                *(float4*)&A[(i0 + r) * ALD + j0]     = acc[r][0];
                                *(float4*)&A[(i0 + r) * ALD + j0 + 4] = acc[r][1];
                            }
                        }
                    }
                    __syncthreads();
                }
            }
            float* dst = ws + (isC2 ? OFF_LC2 : OFF_LC);
            for (int idx = tid; idx < MM * MM; idx += 256) {
                int i = idx / MM, j = idx - i * MM;
                dst[idx] = A[i * ALD + j];
            }
            if (tid == 0) STWSF(&ws[OFF_SCAL + (isC2 ? 8 : 7)], 0.5f * logacc);
        }
        slow_sync(ws, 3, &s_last);
        // -------- Phase E: triangular solves (wave-per-column) --------
        for (int u = blockIdx.x * 4 + wav; u < MM + QD; u += nblk * 4) {
            if (u < MM) {
                if (cnt2 != 0) {
                    const float* L = ws + OFF_LC;
                    float* V = ws + OFF_V;
                    int j = u;
                    int k0 = j + lane, k1 = k0 + 64, k2 = k0 + 128;
                    float x0 = 0, x1 = 0, x2 = 0;
                    for (int i = j; i < MM; i++) {
                        const float* Lr = L + i * MM;
                        float s = 0.0f;
                        if (k0 < i) s = fmaf(Lr[k0], x0, s);
                        if (k1 < i) s = fmaf(Lr[k1], x1, s);
                        if (k2 < i) s = fmaf(Lr[k2], x2, s);
                        #pragma unroll
                        for (int off = 1; off < 64; off <<= 1) s += __shfl_xor(s, off);
                        float xi = ((i == j) ? 1.0f : 0.0f) - s;
                        if (k0 == i) x0 = xi;
                        if (k1 == i) x1 = xi;
                        if (k2 == i) x2 = xi;
                        if (lane == 0) V[i * MM + j] = xi;
                    }
                }
            } else if (gflag != 0) {
                const float* L = ws + OFF_LC2;
                const float* G = ws + OFF_G;
                int c = u - MM;
                int k0 = lane, k1 = lane + 64, k2 = lane + 128;
                float x0 = 0, x1 = 0, x2 = 0, ss = 0;
                for (int i = 0; i < MM; i++) {
                    const float* Lr = L + i * MM;
                    float s = 0.0f;
                    if (k0 < i) s = fmaf(Lr[k0], x0, s);
                    if (k1 < i) s = fmaf(Lr[k1], x1, s);
                    if (k2 < i) s = fmaf(Lr[k2], x2, s);
                    #pragma unroll
                    for (int off = 1; off < 64; off <<= 1) s += __shfl_xor(s, off);
                    float xi = G[i * QD + c] - s;
                    if (k0 == i) x0 = xi;
                    if (k1 == i) x1 = xi;
                    if (k2 == i) x2 = xi;
                    if (lane == 0) ss += xi * xi / Lr[i];
                }
                if (lane == 0) atomicAdd(&ws[OFF_SCAL + 2], ss);
            }
        }
        slow_sync(ws, 4, &s_last);
        // -------- Phase F: trace_raw --------
        if (cnt2 != 0) {
            for (int i = blockIdx.x; i < MM; i += nblk) {
                float* vrow = smem;         // 192
                float* red  = smem + 192;   // 256
                const float* V = ws + OFF_V;
                const float* P = ws + OFF_PSI2;
                for (int a = tid; a < MM; a += 256) vrow[a] = (a <= i) ? V[i * MM + a] : 0.0f;
                __syncthreads();
                float acc = 0.0f;
                for (int a = tid; a <= i; a += 256) {
                    const float* Pr = P + a * MM;
                    float inner = 0.0f;
                    for (int b = 0; b <= i; b++) inner = fmaf(Pr[b], vrow[b], inner);
                    acc = fmaf(vrow[a], inner, acc);
                }
                red[tid] = acc; __syncthreads();
                if (tid < 128) red[tid] += red[tid + 128];
                __syncthreads();
                if (tid < 64) {
                    float s = red[tid] + red[tid + 64];
                    s = wave_reduce(s);
                    if (tid == 0) { float di = ws[OFF_LC + i * MM + i]; atomicAdd(&ws[OFF_SCAL + 0], s / di); }
                }
                __syncthreads();
            }
        }
        slow_sync(ws, 5, &s_last);
    }

    // ------ Final assembly (fast: last arriver; slow: block 0, fenced) ------
    if (do_final) {
        // thread t reads BSUM[t], [t+256], [t+512], [t+768] -> component t&3
        float s = 0.0f;
        #pragma unroll
        for (int r = 0; r < 4; r++) s += LDWSF(ws + OFF_BSUM + tid + 256 * r);
        // sum over lanes with equal (lane & 3) within the wave
        s += __shfl_xor(s, 4); s += __shfl_xor(s, 8);
        s += __shfl_xor(s, 16); s += __shfl_xor(s, 32);
        float* fin = smem;   // 16 floats: [wave][component]
        __syncthreads();
        if (lane < 4) fin[wav * 4 + lane] = s;
        __syncthreads();
        if (tid == 0) {
            float Svo  = fin[0] + fin[4] + fin[8]  + fin[12];
            float Smo2 = fin[1] + fin[5] + fin[9]  + fin[13];
            float Slog = fin[2] + fin[6] + fin[10] + fin[14];
            float Smb  = fin[3] + fin[7] + fin[11] + fin[15];
            // slots 0/2/7/8 are memset-zeroed; nonzero only if slow path ran
            float trRaw = LDWSF(ws + OFF_SCAL + 0);
            float ssY   = LDWSF(ws + OFF_SCAL + 2);
            float ldK   = LDWSF(ws + OFF_SCAL + 7);
            float ldC2  = LDWSF(ws + OFF_SCAL + 8);
            float kv = *kern_var, s2v = *lik;
            float inv_s2 = 1.0f / s2v;
            const float lp2pi = 1.8378770664093453f;  // log(2*pi)
            float trA = trRaw * inv_s2;
            float ldB = 2.0f * (ldC2 - ldK);
            float sc2 = ssY * inv_s2 * inv_s2;
            float ND = 18000.0f;   // (Nt-Lt)*D
            float Df = 12.0f;
            float bound = -0.5f * ND * (lp2pi + logf(s2v));
            bound += -0.5f * inv_s2 * (Svo + Smo2);
            bound += -0.5f * Df * ((kv * 1500.0f) * inv_s2 - trA);
            bound += -0.5f * Df * ldB;
            bound += 0.5f * sc2;
            bound += 0.5f * Slog + 0.5f * ND * lp2pi;      // ent
            bound += -96.0f * lp2pi - 0.5f * Smb;          // ent2 (Lt*D = 96)
            out[0] = bound;
        }
    }
}

extern "C" void kernel_launch(void* const* d_in, const int* in_sizes, int n_in,
                              void* d_out, int out_size, void* d_ws, size_t ws_size,
                              hipStream_t stream)
{
    const float* Xm_m    = (const float*)d_in[1];
    const float* Xm_v    = (const float*)d_in[2];
    const float* Z       = (const float*)d_in[3];
    const float* X_mean  = (const float*)d_in[4];
    const float* X_var   = (const float*)d_in[5];
    const float* kern_var= (const float*)d_in[6];
    const float* kern_ls = (const float*)d_in[7];
    const float* lik_var = (const float*)d_in[8];
    float* ws  = (float*)d_ws;
    float* out = (float*)d_out;

    // zero scalar slots (64 floats incl. pad) + barrier phase 0 only
    // (phases 1-6 are zeroed in-kernel before the first grid sync)
    hipMemsetAsync(ws + OFF_SCAL, 0, (64 + BAR_STRIDE) * sizeof(float), stream);

    k_fused<<<FGRID, 256, 0, stream>>>(Xm_m, Xm_v, Z, X_mean, X_var,
                                       kern_var, kern_ls, lik_var, ws, out);
}

// Round 6
// 77.683 us; speedup vs baseline: 1.6919x; 1.0214x over previous
//
#include <hip/hip_runtime.h>
#include <math.h>

// Problem dims (fixed by setup_inputs)
#define NR   1500     // rows of X_m  (Nt - Lt)
#define NTT  1508     // Nt
#define QD   12       // D
#define LT   8
#define DIN  192      // 2*Lt*Q
#define MM   192      // M
#define JITTER 1e-6f
// Exact per-row suprema: psi1 expo <= logdet1[n], psi2 expo <= logdet2[n].
// Rows below this cut contribute < e^-30 ~ 1e-13 each -> provably < 1e-6 relative.
#define PRUNE_CUT -30.0f

// ---- workspace layout (float offsets) ----
#define OFF_W2    0
#define OFF_WU2   288000
#define OFF_P1    576000
#define OFF_R1    864000
#define OFF_S1    1152000
#define OFF_S2    1153500
#define OFF_V     1155000
#define OFF_D2ZZ  1191864
#define OFF_KUU   1228728
#define OFF_PSI1  1265592
#define OFF_PSI2  1553592
#define OFF_LC    1590456
#define OFF_LC2   1627320
#define OFF_G     1664184
#define OFF_NLIST 1666520     // 1500 ints: surviving-n list for psi2 (sc1 stores)
#define OFF_BSUM  1668032     // 256 blocks x 4 per-block input-sum partials (sc1)
#define OFF_F     1669056     // 288000 floats (de-aliased from P1)
#define OFF_CHA   1957056     // 2 x MM*ALD global scratch for slow-path chol
#define OFF_SCAL  2032384     // 16 floats (zeroed each replay by memset)
// scal slots: 0 trace_raw, 2 ||Y||^2, 7 0.5*logdetKuu, 8 0.5*logdetC2,
//             12 cnt2 (psi2 survivors), 13 cnt1 (psi1 survivors), 14 gflag,
//             15 ticket (arrival count)

// Agent-scope relaxed atomics: on gfx94x/950 these carry sc1 (execute/read at
// the coherent point, bypassing the non-coherent per-XCD L2) -> cross-block
// coherent WITHOUT fences. All fast-path cross-block traffic uses these.
#define LDWSF(p)    __hip_atomic_load((p), __ATOMIC_RELAXED, __HIP_MEMORY_SCOPE_AGENT)
#define LDWSI(p)    __hip_atomic_load((p), __ATOMIC_RELAXED, __HIP_MEMORY_SCOPE_AGENT)
#define STWSF(p,v)  __hip_atomic_store((p), (v), __ATOMIC_RELAXED, __HIP_MEMORY_SCOPE_AGENT)
#define STWSI(p,v)  __hip_atomic_store((p), (v), __ATOMIC_RELAXED, __HIP_MEMORY_SCOPE_AGENT)

__device__ __forceinline__ float wave_reduce(float s) {
    s += __shfl_down(s, 32); s += __shfl_down(s, 16); s += __shfl_down(s, 8);
    s += __shfl_down(s, 4);  s += __shfl_down(s, 2);  s += __shfl_down(s, 1);
    return s;
}
__device__ __forceinline__ float bfly_sum(float s) {
    s += __shfl_xor(s, 32); s += __shfl_xor(s, 16); s += __shfl_xor(s, 8);
    s += __shfl_xor(s, 4);  s += __shfl_xor(s, 2);  s += __shfl_xor(s, 1);
    return s;
}

#define ALD 196
#define NB  32
#define ZR  196
#define FGRID 256

// ============================================================================
// v5: ticket design — NO grid barrier at all.
// Fast path (cnt1==cnt2==0, true for bench data): each block computes only the
// prune sums (v0,v1) + input sums, publishes via sc1 stores/atomics, bumps an
// agent-scope ticket, and EXITS. The block drawing ticket==FGRID-1 has proof
// all writes are at the coherent point; it reads cnts and runs final assembly.
// Slow path (never exercised here): that same last block executes the entire
// original phase chain SINGLE-BLOCK (grid syncs -> __syncthreads), correct but
// slow. One agent acquire fence at entry makes peers' sc1 data visible to
// plain loads.
// ============================================================================
__global__ __launch_bounds__(256) void k_fused(
    const float* __restrict__ Xm_m, const float* __restrict__ Xm_v,
    const float* __restrict__ Z, const float* __restrict__ X_mean,
    const float* __restrict__ X_var, const float* __restrict__ kern_var,
    const float* __restrict__ kern_ls, const float* __restrict__ lik,
    float* __restrict__ ws, float* __restrict__ out)
{
    __shared__ __align__(16) float smem[2 * 32 * ZR];   // 49 KB (slow path tiles)
    __shared__ int s_role;                               // 0 exit, 1 fast-final, 2 slow
    const int tid  = threadIdx.x;
    const int lane = tid & 63;
    const int wav  = tid >> 6;
    const int nblk = gridDim.x;

    // ---------------- Phase A-lite: prune sums only ----------------
    // cnt1/cnt2 depend only on X_var / Xm_v / kern_ls. No derived-array stores,
    // no X_mean/Xm_m loads here. Arithmetic identical to prior rounds.
    for (int n = blockIdx.x * 4 + wav; n < NR; n += nblk * 4) {
        float v0 = 0, v1 = 0;
        #pragma unroll
        for (int s = 0; s < 3; s++) {
            int q = lane + 64 * s;
            float v = (q < 96) ? X_var[n * QD + q] : Xm_v[(1 + n) * QD + (q - 96)];
            float ls = kern_ls[q]; float l2 = ls * ls;
            v0 += log1pf(v / l2);
            v1 += log1pf(2.0f * v / l2);
        }
        v0 = bfly_sum(v0); v1 = bfly_sum(v1);
        if (lane == 0) {
            float ld1 = -0.5f * v0;                // exact sup of psi1 exponent
            float ld2 = -0.5f * v1;                // exact sup of psi2 exponent
            int* cnts = (int*)(ws + OFF_SCAL);
            if (ld1 > PRUNE_CUT) atomicAdd(&cnts[13], 1);
            if (ld2 > PRUNE_CUT) {
                int idx = atomicAdd(&cnts[12], 1);
                STWSI((int*)(ws + OFF_NLIST) + idx, n);   // sc1: visible to last block
            }
        }
    }
    {   // input sums (Svo, Smo2, Slog, Smb) -> per-block sc1 partials
        float pVo = 0, pMo = 0, pLg = 0, pMb = 0;
        for (int idx = blockIdx.x * 256 + tid; idx < NTT * QD; idx += nblk * 256) {
            float xm = X_mean[idx], xv = X_var[idx];
            if (idx >= LT * QD) { pVo += xv; pMo += xm * xm; pLg += logf(xv); }
            else                { pMb += xm * xm + xv; }
        }
        pVo = bfly_sum(pVo); pMo = bfly_sum(pMo); pLg = bfly_sum(pLg); pMb = bfly_sum(pMb);
        float* part = smem;   // 16 floats
        if (lane == 0) { part[wav*4+0] = pVo; part[wav*4+1] = pMo; part[wav*4+2] = pLg; part[wav*4+3] = pMb; }
        __syncthreads();
        if (tid < 4) {
            float s = part[tid] + part[4 + tid] + part[8 + tid] + part[12 + tid];
            STWSF(&ws[OFF_BSUM + blockIdx.x * 4 + tid], s);   // sc1 store
        }
    }

    // ---------------- ticket: last arriver takes over ----------------
    __syncthreads();   // drains vmcnt: this block's sc1 stores are at the coherent point
    if (tid == 0) {
        int t = __hip_atomic_fetch_add((int*)(ws + OFF_SCAL) + 15, 1,
                                       __ATOMIC_RELAXED, __HIP_MEMORY_SCOPE_AGENT);
        int role = 0;
        if (t == FGRID - 1) {
            int c1 = LDWSI((const int*)(ws + OFF_SCAL) + 13);
            int c2 = LDWSI((const int*)(ws + OFF_SCAL) + 12);
            role = ((c1 | c2) != 0) ? 2 : 1;
        }
        s_role = role;
    }
    __syncthreads();
    if (s_role == 0) return;   // non-last blocks: done. no polling, no fences.

    const int cnt1 = LDWSI((const int*)(ws + OFF_SCAL) + 13);
    const int cnt2 = LDWSI((const int*)(ws + OFF_SCAL) + 12);

    if (s_role == 2) {
        // =================== SINGLE-BLOCK SLOW PATH ==========================
        // Never exercised by bench data (cnt1==cnt2==0 there). Correctness-only.
        __builtin_amdgcn_fence(__ATOMIC_ACQUIRE, "agent");  // see peers' sc1 NLIST
        const int ty4 = tid >> 4, tx4 = tid & 15;
        float kv = *kern_var;

        // ---- A2: full per-n prep (derived arrays + S1/S2) ----
        for (int n = wav; n < NR; n += 4) {
            float v0 = 0, v1 = 0, v2 = 0, v3 = 0;
            #pragma unroll
            for (int s = 0; s < 3; s++) {
                int q = lane + 64 * s;
                float u, v;
                if (q < 96) { u = X_mean[n * QD + q]; v = X_var[n * QD + q]; }
                else        { int j = q - 96; u = Xm_m[(1 + n) * QD + j]; v = Xm_v[(1 + n) * QD + j]; }
                float ls = kern_ls[q]; float l2 = ls * ls;
                float d1 = l2 + v, d2 = l2 + 2.0f * v;
                float i1 = 1.0f / d1, i2 = 1.0f / d2;
                ws[OFF_P1  + n * DIN + q] = u * i1;
                ws[OFF_R1  + n * DIN + q] = i1;
                ws[OFF_W2  + n * DIN + q] = i2;
                ws[OFF_WU2 + n * DIN + q] = u * i2;
                v0 += log1pf(v / l2);
                v1 += log1pf(2.0f * v / l2);
                v2 += u * u * i1;
                v3 += u * u * i2;
            }
            v0 = bfly_sum(v0); v1 = bfly_sum(v1); v2 = bfly_sum(v2); v3 = bfly_sum(v3);
            if (lane == 0) {
                ws[OFF_S1 + n] = -0.5f * (v0 + v2);
                ws[OFF_S2 + n] = -0.5f * v1 - v3;
            }
        }
        __syncthreads();

        // ---- B: Kuu/d2zz tiles + psi1 tiles + F tiles ----
        for (int vb = 0; vb < 144 + 2 * 1128; vb++) {
            if (vb < 144) {
                int bx = vb / 12, by = vb - bx * 12;
                float (*Zm)[17] = (float(*)[17])smem;
                float (*Zp)[17] = (float(*)[17])(smem + 272);
                int m = bx * 16 + ty4, p = by * 16 + tx4;
                float d = 0.0f;
                for (int qc = 0; qc < 12; qc++) {
                    int q0 = qc * 16;
                    float inv_ls = 1.0f / kern_ls[q0 + tx4];
                    Zm[ty4][tx4] = Z[(bx * 16 + ty4) * DIN + q0 + tx4] * inv_ls;
                    Zp[ty4][tx4] = Z[(by * 16 + ty4) * DIN + q0 + tx4] * inv_ls;
                    __syncthreads();
                    #pragma unroll
                    for (int k = 0; k < 16; k++) { float t = Zm[ty4][k] - Zp[tx4][k]; d = fmaf(t, t, d); }
                    __syncthreads();
                }
                ws[OFF_D2ZZ + m * MM + p] = d;
                ws[OFF_KUU  + m * MM + p] = kv * __expf(-0.5f * d) + ((m == p) ? JITTER : 0.0f);
            } else if (vb < 144 + 1128) {
                if (cnt1 != 0) {
                    int t = vb - 144, bx = t % 94, by = t / 94;
                    int n = bx * 16 + ty4, m = by * 16 + tx4;
                    float (*Ps)[17]  = (float(*)[17])smem;
                    float (*Rs)[17]  = (float(*)[17])(smem + 272);
                    float (*Zs)[17]  = (float(*)[17])(smem + 544);
                    float (*Z2s)[17] = (float(*)[17])(smem + 816);
                    float dot1 = 0.0f, dot2 = 0.0f;
                    for (int qc = 0; qc < 12; qc++) {
                        int q0 = qc * 16;
                        Ps[ty4][tx4] = (n < NR) ? ws[OFF_P1 + n * DIN + q0 + tx4] : 0.0f;
                        Rs[ty4][tx4] = (n < NR) ? ws[OFF_R1 + n * DIN + q0 + tx4] : 0.0f;
                        float z = Z[(by * 16 + ty4) * DIN + q0 + tx4];
                        Zs[ty4][tx4] = z; Z2s[ty4][tx4] = z * z;
                        __syncthreads();
                        #pragma unroll
                        for (int k = 0; k < 16; k++) {
                            dot1 = fmaf(Ps[ty4][k], Zs[tx4][k], dot1);
                            dot2 = fmaf(Rs[ty4][k], Z2s[tx4][k], dot2);
                        }
                        __syncthreads();
                    }
                    if (n < NR) ws[OFF_PSI1 + n * MM + m] = kv * __expf(ws[OFF_S1 + n] + dot1 - 0.5f * dot2);
                }
            } else {
                if (cnt2 != 0) {
                    int t = vb - (144 + 1128), bx = t % 94, by = t / 94;
                    int n = bx * 16 + ty4, m = by * 16 + tx4;
                    float (*Us)[17] = (float(*)[17])smem;
                    float (*Ws)[17] = (float(*)[17])(smem + 272);
                    float (*Zb)[17] = (float(*)[17])(smem + 544);
                    float dotB = 0.0f, dotC = 0.0f;
                    for (int qc = 0; qc < 12; qc++) {
                        int q0 = qc * 16;
                        Us[ty4][tx4] = (n < NR) ? ws[OFF_WU2 + n * DIN + q0 + tx4] : 0.0f;
                        Ws[ty4][tx4] = (n < NR) ? ws[OFF_W2  + n * DIN + q0 + tx4] : 0.0f;
                        Zb[ty4][tx4] = Z[(by * 16 + ty4) * DIN + q0 + tx4];
                        __syncthreads();
                        #pragma unroll
                        for (int k = 0; k < 16; k++) {
                            float z = Zb[tx4][k];
                            dotB = fmaf(z, Us[ty4][k], dotB);
                            dotC = fmaf(z * z, Ws[ty4][k], dotC);
                        }
                        __syncthreads();
                    }
                    if (n < NR) ws[OFF_F + n * MM + m] = fmaf(-0.25f, dotC, dotB);
                }
            }
        }
        __syncthreads();

        // ---- C: G rows + psi2 tiles (or exact-zero fill) ----
        for (int vb = 0; vb < 192 + 36; vb++) {
            if (vb < 192) {
                if (cnt1 != 0) {
                    int m = vb;
                    const float* psi1 = ws + OFF_PSI1;
                    float g[QD];
                    #pragma unroll
                    for (int d = 0; d < QD; d++) g[d] = 0.0f;
                    for (int n = tid; n < NR; n += 256) {
                        float p = psi1[n * MM + m];
                        const float* xr = X_mean + (LT + n) * QD;
                        #pragma unroll
                        for (int d = 0; d < QD; d++) g[d] = fmaf(p, xr[d], g[d]);
                    }
                    float* red = smem;   // 256 floats
                    bool any = false;
                    for (int d = 0; d < QD; d++) {
                        red[tid] = g[d]; __syncthreads();
                        if (tid < 128) red[tid] += red[tid + 128];
                        __syncthreads();
                        if (tid < 64) {
                            float s = red[tid] + red[tid + 64];
                            s = wave_reduce(s);
                            if (tid == 0) { ws[OFF_G + m * QD + d] = s; any |= (s != 0.0f); }
                        }
                        __syncthreads();
                    }
                    if (tid == 0 && any) atomicOr((int*)(ws + OFF_SCAL) + 14, 1);
                }
            } else {
                int t = vb - 192, bx = t / 6, by = t - 6 * bx;
                int m0 = bx * 32, p0 = by * 32;
                int ty4b = tid >> 4, tx4b = tid & 15;
                int mA = m0 + 2 * ty4b, pA = p0 + 2 * tx4b;
                float* P2 = ws + OFF_PSI2;
                if (cnt2 == 0) {
                    P2[(mA    ) * MM + pA    ] = 0.0f;
                    P2[(mA    ) * MM + pA + 1] = 0.0f;
                    P2[(mA + 1) * MM + pA    ] = 0.0f;
                    P2[(mA + 1) * MM + pA + 1] = 0.0f;
                    __syncthreads();
                } else {
                    float a00 = 0, a01 = 0, a10 = 0, a11 = 0;
                    float* Zm = smem;             // 32*ZR
                    float* Zp = smem + 32 * ZR;   // 32*ZR
                    for (int idx = tid; idx < 32 * DIN; idx += 256) {
                        int r = idx / DIN, q = idx - r * DIN;
                        Zm[r * ZR + q] = Z[(m0 + r) * DIN + q];
                        Zp[r * ZR + q] = Z[(p0 + r) * DIN + q];
                    }
                    __syncthreads();
                    const float* w2base = ws + OFF_W2;
                    const float* F      = ws + OFF_F;
                    const float* s2arr  = ws + OFF_S2;
                    const int* list     = (const int*)(ws + OFF_NLIST);
                    const float4* zm0 = (const float4*)(Zm + (2 * ty4b    ) * ZR);
                    const float4* zm1 = (const float4*)(Zm + (2 * ty4b + 1) * ZR);
                    const float4* zp0 = (const float4*)(Zp + (2 * tx4b    ) * ZR);
                    const float4* zp1 = (const float4*)(Zp + (2 * tx4b + 1) * ZR);
                    for (int li = 0; li < cnt2; li++) {
                        int n = list[li];
                        const float4* w2p = (const float4*)(w2base + n * DIN);
                        float e00 = 0, e01 = 0, e10 = 0, e11 = 0;
                        #pragma unroll 4
                        for (int g = 0; g < DIN / 4; g++) {
                            float4 w = w2p[g];
                            float4 a = zm0[g], b = zm1[g], c = zp0[g], d = zp1[g];
                            float wp0, wp1;
                            wp0 = w.x * c.x; wp1 = w.x * d.x;
                            e00 = fmaf(a.x, wp0, e00); e01 = fmaf(a.x, wp1, e01);
                            e10 = fmaf(b.x, wp0, e10); e11 = fmaf(b.x, wp1, e11);
                            wp0 = w.y * c.y; wp1 = w.y * d.y;
                            e00 = fmaf(a.y, wp0, e00); e01 = fmaf(a.y, wp1, e01);
                            e10 = fmaf(b.y, wp0, e10); e11 = fmaf(b.y, wp1, e11);
                            wp0 = w.z * c.z; wp1 = w.z * d.z;
                            e00 = fmaf(a.z, wp0, e00); e01 = fmaf(a.z, wp1, e01);
                            e10 = fmaf(b.z, wp0, e10); e11 = fmaf(b.z, wp1, e11);
                            wp0 = w.w * c.w; wp1 = w.w * d.w;
                            e00 = fmaf(a.w, wp0, e00); e01 = fmaf(a.w, wp1, e01);
                            e10 = fmaf(b.w, wp0, e10); e11 = fmaf(b.w, wp1, e11);
                        }
                        float s2n = s2arr[n];
                        float Fm0 = F[n * MM + mA], Fm1 = F[n * MM + mA + 1];
                        float Fp0 = F[n * MM + pA], Fp1 = F[n * MM + pA + 1];
                        a00 += __expf(s2n + Fm0 + Fp0 - 0.5f * e00);
                        a01 += __expf(s2n + Fm0 + Fp1 - 0.5f * e01);
                        a10 += __expf(s2n + Fm1 + Fp0 - 0.5f * e10);
                        a11 += __expf(s2n + Fm1 + Fp1 - 0.5f * e11);
                    }
                    float kv2 = kv * kv;
                    const float* dz = ws + OFF_D2ZZ;
                    P2[(mA    ) * MM + pA    ] = kv2 * __expf(-0.25f * dz[(mA    ) * MM + pA    ]) * a00;
                    P2[(mA    ) * MM + pA + 1] = kv2 * __expf(-0.25f * dz[(mA    ) * MM + pA + 1]) * a01;
                    P2[(mA + 1) * MM + pA    ] = kv2 * __expf(-0.25f * dz[(mA + 1) * MM + pA    ]) * a10;
                    P2[(mA + 1) * MM + pA + 1] = kv2 * __expf(-0.25f * dz[(mA + 1) * MM + pA + 1]) * a11;
                    __syncthreads();
                }
            }
        }
        __syncthreads();
        const int gflag = LDWSI((const int*)(ws + OFF_SCAL) + 14);

        // ---- D: dual blocked LDL^T (sequential) in global scratch ----
        if (cnt2 != 0 || gflag != 0) {
            for (int mat = 0; mat < 2; mat++) {
                bool isC2 = (mat == 1);
                float* A = ws + OFF_CHA + (size_t)mat * (MM * ALD);
                const float* Kuu  = ws + OFF_KUU;
                const float* psi2 = ws + OFF_PSI2;
                float inv_s2 = 1.0f / (*lik);
                for (int idx = tid; idx < MM * MM; idx += 256) {
                    int i = idx / MM, j = idx - i * MM;
                    float v = Kuu[idx];
                    if (isC2) v = fmaf(psi2[idx], inv_s2, v);
                    A[i * ALD + j] = v;
                }
                __syncthreads();
                float logacc = 0.0f;
                int ty = tid >> 4, tx = tid & 15;
                for (int p = 0; p < MM / NB; p++) {
                    int k0 = p * NB;
                    int e  = k0 + NB;
                    if (tid < 64) {
                        int l64 = tid;
                        float P[3][NB];
                        #pragma unroll
                        for (int s = 0; s < 3; s++) {
                            int r = l64 + 64 * s;
                            #pragma unroll
                            for (int g = 0; g < NB / 4; g++) {
                                float4 v = *(const float4*)&A[r * ALD + k0 + 4 * g];
                                P[s][4*g] = v.x; P[s][4*g+1] = v.y; P[s][4*g+2] = v.z; P[s][4*g+3] = v.w;
                            }
                        }
                        int sD = k0 >> 6;
                        int lD = k0 & 63;
                        #pragma unroll
                        for (int c = 0; c < NB; c++) {
                            int k = k0 + c;
                            float colc = (sD == 0) ? P[0][c] : ((sD == 1) ? P[1][c] : P[2][c]);
                            float dkk = __shfl(colc, lD + c);
                            float inv = 1.0f / dkk;
                            logacc += logf(dkk);
                            float m0 = (l64       > k) ? P[0][c] * inv : 0.0f;
                            float m1 = (l64 + 64  > k) ? P[1][c] * inv : 0.0f;
                            float m2 = (l64 + 128 > k) ? P[2][c] * inv : 0.0f;
                            P[0][c] = (l64       > k) ? m0 : P[0][c];
                            P[1][c] = (l64 + 64  > k) ? m1 : P[1][c];
                            P[2][c] = (l64 + 128 > k) ? m2 : P[2][c];
                            #pragma unroll
                            for (int j = c + 1; j < NB; j++) {
                                float w = __shfl(colc, lD + j);
                                P[0][j] = fmaf(-m0, w, P[0][j]);
                                P[1][j] = fmaf(-m1, w, P[1][j]);
                                P[2][j] = fmaf(-m2, w, P[2][j]);
                            }
                        }
                        #pragma unroll
                        for (int s = 0; s < 3; s++) {
                            int r = l64 + 64 * s;
                            #pragma unroll
                            for (int g = 0; g < NB / 4; g++) {
                                float4 v = make_float4(P[s][4*g], P[s][4*g+1], P[s][4*g+2], P[s][4*g+3]);
                                *(float4*)&A[r * ALD + k0 + 4 * g] = v;
                            }
                        }
                    }
                    __syncthreads();
                    int T = MM - e;
                    if (T > 0) {
                        for (int idx = tid; idx < NB * T; idx += 256) {
                            int c = idx / T, j = e + (idx - c * T);
                            float d = A[(k0 + c) * ALD + (k0 + c)];
                            A[(k0 + c) * ALD + j] = A[j * ALD + k0 + c] * sqrtf(d);
                        }
                        __syncthreads();
                        int nT = (T + 127) / 128;
                        for (int bi = 0; bi < nT; bi++)
                        for (int bj = 0; bj < nT; bj++) {
                            int i0 = e + 128 * bi + 8 * ty;
                            int j0 = e + 128 * bj + 8 * tx;
                            int ic = (i0 < MM - 8) ? i0 : (MM - 8);
                            int jc = (j0 < MM - 8) ? j0 : (MM - 8);
                            float4 acc[8][2];
                            #pragma unroll
                            for (int r = 0; r < 8; r++) {
                                acc[r][0] = *(const float4*)&A[(ic + r) * ALD + jc];
                                acc[r][1] = *(const float4*)&A[(ic + r) * ALD + jc + 4];
                            }
                            #pragma unroll 4
                            for (int c = 0; c < NB; c++) {
                                const float* row = &A[(k0 + c) * ALD];
                                float4 av0 = *(const float4*)&row[ic];
                                float4 av1 = *(const float4*)&row[ic + 4];
                                float4 bv0 = *(const float4*)&row[jc];
                                float4 bv1 = *(const float4*)&row[jc + 4];
                                float avs[8] = {av0.x, av0.y, av0.z, av0.w, av1.x, av1.y, av1.z, av1.w};
                                #pragma unroll
                                for (int r = 0; r < 8; r++) {
                                    float a = avs[r];
                                    acc[r][0].x = fmaf(-a, bv0.x, acc[r][0].x);
                                    acc[r][0].y = fmaf(-a, bv0.y, acc[r][0].y);
                                    acc[r][0].z = fmaf(-a, bv0.z, acc[r][0].z);
                                    acc[r][0].w = fmaf(-a, bv0.w, acc[r][0].w);
                                    acc[r][1].x = fmaf(-a, bv1.x, acc[r][1].x);
                                    acc[r][1].y = fmaf(-a, bv1.y, acc[r][1].y);
                                    acc[r][1].z = fmaf(-a, bv1.z, acc[r][1].z);
                                    acc[r][1].w = fmaf(-a, bv1.w, acc[r][1].w);
                                }
                            }
                            if (ic == i0 && jc == j0) {
                                #pragma unroll
                                for (int r = 0; r < 8; r++) {
                                    *(float4*)&A[(i0 + r) * ALD + j0]     = acc[r][0];
                                    *(float4*)&A[(i0 + r) * ALD + j0 + 4] = acc[r][1];
                                }
                            }
                        }
                        __syncthreads();
                    }
                }
                float* dst = ws + (isC2 ? OFF_LC2 : OFF_LC);
                for (int idx = tid; idx < MM * MM; idx += 256) {
                    int i = idx / MM, j = idx - i * MM;
                    dst[idx] = A[i * ALD + j];
                }
                if (tid == 0) ws[OFF_SCAL + (isC2 ? 8 : 7)] = 0.5f * logacc;
                __syncthreads();
            }
        }

        // ---- E: triangular solves (wave-per-column, 4 waves) ----
        for (int u = wav; u < MM + QD; u += 4) {
            if (u < MM) {
                if (cnt2 != 0) {
                    const float* L = ws + OFF_LC;
                    float* V = ws + OFF_V;
                    int j = u;
                    int k0 = j + lane, k1 = k0 + 64, k2 = k0 + 128;
                    float x0 = 0, x1 = 0, x2 = 0;
                    for (int i = j; i < MM; i++) {
                        const float* Lr = L + i * MM;
                        float s = 0.0f;
                        if (k0 < i) s = fmaf(Lr[k0], x0, s);
                        if (k1 < i) s = fmaf(Lr[k1], x1, s);
                        if (k2 < i) s = fmaf(Lr[k2], x2, s);
                        #pragma unroll
                        for (int off = 1; off < 64; off <<= 1) s += __shfl_xor(s, off);
                        float xi = ((i == j) ? 1.0f : 0.0f) - s;
                        if (k0 == i) x0 = xi;
                        if (k1 == i) x1 = xi;
                        if (k2 == i) x2 = xi;
                        if (lane == 0) V[i * MM + j] = xi;
                    }
                }
            } else if (gflag != 0) {
                const float* L = ws + OFF_LC2;
                const float* G = ws + OFF_G;
                int c = u - MM;
                int k0 = lane, k1 = lane + 64, k2 = lane + 128;
                float x0 = 0, x1 = 0, x2 = 0, ss = 0;
                for (int i = 0; i < MM; i++) {
                    const float* Lr = L + i * MM;
                    float s = 0.0f;
                    if (k0 < i) s = fmaf(Lr[k0], x0, s);
                    if (k1 < i) s = fmaf(Lr[k1], x1, s);
                    if (k2 < i) s = fmaf(Lr[k2], x2, s);
                    #pragma unroll
                    for (int off = 1; off < 64; off <<= 1) s += __shfl_xor(s, off);
                    float xi = G[i * QD + c] - s;
                    if (k0 == i) x0 = xi;
                    if (k1 == i) x1 = xi;
                    if (k2 == i) x2 = xi;
                    if (lane == 0) ss += xi * xi / Lr[i];
                }
                if (lane == 0) atomicAdd(&ws[OFF_SCAL + 2], ss);
            }
        }
        __syncthreads();

        // ---- F: trace_raw ----
        if (cnt2 != 0) {
            for (int i = 0; i < MM; i++) {
                float* vrow = smem;         // 192
                float* red  = smem + 192;   // 256
                const float* V = ws + OFF_V;
                const float* P = ws + OFF_PSI2;
                for (int a = tid; a < MM; a += 256) vrow[a] = (a <= i) ? V[i * MM + a] : 0.0f;
                __syncthreads();
                float acc = 0.0f;
                for (int a = tid; a <= i; a += 256) {
                    const float* Pr = P + a * MM;
                    float inner = 0.0f;
                    for (int b = 0; b <= i; b++) inner = fmaf(Pr[b], vrow[b], inner);
                    acc = fmaf(vrow[a], inner, acc);
                }
                red[tid] = acc; __syncthreads();
                if (tid < 128) red[tid] += red[tid + 128];
                __syncthreads();
                if (tid < 64) {
                    float s = red[tid] + red[tid + 64];
                    s = wave_reduce(s);
                    if (tid == 0) { float di = ws[OFF_LC + i * MM + i]; atomicAdd(&ws[OFF_SCAL + 0], s / di); }
                }
                __syncthreads();
            }
        }
        __syncthreads();
    }

    // ---------------- Final assembly (last-ticket block) ----------------
    {
        // thread t reads BSUM[t], [t+256], [t+512], [t+768] -> component t&3
        float s = 0.0f;
        #pragma unroll
        for (int r = 0; r < 4; r++) s += LDWSF(ws + OFF_BSUM + tid + 256 * r);
        // sum over lanes with equal (lane & 3) within the wave
        s += __shfl_xor(s, 4); s += __shfl_xor(s, 8);
        s += __shfl_xor(s, 16); s += __shfl_xor(s, 32);
        float* fin = smem;   // 16 floats: [wave][component]
        __syncthreads();
        if (lane < 4) fin[wav * 4 + lane] = s;
        __syncthreads();
        if (tid == 0) {
            float Svo  = fin[0] + fin[4] + fin[8]  + fin[12];
            float Smo2 = fin[1] + fin[5] + fin[9]  + fin[13];
            float Slog = fin[2] + fin[6] + fin[10] + fin[14];
            float Smb  = fin[3] + fin[7] + fin[11] + fin[15];
            // slots 0/2/7/8 are memset-zeroed; nonzero only if slow path ran
            float trRaw = LDWSF(ws + OFF_SCAL + 0);
            float ssY   = LDWSF(ws + OFF_SCAL + 2);
            float ldK   = LDWSF(ws + OFF_SCAL + 7);
            float ldC2  = LDWSF(ws + OFF_SCAL + 8);
            float kv = *kern_var, s2v = *lik;
            float inv_s2 = 1.0f / s2v;
            const float lp2pi = 1.8378770664093453f;  // log(2*pi)
            float trA = trRaw * inv_s2;
            float ldB = 2.0f * (ldC2 - ldK);
            float sc2 = ssY * inv_s2 * inv_s2;
            float ND = 18000.0f;   // (Nt-Lt)*D
            float Df = 12.0f;
            float bound = -0.5f * ND * (lp2pi + logf(s2v));
            bound += -0.5f * inv_s2 * (Svo + Smo2);
            bound += -0.5f * Df * ((kv * 1500.0f) * inv_s2 - trA);
            bound += -0.5f * Df * ldB;
            bound += 0.5f * sc2;
            bound += 0.5f * Slog + 0.5f * ND * lp2pi;      // ent
            bound += -96.0f * lp2pi - 0.5f * Smb;          // ent2 (Lt*D = 96)
            out[0] = bound;
        }
    }
}

extern "C" void kernel_launch(void* const* d_in, const int* in_sizes, int n_in,
                              void* d_out, int out_size, void* d_ws, size_t ws_size,
                              hipStream_t stream)
{
    const float* Xm_m    = (const float*)d_in[1];
    const float* Xm_v    = (const float*)d_in[2];
    const float* Z       = (const float*)d_in[3];
    const float* X_mean  = (const float*)d_in[4];
    const float* X_var   = (const float*)d_in[5];
    const float* kern_var= (const float*)d_in[6];
    const float* kern_ls = (const float*)d_in[7];
    const float* lik_var = (const float*)d_in[8];
    float* ws  = (float*)d_ws;
    float* out = (float*)d_out;

    // zero scalar slots only (16 floats; pad to 64). No barrier state anymore.
    hipMemsetAsync(ws + OFF_SCAL, 0, 64 * sizeof(float), stream);

    k_fused<<<FGRID, 256, 0, stream>>>(Xm_m, Xm_v, Z, X_mean, X_var,
                                       kern_var, kern_ls, lik_var, ws, out);
}

// Round 7
// 77.465 us; speedup vs baseline: 1.6966x; 1.0028x over previous
//
#include <hip/hip_runtime.h>
#include <math.h>

// Problem dims (fixed by setup_inputs)
#define NR   1500     // rows of X_m  (Nt - Lt)
#define NTT  1508     // Nt
#define QD   12       // D
#define LT   8
#define DIN  192      // 2*Lt*Q
#define MM   192      // M
#define JITTER 1e-6f
// Exact per-row suprema: psi1 expo <= logdet1[n], psi2 expo <= logdet2[n].
// Rows below this cut contribute < e^-30 ~ 1e-13 each -> provably < 1e-6 relative.
#define PRUNE_CUT -30.0f

// ---- workspace layout (float offsets) ----
// NOTHING here requires zero-initialization: every consumed slot is either
// unconditionally written each run, or guarded by the sentinel handshake /
// slow-path self-zeroing. The host launch is a SINGLE kernel node (no memset).
#define OFF_W2    0
#define OFF_WU2   288000
#define OFF_P1    576000
#define OFF_R1    864000
#define OFF_S1    1152000
#define OFF_S2    1153500
#define OFF_V     1155000
#define OFF_D2ZZ  1191864
#define OFF_KUU   1228728
#define OFF_PSI1  1265592
#define OFF_PSI2  1553592
#define OFF_LC    1590456
#define OFF_LC2   1627320
#define OFF_G     1664184
#define OFF_NLIST 1666520     // 1500 ints: compacted surviving-n list (slow path builds it)
#define OFF_BSUM  1668032     // 256 blocks x 4 input-sum partials (sc1, all written)
#define OFF_F     1669056     // 288000 floats (de-aliased from P1)
#define OFF_CHA   1957056     // 2 x MM*ALD global scratch for slow-path chol
#define OFF_SCAL  2032384     // 16 floats: slow-path accumulators (slow path self-zeroes)
#define OFF_PBC   2032448     // 256 x 2 ints: per-block {cnt1,cnt2} partials (all written)
#define OFF_PBL   2032960     // 256 x 8 ints: per-block surviving-n segments
#define OFF_SENT  2035008     // 256 x 2 ints: per-block sentinel pair (written LAST)
// scal slots (slow path only): 0 trace_raw, 2 ||Y||^2, 7 0.5*logdetKuu,
//                              8 0.5*logdetC2, 14 gflag

// Poison-proof sentinels: the harness re-poison fill writes ONE uniform
// pattern across ws; requiring two DISTINCT values in two slots means no
// fill pattern can fake completion. (Stale sentinels from a hypothetical
// un-poisoned replay are benign: all published values are deterministic.)
#define SENT_A 0x1CEB00DA
#define SENT_B 0x600DF00D

// Agent-scope relaxed atomics: on gfx94x/950 these carry sc1 (execute/read at
// the coherent point, bypassing the non-coherent per-XCD L2) -> cross-block
// coherent WITHOUT fences. All fast-path cross-block traffic uses these.
// (Empirically validated rounds 3-6: absmax 0.0 with BSUM/cnt traffic on this path.)
#define LDWSF(p)    __hip_atomic_load((p), __ATOMIC_RELAXED, __HIP_MEMORY_SCOPE_AGENT)
#define LDWSI(p)    __hip_atomic_load((p), __ATOMIC_RELAXED, __HIP_MEMORY_SCOPE_AGENT)
#define STWSF(p,v)  __hip_atomic_store((p), (v), __ATOMIC_RELAXED, __HIP_MEMORY_SCOPE_AGENT)
#define STWSI(p,v)  __hip_atomic_store((p), (v), __ATOMIC_RELAXED, __HIP_MEMORY_SCOPE_AGENT)

__device__ __forceinline__ float wave_reduce(float s) {
    s += __shfl_down(s, 32); s += __shfl_down(s, 16); s += __shfl_down(s, 8);
    s += __shfl_down(s, 4);  s += __shfl_down(s, 2);  s += __shfl_down(s, 1);
    return s;
}
__device__ __forceinline__ float bfly_sum(float s) {
    s += __shfl_xor(s, 32); s += __shfl_xor(s, 16); s += __shfl_xor(s, 8);
    s += __shfl_xor(s, 4);  s += __shfl_xor(s, 2);  s += __shfl_xor(s, 1);
    return s;
}
__device__ __forceinline__ int bfly_sum_i(int s) {
    s += __shfl_xor(s, 32); s += __shfl_xor(s, 16); s += __shfl_xor(s, 8);
    s += __shfl_xor(s, 4);  s += __shfl_xor(s, 2);  s += __shfl_xor(s, 1);
    return s;
}

#define ALD 196
#define NB  32
#define ZR  196
#define FGRID 256

// ============================================================================
// v6: single-node graph — no memset, no ticket counter.
// Each block: prune partials + input sums -> sc1 per-block slots -> vmcnt
// drain -> sentinel pair -> exit. Block 0 polls the 256 sentinel pairs
// (distributed addresses, 1/thread), sums partial counts, and finalizes.
// Fast path (cnt1==cnt2==0, true for bench data): zero slow-only terms as
// literals. Slow path (cold): block 0 self-zeroes scal slots, compacts the
// n-list, and runs the original single-block phase chain.
// ============================================================================
__global__ __launch_bounds__(256) void k_fused(
    const float* __restrict__ Xm_m, const float* __restrict__ Xm_v,
    const float* __restrict__ Z, const float* __restrict__ X_mean,
    const float* __restrict__ X_var, const float* __restrict__ kern_var,
    const float* __restrict__ kern_ls, const float* __restrict__ lik,
    float* __restrict__ ws, float* __restrict__ out)
{
    __shared__ __align__(16) float smem[2 * 32 * ZR];   // 49 KB (slow path tiles)
    __shared__ int s_bc1, s_bc2, s_blist[8];
    __shared__ int s_c1, s_c2;
    __shared__ int s_red[8];
    const int tid  = threadIdx.x;
    const int lane = tid & 63;
    const int wav  = tid >> 6;
    const int nblk = gridDim.x;
    const int bid  = blockIdx.x;

    if (tid == 0) { s_bc1 = 0; s_bc2 = 0; }
    __syncthreads();

    // ---------------- Phase A-lite: prune partials (per-block) ----------------
    // cnt1/cnt2 depend only on X_var / Xm_v / kern_ls. Max 8 surviving n per
    // block (4 waves x <=2 grid-stride iterations). Arithmetic identical.
    for (int n = bid * 4 + wav; n < NR; n += nblk * 4) {
        float v0 = 0, v1 = 0;
        #pragma unroll
        for (int s = 0; s < 3; s++) {
            int q = lane + 64 * s;
            float v = (q < 96) ? X_var[n * QD + q] : Xm_v[(1 + n) * QD + (q - 96)];
            float ls = kern_ls[q]; float l2 = ls * ls;
            v0 += log1pf(v / l2);
            v1 += log1pf(2.0f * v / l2);
        }
        v0 = bfly_sum(v0); v1 = bfly_sum(v1);
        if (lane == 0) {
            float ld1 = -0.5f * v0;                // exact sup of psi1 exponent
            float ld2 = -0.5f * v1;                // exact sup of psi2 exponent
            if (ld1 > PRUNE_CUT) atomicAdd(&s_bc1, 1);
            if (ld2 > PRUNE_CUT) { int i = atomicAdd(&s_bc2, 1); s_blist[i] = n; }
        }
    }
    {   // input sums (Svo, Smo2, Slog, Smb) -> per-block sc1 partials
        float pVo = 0, pMo = 0, pLg = 0, pMb = 0;
        for (int idx = bid * 256 + tid; idx < NTT * QD; idx += nblk * 256) {
            float xm = X_mean[idx], xv = X_var[idx];
            if (idx >= LT * QD) { pVo += xv; pMo += xm * xm; pLg += logf(xv); }
            else                { pMb += xm * xm + xv; }
        }
        pVo = bfly_sum(pVo); pMo = bfly_sum(pMo); pLg = bfly_sum(pLg); pMb = bfly_sum(pMb);
        float* part = smem;   // 16 floats
        if (lane == 0) { part[wav*4+0] = pVo; part[wav*4+1] = pMo; part[wav*4+2] = pLg; part[wav*4+3] = pMb; }
        __syncthreads();      // also publishes s_bc1/s_bc2/s_blist block-wide
        if (tid < 4) {
            float s = part[tid] + part[4 + tid] + part[8 + tid] + part[12 + tid];
            STWSF(&ws[OFF_BSUM + bid * 4 + tid], s);            // sc1 store
        }
        if (tid < 2) STWSI((int*)(ws + OFF_PBC) + 2 * bid + tid,
                           (tid == 0) ? s_bc1 : s_bc2);          // sc1 store
        if (tid < s_bc2) STWSI((int*)(ws + OFF_PBL) + 8 * bid + tid, s_blist[tid]);
    }

    // ---- publish: drain vmcnt (data at coherent point), then sentinels ----
    __syncthreads();   // emits s_waitcnt vmcnt(0) before s_barrier
    if (tid == 0) STWSI((int*)(ws + OFF_SENT) + 2 * bid,     SENT_A);
    if (tid == 1) STWSI((int*)(ws + OFF_SENT) + 2 * bid + 1, SENT_B);
    if (bid != 0) return;   // non-finalizer blocks: done. no polling, no fences.

    // ================= Block 0: wait for all, then finalize =================
    {   // poll 256 sentinel pairs, one pair per thread (distributed addresses)
        const int* sent = (const int*)(ws + OFF_SENT);
        for (;;) {
            int a = LDWSI(sent + 2 * tid);
            int b = LDWSI(sent + 2 * tid + 1);
            int ok = (a == (int)SENT_A) && (b == (int)SENT_B);
            if (__syncthreads_and(ok)) break;
            __builtin_amdgcn_s_sleep(2);
        }
    }
    {   // sum per-block counts
        const int* pbc = (const int*)(ws + OFF_PBC);
        int c1 = bfly_sum_i(LDWSI(pbc + 2 * tid));
        int c2 = bfly_sum_i(LDWSI(pbc + 2 * tid + 1));
        if (lane == 0) { s_red[wav] = c1; s_red[4 + wav] = c2; }
        __syncthreads();
        if (tid == 0) {
            s_c1 = s_red[0] + s_red[1] + s_red[2] + s_red[3];
            s_c2 = s_red[4] + s_red[5] + s_red[6] + s_red[7];
        }
        __syncthreads();
    }
    const int cnt1 = s_c1;
    const int cnt2 = s_c2;
    const bool slowran = (cnt1 | cnt2) != 0;

    if (slowran) {
        // =================== SINGLE-BLOCK SLOW PATH ==========================
        // Never exercised by bench data (cnt1==cnt2==0 there). Correctness-only.
        __builtin_amdgcn_fence(__ATOMIC_ACQUIRE, "agent");  // see peers' sc1 data
        // self-zero scalar accumulators (poison otherwise)
        if (tid < 16) ws[OFF_SCAL + tid] = 0.0f;
        // compact the surviving-n list from per-block segments
        if (tid == 0) {
            const int* pbc = (const int*)(ws + OFF_PBC);
            const int* pbl = (const int*)(ws + OFF_PBL);
            int* nl = (int*)(ws + OFF_NLIST);
            int p = 0;
            for (int b = 0; b < FGRID; b++) {
                int c = pbc[2 * b + 1];
                for (int j = 0; j < c; j++) nl[p++] = pbl[8 * b + j];
            }
        }
        __syncthreads();
        const int ty4 = tid >> 4, tx4 = tid & 15;
        float kv = *kern_var;

        // ---- A2: full per-n prep (derived arrays + S1/S2) ----
        for (int n = wav; n < NR; n += 4) {
            float v0 = 0, v1 = 0, v2 = 0, v3 = 0;
            #pragma unroll
            for (int s = 0; s < 3; s++) {
                int q = lane + 64 * s;
                float u, v;
                if (q < 96) { u = X_mean[n * QD + q]; v = X_var[n * QD + q]; }
                else        { int j = q - 96; u = Xm_m[(1 + n) * QD + j]; v = Xm_v[(1 + n) * QD + j]; }
                float ls = kern_ls[q]; float l2 = ls * ls;
                float d1 = l2 + v, d2 = l2 + 2.0f * v;
                float i1 = 1.0f / d1, i2 = 1.0f / d2;
                ws[OFF_P1  + n * DIN + q] = u * i1;
                ws[OFF_R1  + n * DIN + q] = i1;
                ws[OFF_W2  + n * DIN + q] = i2;
                ws[OFF_WU2 + n * DIN + q] = u * i2;
                v0 += log1pf(v / l2);
                v1 += log1pf(2.0f * v / l2);
                v2 += u * u * i1;
                v3 += u * u * i2;
            }
            v0 = bfly_sum(v0); v1 = bfly_sum(v1); v2 = bfly_sum(v2); v3 = bfly_sum(v3);
            if (lane == 0) {
                ws[OFF_S1 + n] = -0.5f * (v0 + v2);
                ws[OFF_S2 + n] = -0.5f * v1 - v3;
            }
        }
        __syncthreads();

        // ---- B: Kuu/d2zz tiles + psi1 tiles + F tiles ----
        for (int vb = 0; vb < 144 + 2 * 1128; vb++) {
            if (vb < 144) {
                int bx = vb / 12, by = vb - bx * 12;
                float (*Zm)[17] = (float(*)[17])smem;
                float (*Zp)[17] = (float(*)[17])(smem + 272);
                int m = bx * 16 + ty4, p = by * 16 + tx4;
                float d = 0.0f;
                for (int qc = 0; qc < 12; qc++) {
                    int q0 = qc * 16;
                    float inv_ls = 1.0f / kern_ls[q0 + tx4];
                    Zm[ty4][tx4] = Z[(bx * 16 + ty4) * DIN + q0 + tx4] * inv_ls;
                    Zp[ty4][tx4] = Z[(by * 16 + ty4) * DIN + q0 + tx4] * inv_ls;
                    __syncthreads();
                    #pragma unroll
                    for (int k = 0; k < 16; k++) { float t = Zm[ty4][k] - Zp[tx4][k]; d = fmaf(t, t, d); }
                    __syncthreads();
                }
                ws[OFF_D2ZZ + m * MM + p] = d;
                ws[OFF_KUU  + m * MM + p] = kv * __expf(-0.5f * d) + ((m == p) ? JITTER : 0.0f);
            } else if (vb < 144 + 1128) {
                if (cnt1 != 0) {
                    int t = vb - 144, bx = t % 94, by = t / 94;
                    int n = bx * 16 + ty4, m = by * 16 + tx4;
                    float (*Ps)[17]  = (float(*)[17])smem;
                    float (*Rs)[17]  = (float(*)[17])(smem + 272);
                    float (*Zs)[17]  = (float(*)[17])(smem + 544);
                    float (*Z2s)[17] = (float(*)[17])(smem + 816);
                    float dot1 = 0.0f, dot2 = 0.0f;
                    for (int qc = 0; qc < 12; qc++) {
                        int q0 = qc * 16;
                        Ps[ty4][tx4] = (n < NR) ? ws[OFF_P1 + n * DIN + q0 + tx4] : 0.0f;
                        Rs[ty4][tx4] = (n < NR) ? ws[OFF_R1 + n * DIN + q0 + tx4] : 0.0f;
                        float z = Z[(by * 16 + ty4) * DIN + q0 + tx4];
                        Zs[ty4][tx4] = z; Z2s[ty4][tx4] = z * z;
                        __syncthreads();
                        #pragma unroll
                        for (int k = 0; k < 16; k++) {
                            dot1 = fmaf(Ps[ty4][k], Zs[tx4][k], dot1);
                            dot2 = fmaf(Rs[ty4][k], Z2s[tx4][k], dot2);
                        }
                        __syncthreads();
                    }
                    if (n < NR) ws[OFF_PSI1 + n * MM + m] = kv * __expf(ws[OFF_S1 + n] + dot1 - 0.5f * dot2);
                }
            } else {
                if (cnt2 != 0) {
                    int t = vb - (144 + 1128), bx = t % 94, by = t / 94;
                    int n = bx * 16 + ty4, m = by * 16 + tx4;
                    float (*Us)[17] = (float(*)[17])smem;
                    float (*Ws)[17] = (float(*)[17])(smem + 272);
                    float (*Zb)[17] = (float(*)[17])(smem + 544);
                    float dotB = 0.0f, dotC = 0.0f;
                    for (int qc = 0; qc < 12; qc++) {
                        int q0 = qc * 16;
                        Us[ty4][tx4] = (n < NR) ? ws[OFF_WU2 + n * DIN + q0 + tx4] : 0.0f;
                        Ws[ty4][tx4] = (n < NR) ? ws[OFF_W2  + n * DIN + q0 + tx4] : 0.0f;
                        Zb[ty4][tx4] = Z[(by * 16 + ty4) * DIN + q0 + tx4];
                        __syncthreads();
                        #pragma unroll
                        for (int k = 0; k < 16; k++) {
                            float z = Zb[tx4][k];
                            dotB = fmaf(z, Us[ty4][k], dotB);
                            dotC = fmaf(z * z, Ws[ty4][k], dotC);
                        }
                        __syncthreads();
                    }
                    if (n < NR) ws[OFF_F + n * MM + m] = fmaf(-0.25f, dotC, dotB);
                }
            }
        }
        __syncthreads();

        // ---- C: G rows + psi2 tiles (or exact-zero fill) ----
        for (int vb = 0; vb < 192 + 36; vb++) {
            if (vb < 192) {
                if (cnt1 != 0) {
                    int m = vb;
                    const float* psi1 = ws + OFF_PSI1;
                    float g[QD];
                    #pragma unroll
                    for (int d = 0; d < QD; d++) g[d] = 0.0f;
                    for (int n = tid; n < NR; n += 256) {
                        float p = psi1[n * MM + m];
                        const float* xr = X_mean + (LT + n) * QD;
                        #pragma unroll
                        for (int d = 0; d < QD; d++) g[d] = fmaf(p, xr[d], g[d]);
                    }
                    float* red = smem;   // 256 floats
                    bool any = false;
                    for (int d = 0; d < QD; d++) {
                        red[tid] = g[d]; __syncthreads();
                        if (tid < 128) red[tid] += red[tid + 128];
                        __syncthreads();
                        if (tid < 64) {
                            float s = red[tid] + red[tid + 64];
                            s = wave_reduce(s);
                            if (tid == 0) { ws[OFF_G + m * QD + d] = s; any |= (s != 0.0f); }
                        }
                        __syncthreads();
                    }
                    if (tid == 0 && any) atomicOr((int*)(ws + OFF_SCAL) + 14, 1);
                }
            } else {
                int t = vb - 192, bx = t / 6, by = t - 6 * bx;
                int m0 = bx * 32, p0 = by * 32;
                int ty4b = tid >> 4, tx4b = tid & 15;
                int mA = m0 + 2 * ty4b, pA = p0 + 2 * tx4b;
                float* P2 = ws + OFF_PSI2;
                if (cnt2 == 0) {
                    P2[(mA    ) * MM + pA    ] = 0.0f;
                    P2[(mA    ) * MM + pA + 1] = 0.0f;
                    P2[(mA + 1) * MM + pA    ] = 0.0f;
                    P2[(mA + 1) * MM + pA + 1] = 0.0f;
                    __syncthreads();
                } else {
                    float a00 = 0, a01 = 0, a10 = 0, a11 = 0;
                    float* Zm = smem;             // 32*ZR
                    float* Zp = smem + 32 * ZR;   // 32*ZR
                    for (int idx = tid; idx < 32 * DIN; idx += 256) {
                        int r = idx / DIN, q = idx - r * DIN;
                        Zm[r * ZR + q] = Z[(m0 + r) * DIN + q];
                        Zp[r * ZR + q] = Z[(p0 + r) * DIN + q];
                    }
                    __syncthreads();
                    const float* w2base = ws + OFF_W2;
                    const float* F      = ws + OFF_F;
                    const float* s2arr  = ws + OFF_S2;
                    const int* list     = (const int*)(ws + OFF_NLIST);
                    const float4* zm0 = (const float4*)(Zm + (2 * ty4b    ) * ZR);
                    const float4* zm1 = (const float4*)(Zm + (2 * ty4b + 1) * ZR);
                    const float4* zp0 = (const float4*)(Zp + (2 * tx4b    ) * ZR);
                    const float4* zp1 = (const float4*)(Zp + (2 * tx4b + 1) * ZR);
                    for (int li = 0; li < cnt2; li++) {
                        int n = list[li];
                        const float4* w2p = (const float4*)(w2base + n * DIN);
                        float e00 = 0, e01 = 0, e10 = 0, e11 = 0;
                        #pragma unroll 4
                        for (int g = 0; g < DIN / 4; g++) {
                            float4 w = w2p[g];
                            float4 a = zm0[g], b = zm1[g], c = zp0[g], d = zp1[g];
                            float wp0, wp1;
                            wp0 = w.x * c.x; wp1 = w.x * d.x;
                            e00 = fmaf(a.x, wp0, e00); e01 = fmaf(a.x, wp1, e01);
                            e10 = fmaf(b.x, wp0, e10); e11 = fmaf(b.x, wp1, e11);
                            wp0 = w.y * c.y; wp1 = w.y * d.y;
                            e00 = fmaf(a.y, wp0, e00); e01 = fmaf(a.y, wp1, e01);
                            e10 = fmaf(b.y, wp0, e10); e11 = fmaf(b.y, wp1, e11);
                            wp0 = w.z * c.z; wp1 = w.z * d.z;
                            e00 = fmaf(a.z, wp0, e00); e01 = fmaf(a.z, wp1, e01);
                            e10 = fmaf(b.z, wp0, e10); e11 = fmaf(b.z, wp1, e11);
                            wp0 = w.w * c.w; wp1 = w.w * d.w;
                            e00 = fmaf(a.w, wp0, e00); e01 = fmaf(a.w, wp1, e01);
                            e10 = fmaf(b.w, wp0, e10); e11 = fmaf(b.w, wp1, e11);
                        }
                        float s2n = s2arr[n];
                        float Fm0 = F[n * MM + mA], Fm1 = F[n * MM + mA + 1];
                        float Fp0 = F[n * MM + pA], Fp1 = F[n * MM + pA + 1];
                        a00 += __expf(s2n + Fm0 + Fp0 - 0.5f * e00);
                        a01 += __expf(s2n + Fm0 + Fp1 - 0.5f * e01);
                        a10 += __expf(s2n + Fm1 + Fp0 - 0.5f * e10);
                        a11 += __expf(s2n + Fm1 + Fp1 - 0.5f * e11);
                    }
                    float kv2 = kv * kv;
                    const float* dz = ws + OFF_D2ZZ;
                    P2[(mA    ) * MM + pA    ] = kv2 * __expf(-0.25f * dz[(mA    ) * MM + pA    ]) * a00;
                    P2[(mA    ) * MM + pA + 1] = kv2 * __expf(-0.25f * dz[(mA    ) * MM + pA + 1]) * a01;
                    P2[(mA + 1) * MM + pA    ] = kv2 * __expf(-0.25f * dz[(mA + 1) * MM + pA    ]) * a10;
                    P2[(mA + 1) * MM + pA + 1] = kv2 * __expf(-0.25f * dz[(mA + 1) * MM + pA + 1]) * a11;
                    __syncthreads();
                }
            }
        }
        __syncthreads();
        const int gflag = ((const int*)(ws + OFF_SCAL))[14];

        // ---- D: dual blocked LDL^T (sequential) in global scratch ----
        if (cnt2 != 0 || gflag != 0) {
            for (int mat = 0; mat < 2; mat++) {
                bool isC2 = (mat == 1);
                float* A = ws + OFF_CHA + (size_t)mat * (MM * ALD);
                const float* Kuu  = ws + OFF_KUU;
                const float* psi2 = ws + OFF_PSI2;
                float inv_s2 = 1.0f / (*lik);
                for (int idx = tid; idx < MM * MM; idx += 256) {
                    int i = idx / MM, j = idx - i * MM;
                    float v = Kuu[idx];
                    if (isC2) v = fmaf(psi2[idx], inv_s2, v);
                    A[i * ALD + j] = v;
                }
                __syncthreads();
                float logacc = 0.0f;
                int ty = tid >> 4, tx = tid & 15;
                for (int p = 0; p < MM / NB; p++) {
                    int k0 = p * NB;
                    int e  = k0 + NB;
                    if (tid < 64) {
                        int l64 = tid;
                        float P[3][NB];
                        #pragma unroll
                        for (int s = 0; s < 3; s++) {
                            int r = l64 + 64 * s;
                            #pragma unroll
                            for (int g = 0; g < NB / 4; g++) {
                                float4 v = *(const float4*)&A[r * ALD + k0 + 4 * g];
                                P[s][4*g] = v.x; P[s][4*g+1] = v.y; P[s][4*g+2] = v.z; P[s][4*g+3] = v.w;
                            }
                        }
                        int sD = k0 >> 6;
                        int lD = k0 & 63;
                        #pragma unroll
                        for (int c = 0; c < NB; c++) {
                            int k = k0 + c;
                            float colc = (sD == 0) ? P[0][c] : ((sD == 1) ? P[1][c] : P[2][c]);
                            float dkk = __shfl(colc, lD + c);
                            float inv = 1.0f / dkk;
                            logacc += logf(dkk);
                            float m0 = (l64       > k) ? P[0][c] * inv : 0.0f;
                            float m1 = (l64 + 64  > k) ? P[1][c] * inv : 0.0f;
                            float m2 = (l64 + 128 > k) ? P[2][c] * inv : 0.0f;
                            P[0][c] = (l64       > k) ? m0 : P[0][c];
                            P[1][c] = (l64 + 64  > k) ? m1 : P[1][c];
                            P[2][c] = (l64 + 128 > k) ? m2 : P[2][c];
                            #pragma unroll
                            for (int j = c + 1; j < NB; j++) {
                                float w = __shfl(colc, lD + j);
                                P[0][j] = fmaf(-m0, w, P[0][j]);
                                P[1][j] = fmaf(-m1, w, P[1][j]);
                                P[2][j] = fmaf(-m2, w, P[2][j]);
                            }
                        }
                        #pragma unroll
                        for (int s = 0; s < 3; s++) {
                            int r = l64 + 64 * s;
                            #pragma unroll
                            for (int g = 0; g < NB / 4; g++) {
                                float4 v = make_float4(P[s][4*g], P[s][4*g+1], P[s][4*g+2], P[s][4*g+3]);
                                *(float4*)&A[r * ALD + k0 + 4 * g] = v;
                            }
                        }
                    }
                    __syncthreads();
                    int T = MM - e;
                    if (T > 0) {
                        for (int idx = tid; idx < NB * T; idx += 256) {
                            int c = idx / T, j = e + (idx - c * T);
                            float d = A[(k0 + c) * ALD + (k0 + c)];
                            A[(k0 + c) * ALD + j] = A[j * ALD + k0 + c] * sqrtf(d);
                        }
                        __syncthreads();
                        int nT = (T + 127) / 128;
                        for (int bi = 0; bi < nT; bi++)
                        for (int bj = 0; bj < nT; bj++) {
                            int i0 = e + 128 * bi + 8 * ty;
                            int j0 = e + 128 * bj + 8 * tx;
                            int ic = (i0 < MM - 8) ? i0 : (MM - 8);
                            int jc = (j0 < MM - 8) ? j0 : (MM - 8);
                            float4 acc[8][2];
                            #pragma unroll
                            for (int r = 0; r < 8; r++) {
                                acc[r][0] = *(const float4*)&A[(ic + r) * ALD + jc];
                                acc[r][1] = *(const float4*)&A[(ic + r) * ALD + jc + 4];
                            }
                            #pragma unroll 4
                            for (int c = 0; c < NB; c++) {
                                const float* row = &A[(k0 + c) * ALD];
                                float4 av0 = *(const float4*)&row[ic];
                                float4 av1 = *(const float4*)&row[ic + 4];
                                float4 bv0 = *(const float4*)&row[jc];
                                float4 bv1 = *(const float4*)&row[jc + 4];
                                float avs[8] = {av0.x, av0.y, av0.z, av0.w, av1.x, av1.y, av1.z, av1.w};
                                #pragma unroll
                                for (int r = 0; r < 8; r++) {
                                    float a = avs[r];
                                    acc[r][0].x = fmaf(-a, bv0.x, acc[r][0].x);
                                    acc[r][0].y = fmaf(-a, bv0.y, acc[r][0].y);
                                    acc[r][0].z = fmaf(-a, bv0.z, acc[r][0].z);
                                    acc[r][0].w = fmaf(-a, bv0.w, acc[r][0].w);
                                    acc[r][1].x = fmaf(-a, bv1.x, acc[r][1].x);
                                    acc[r][1].y = fmaf(-a, bv1.y, acc[r][1].y);
                                    acc[r][1].z = fmaf(-a, bv1.z, acc[r][1].z);
                                    acc[r][1].w = fmaf(-a, bv1.w, acc[r][1].w);
                                }
                            }
                            if (ic == i0 && jc == j0) {
                                #pragma unroll
                                for (int r = 0; r < 8; r++) {
                                    *(float4*)&A[(i0 + r) * ALD + j0]     = acc[r][0];
                                    *(float4*)&A[(i0 + r) * ALD + j0 + 4] = acc[r][1];
                                }
                            }
                        }
                        __syncthreads();
                    }
                }
                float* dst = ws + (isC2 ? OFF_LC2 : OFF_LC);
                for (int idx = tid; idx < MM * MM; idx += 256) {
                    int i = idx / MM, j = idx - i * MM;
                    dst[idx] = A[i * ALD + j];
                }
                if (tid == 0) ws[OFF_SCAL + (isC2 ? 8 : 7)] = 0.5f * logacc;
                __syncthreads();
            }
        }

        // ---- E: triangular solves (wave-per-column, 4 waves) ----
        for (int u = wav; u < MM + QD; u += 4) {
            if (u < MM) {
                if (cnt2 != 0) {
                    const float* L = ws + OFF_LC;
                    float* V = ws + OFF_V;
                    int j = u;
                    int k0 = j + lane, k1 = k0 + 64, k2 = k0 + 128;
                    float x0 = 0, x1 = 0, x2 = 0;
                    for (int i = j; i < MM; i++) {
                        const float* Lr = L + i * MM;
                        float s = 0.0f;
                        if (k0 < i) s = fmaf(Lr[k0], x0, s);
                        if (k1 < i) s = fmaf(Lr[k1], x1, s);
                        if (k2 < i) s = fmaf(Lr[k2], x2, s);
                        #pragma unroll
                        for (int off = 1; off < 64; off <<= 1) s += __shfl_xor(s, off);
                        float xi = ((i == j) ? 1.0f : 0.0f) - s;
                        if (k0 == i) x0 = xi;
                        if (k1 == i) x1 = xi;
                        if (k2 == i) x2 = xi;
                        if (lane == 0) V[i * MM + j] = xi;
                    }
                }
            } else if (gflag != 0) {
                const float* L = ws + OFF_LC2;
                const float* G = ws + OFF_G;
                int c = u - MM;
                int k0 = lane, k1 = lane + 64, k2 = lane + 128;
                float x0 = 0, x1 = 0, x2 = 0, ss = 0;
                for (int i = 0; i < MM; i++) {
                    const float* Lr = L + i * MM;
                    float s = 0.0f;
                    if (k0 < i) s = fmaf(Lr[k0], x0, s);
                    if (k1 < i) s = fmaf(Lr[k1], x1, s);
                    if (k2 < i) s = fmaf(Lr[k2], x2, s);
                    #pragma unroll
                    for (int off = 1; off < 64; off <<= 1) s += __shfl_xor(s, off);
                    float xi = G[i * QD + c] - s;
                    if (k0 == i) x0 = xi;
                    if (k1 == i) x1 = xi;
                    if (k2 == i) x2 = xi;
                    if (lane == 0) ss += xi * xi / Lr[i];
                }
                if (lane == 0) atomicAdd(&ws[OFF_SCAL + 2], ss);
            }
        }
        __syncthreads();

        // ---- F: trace_raw ----
        if (cnt2 != 0) {
            for (int i = 0; i < MM; i++) {
                float* vrow = smem;         // 192
                float* red  = smem + 192;   // 256
                const float* V = ws + OFF_V;
                const float* P = ws + OFF_PSI2;
                for (int a = tid; a < MM; a += 256) vrow[a] = (a <= i) ? V[i * MM + a] : 0.0f;
                __syncthreads();
                float acc = 0.0f;
                for (int a = tid; a <= i; a += 256) {
                    const float* Pr = P + a * MM;
                    float inner = 0.0f;
                    for (int b = 0; b <= i; b++) inner = fmaf(Pr[b], vrow[b], inner);
                    acc = fmaf(vrow[a], inner, acc);
                }
                red[tid] = acc; __syncthreads();
                if (tid < 128) red[tid] += red[tid + 128];
                __syncthreads();
                if (tid < 64) {
                    float s = red[tid] + red[tid + 64];
                    s = wave_reduce(s);
                    if (tid == 0) { float di = ws[OFF_LC + i * MM + i]; atomicAdd(&ws[OFF_SCAL + 0], s / di); }
                }
                __syncthreads();
            }
        }
        __syncthreads();
    }

    // ---------------- Final assembly (block 0) ----------------
    {
        // thread t reads BSUM[t], [t+256], [t+512], [t+768] -> component t&3
        float s = 0.0f;
        #pragma unroll
        for (int r = 0; r < 4; r++) s += LDWSF(ws + OFF_BSUM + tid + 256 * r);
        // sum over lanes with equal (lane & 3) within the wave
        s += __shfl_xor(s, 4); s += __shfl_xor(s, 8);
        s += __shfl_xor(s, 16); s += __shfl_xor(s, 32);
        float* fin = smem;   // 16 floats: [wave][component]
        __syncthreads();
        if (lane < 4) fin[wav * 4 + lane] = s;
        __syncthreads();
        if (tid == 0) {
            float Svo  = fin[0] + fin[4] + fin[8]  + fin[12];
            float Smo2 = fin[1] + fin[5] + fin[9]  + fin[13];
            float Slog = fin[2] + fin[6] + fin[10] + fin[14];
            float Smb  = fin[3] + fin[7] + fin[11] + fin[15];
            // slow-only terms: exact zeros on the fast path (identical to the
            // memset-zeroed loads of prior rounds), slot reads after slow path.
            float trRaw = slowran ? ws[OFF_SCAL + 0] : 0.0f;
            float ssY   = slowran ? ws[OFF_SCAL + 2] : 0.0f;
            float ldK   = slowran ? ws[OFF_SCAL + 7] : 0.0f;
            float ldC2  = slowran ? ws[OFF_SCAL + 8] : 0.0f;
            float kv = *kern_var, s2v = *lik;
            float inv_s2 = 1.0f / s2v;
            const float lp2pi = 1.8378770664093453f;  // log(2*pi)
            float trA = trRaw * inv_s2;
            float ldB = 2.0f * (ldC2 - ldK);
            float sc2 = ssY * inv_s2 * inv_s2;
            float ND = 18000.0f;   // (Nt-Lt)*D
            float Df = 12.0f;
            float bound = -0.5f * ND * (lp2pi + logf(s2v));
            bound += -0.5f * inv_s2 * (Svo + Smo2);
            bound += -0.5f * Df * ((kv * 1500.0f) * inv_s2 - trA);
            bound += -0.5f * Df * ldB;
            bound += 0.5f * sc2;
            bound += 0.5f * Slog + 0.5f * ND * lp2pi;      // ent
            bound += -96.0f * lp2pi - 0.5f * Smb;          // ent2 (Lt*D = 96)
            out[0] = bound;
        }
    }
}

extern "C" void kernel_launch(void* const* d_in, const int* in_sizes, int n_in,
                              void* d_out, int out_size, void* d_ws, size_t ws_size,
                              hipStream_t stream)
{
    const float* Xm_m    = (const float*)d_in[1];
    const float* Xm_v    = (const float*)d_in[2];
    const float* Z       = (const float*)d_in[3];
    const float* X_mean  = (const float*)d_in[4];
    const float* X_var   = (const float*)d_in[5];
    const float* kern_var= (const float*)d_in[6];
    const float* kern_ls = (const float*)d_in[7];
    const float* lik_var = (const float*)d_in[8];
    float* ws  = (float*)d_ws;
    float* out = (float*)d_out;

    // SINGLE graph node: no memset — all state is sentinel-guarded or
    // unconditionally written (poison-proof handshake, see OFF_SENT).
    k_fused<<<FGRID, 256, 0, stream>>>(Xm_m, Xm_v, Z, X_mean, X_var,
                                       kern_var, kern_ls, lik_var, ws, out);
}